// Round 7
// baseline (6030.377 us; speedup 1.0000x reference)
//
#include <hip/hip_runtime.h>
#include <hip/hip_bf16.h>

#define NN   30000
#define NE   480000
#define EMBD 256
#define NG   512
#define NLAY 3
#define LEAK 0.2f

typedef __attribute__((ext_vector_type(8))) short bf16x8;
typedef __attribute__((ext_vector_type(4))) float f32x4;

__device__ __forceinline__ float bf2f(unsigned short u) {
  union { unsigned int i; float f; } v; v.i = ((unsigned int)u) << 16; return v.f;
}
__device__ __forceinline__ unsigned short f2bf(float f) {
  union { float f; unsigned int i; } v; v.f = f;
  unsigned int u = v.i;
  u += 0x7fffu + ((u >> 16) & 1u);
  return (unsigned short)(u >> 16);
}
// read a float input that may be fp32 or bf16 on device
__device__ __forceinline__ float rdw(const void* p, size_t i, int f32) {
  return f32 ? ((const float*)p)[i] : bf2f(((const unsigned short*)p)[i]);
}
__device__ __forceinline__ void atomic_max_f32(float* addr, float val) {
  int* ia = (int*)addr;
  int cur = *ia;
  while (__int_as_float(cur) < val) {
    int assumed = cur;
    cur = atomicCAS(ia, assumed, __float_as_int(val));
    if (cur == assumed) break;
  }
}

// ---------------- dtype sniff ----------------
// If the float inputs are fp32 read as u16, even-indexed u16s are fp32 low
// mantissa halves -> ~1/256 have a bf16-NaN exponent pattern. True bf16
// weight data never does.
__global__ void k_sniff(const unsigned short* __restrict__ w, int* flag) {
  __shared__ int cnt;
  if (threadIdx.x == 0) cnt = 0;
  __syncthreads();
  int local = 0;
  for (int i = threadIdx.x * 2; i < 65536; i += 512) {
    unsigned short u = w[i];
    if (((u >> 7) & 0xFF) == 0xFF) local++;
  }
  atomicAdd(&cnt, local);
  __syncthreads();
  if (threadIdx.x == 0) *flag = (cnt >= 4) ? 1 : 0;
}

// ---------------- setup kernels ----------------

__global__ void k_transpose_w(const void* __restrict__ W, unsigned short* __restrict__ Wt,
                              const int* __restrict__ flagp) {
  int f32 = *flagp;
  int t = blockIdx.x * 256 + threadIdx.x;          // t = l*65536 + k*256 + c
  int l = t >> 16;
  int k = (t >> 8) & 255;
  int c = t & 255;
  Wt[(l << 16) + (c << 8) + k] = f2bf(rdw(W, t, f32));
}

__global__ void k_atom_enc(const int* __restrict__ x, const void* __restrict__ emb,
                           float* __restrict__ h, unsigned short* __restrict__ hbf,
                           const int* __restrict__ flagp) {
  int f32 = *flagp;
  int n = blockIdx.x, c = threadIdx.x;
  float s = 0.f;
  #pragma unroll
  for (int i = 0; i < 9; ++i) {
    int xi = x[n * 9 + i];
    s += rdw(emb, (size_t)(i * 128 + xi) * 256 + c, f32);
  }
  h[n * 256 + c] = s;
  hbf[n * 256 + c] = f2bf(s);
}

// ---------------- per-layer kernels ----------------

__global__ void k_init_layer(float* deg, float* loop3, float* mmax, float* denom,
                             float* wa, const void* __restrict__ We,
                             const void* __restrict__ ae, int l,
                             const int* __restrict__ flagp) {
  int t = blockIdx.x * 256 + threadIdx.x;
  if (t < NN) {
    deg[t] = 0.f; mmax[t] = -1e30f; denom[t] = 0.f;
    loop3[3*t] = 0.f; loop3[3*t+1] = 0.f; loop3[3*t+2] = 0.f;
  }
  if (blockIdx.x == 0 && t < 3) {   // wa[j] = sum_c We[l,j,c] * att_edge[l,c]
    int f32 = *flagp;
    float s = 0.f;
    for (int c = 0; c < 256; ++c)
      s += rdw(We, (size_t)l*3*256 + t*256 + c, f32) * rdw(ae, (size_t)l*256 + c, f32);
    wa[t] = s;
  }
}

__global__ void k_bond_scatter(const int* __restrict__ eattr, const int* __restrict__ dst,
                               const void* __restrict__ bemb, int l, float* __restrict__ e_enc,
                               float* deg, float* loop3, const int* __restrict__ flagp) {
  int f32 = *flagp;
  int e = blockIdx.x * 256 + threadIdx.x;
  if (e >= NE) return;
  float v0 = 0.f, v1 = 0.f, v2 = 0.f;
  #pragma unroll
  for (int t = 0; t < 3; ++t) {
    int a = eattr[e*3 + t];
    size_t base = (size_t)l*144 + (size_t)(t*16 + a)*3;
    v0 += rdw(bemb, base+0, f32);
    v1 += rdw(bemb, base+1, f32);
    v2 += rdw(bemb, base+2, f32);
  }
  e_enc[e*3] = v0; e_enc[e*3+1] = v1; e_enc[e*3+2] = v2;
  int d = dst[e];
  unsafeAtomicAdd(&deg[d], 1.f);
  unsafeAtomicAdd(&loop3[d*3],   v0);
  unsafeAtomicAdd(&loop3[d*3+1], v1);
  unsafeAtomicAdd(&loop3[d*3+2], v2);
}

__global__ void k_loop_div(float* loop3, const float* __restrict__ deg) {
  int n = blockIdx.x * 256 + threadIdx.x;
  if (n >= NN) return;
  float inv = 1.f / fmaxf(deg[n], 1.f);
  loop3[n*3] *= inv; loop3[n*3+1] *= inv; loop3[n*3+2] *= inv;
}

// xl = h_bf16 @ W[l] ; A row-major [NN,256] bf16, Bt = W^T [col][k] bf16, C f32
__global__ __launch_bounds__(256) void k_gemm_xl(const unsigned short* __restrict__ A,
                                                 const unsigned short* __restrict__ Bt,
                                                 float* __restrict__ C) {
  int wid  = blockIdx.x * 4 + (threadIdx.x >> 6);   // 7500 waves
  int lane = threadIdx.x & 63;
  int m0 = (wid >> 2) * 16;
  int c0 = (wid & 3) * 64;
  int lr = lane & 15;
  int lk = (lane >> 4) * 8;
  f32x4 acc0 = {0.f,0.f,0.f,0.f}, acc1 = {0.f,0.f,0.f,0.f};
  f32x4 acc2 = {0.f,0.f,0.f,0.f}, acc3 = {0.f,0.f,0.f,0.f};
  const unsigned short* arow = A  + (size_t)(m0 + lr) * 256 + lk;
  const unsigned short* b0   = Bt + (size_t)(c0 + lr) * 256 + lk;
  #pragma unroll
  for (int k = 0; k < 256; k += 32) {
    bf16x8 a = *(const bf16x8*)(arow + k);
    acc0 = __builtin_amdgcn_mfma_f32_16x16x32_bf16(a, *(const bf16x8*)(b0 + k),          acc0, 0,0,0);
    acc1 = __builtin_amdgcn_mfma_f32_16x16x32_bf16(a, *(const bf16x8*)(b0 + 16*256 + k), acc1, 0,0,0);
    acc2 = __builtin_amdgcn_mfma_f32_16x16x32_bf16(a, *(const bf16x8*)(b0 + 32*256 + k), acc2, 0,0,0);
    acc3 = __builtin_amdgcn_mfma_f32_16x16x32_bf16(a, *(const bf16x8*)(b0 + 48*256 + k), acc3, 0,0,0);
  }
  // C/D layout: col = lane&15, row = (lane>>4)*4 + reg
  float* crow = C + (size_t)(m0 + (lane >> 4) * 4) * 256 + c0 + lr;
  #pragma unroll
  for (int r = 0; r < 4; ++r) {
    crow[r*256 +  0] = acc0[r];
    crow[r*256 + 16] = acc1[r];
    crow[r*256 + 32] = acc2[r];
    crow[r*256 + 48] = acc3[r];
  }
}

__global__ void k_node_dots(const float* __restrict__ xl, const void* __restrict__ as_w,
                            const void* __restrict__ ad_w, int l,
                            float* __restrict__ as_, float* __restrict__ ad_,
                            const int* __restrict__ flagp) {
  int f32 = *flagp;
  int n = blockIdx.x;
  int lane = threadIdx.x;   // 64
  float s = 0.f, d = 0.f;
  #pragma unroll
  for (int c = lane; c < 256; c += 64) {
    float xv = xl[n*256 + c];
    s += xv * rdw(as_w, (size_t)l*256 + c, f32);
    d += xv * rdw(ad_w, (size_t)l*256 + c, f32);
  }
  #pragma unroll
  for (int o = 32; o > 0; o >>= 1) { s += __shfl_down(s, o); d += __shfl_down(d, o); }
  if (lane == 0) { as_[n] = s; ad_[n] = d; }
}

__global__ void k_alpha_edge(const int* __restrict__ src, const int* __restrict__ dst,
                             const float* __restrict__ e_enc, const float* __restrict__ as_,
                             const float* __restrict__ ad_, const float* __restrict__ wa,
                             float* __restrict__ alpha, float* mmax) {
  int e = blockIdx.x * 256 + threadIdx.x;
  if (e >= NE) return;
  int d = dst[e];
  float a = as_[src[e]] + ad_[d]
          + e_enc[e*3]*wa[0] + e_enc[e*3+1]*wa[1] + e_enc[e*3+2]*wa[2];
  a = (a >= 0.f) ? a : LEAK * a;
  alpha[e] = a;
  atomic_max_f32(&mmax[d], a);
}

__global__ void k_alpha_self(const float* __restrict__ loop3, const float* __restrict__ as_,
                             const float* __restrict__ ad_, const float* __restrict__ wa,
                             float* __restrict__ aself, float* mmax) {
  int n = blockIdx.x * 256 + threadIdx.x;
  if (n >= NN) return;
  float a = as_[n] + ad_[n]
          + loop3[n*3]*wa[0] + loop3[n*3+1]*wa[1] + loop3[n*3+2]*wa[2];
  a = (a >= 0.f) ? a : LEAK * a;
  aself[n] = a;
  atomic_max_f32(&mmax[n], a);
}

__global__ void k_p_edge(const int* __restrict__ dst, const float* __restrict__ mmax,
                         float* __restrict__ alpha, float* denom) {
  int e = blockIdx.x * 256 + threadIdx.x;
  if (e >= NE) return;
  int d = dst[e];
  float p = __expf(alpha[e] - mmax[d]);
  alpha[e] = p;
  unsafeAtomicAdd(&denom[d], p);
}

__global__ void k_p_self(const float* __restrict__ mmax, float* __restrict__ aself, float* denom) {
  int n = blockIdx.x * 256 + threadIdx.x;
  if (n >= NN) return;
  float p = __expf(aself[n] - mmax[n]);
  aself[n] = p;
  unsafeAtomicAdd(&denom[n], p);
}

__global__ void k_agg_edge(const int* __restrict__ src, const int* __restrict__ dst,
                           const float* __restrict__ p, const float* __restrict__ denom,
                           const float* __restrict__ xl, float* hc) {
  int t = blockIdx.x * 256 + threadIdx.x;   // one wave per edge
  int e = t >> 6;
  if (e >= NE) return;
  int lane = t & 63;
  int s = src[e], d = dst[e];
  float w = p[e] / denom[d];
  float4 xv = *(const float4*)(xl + (size_t)s*256 + lane*4);
  float* o = hc + (size_t)d*256 + lane*4;
  unsafeAtomicAdd(o+0, w*xv.x);
  unsafeAtomicAdd(o+1, w*xv.y);
  unsafeAtomicAdd(o+2, w*xv.z);
  unsafeAtomicAdd(o+3, w*xv.w);
}

__global__ void k_finalize(const float* __restrict__ hc, const float* __restrict__ xl,
                           const float* __restrict__ pself, const float* __restrict__ denom,
                           const void* __restrict__ bias, int l, float* __restrict__ h,
                           unsigned short* __restrict__ hbf, int do_relu,
                           const int* __restrict__ flagp) {
  int f32 = *flagp;
  int n = blockIdx.x, c = threadIdx.x;
  float w = pself[n] / denom[n];
  float val = hc[n*256 + c] + w * xl[n*256 + c] + rdw(bias, (size_t)l*256 + c, f32);
  if (do_relu) val = fmaxf(val, 0.f);
  float hn = val + h[n*256 + c];    // residual
  h[n*256 + c] = hn;
  hbf[n*256 + c] = f2bf(hn);
}

// ---------------- pooling + head ----------------

__global__ void k_pool(const float* __restrict__ h, const int* __restrict__ batch,
                       float* hg, float* cnt) {
  int t = blockIdx.x * 256 + threadIdx.x;   // one wave per node
  int n = t >> 6;
  if (n >= NN) return;
  int lane = t & 63;
  int b = batch[n];
  float4 v = *(const float4*)(h + (size_t)n*256 + lane*4);
  float* o = hg + (size_t)b*256 + lane*4;
  unsafeAtomicAdd(o+0, v.x);
  unsafeAtomicAdd(o+1, v.y);
  unsafeAtomicAdd(o+2, v.z);
  unsafeAtomicAdd(o+3, v.w);
  if (lane == 0) unsafeAtomicAdd(&cnt[b], 1.f);
}

__global__ void k_head_v(const void* __restrict__ W1, const void* __restrict__ b1,
                         const void* __restrict__ W2, const void* __restrict__ b2,
                         float* __restrict__ v, float* __restrict__ c0,
                         const int* __restrict__ flagp) {
  int f32 = *flagp;
  int k = threadIdx.x;  // 256
  float s = 0.f;
  for (int c = 0; c < 256; ++c) s += rdw(W1, (size_t)k*256 + c, f32) * rdw(W2, c, f32);
  v[k] = s;
  if (k == 0) {
    float t = 0.f;
    for (int c = 0; c < 256; ++c) t += rdw(b1, c, f32) * rdw(W2, c, f32);
    *c0 = t + rdw(b2, 0, f32);
  }
}

__global__ void k_head_out(const float* __restrict__ hg, const float* __restrict__ cnt,
                           const float* __restrict__ v, const float* __restrict__ c0,
                           void* __restrict__ out, const int* __restrict__ flagp) {
  int g = blockIdx.x;
  int lane = threadIdx.x;  // 64
  float s = 0.f;
  #pragma unroll
  for (int c = lane; c < 256; c += 64) s += hg[g*256 + c] * v[c];
  #pragma unroll
  for (int o = 32; o > 0; o >>= 1) s += __shfl_down(s, o);
  if (lane == 0) {
    float inv = 1.f / fmaxf(cnt[g], 1.f);
    float val = s * inv + *c0;
    if (*flagp) ((float*)out)[g] = val;
    else        ((unsigned short*)out)[g] = f2bf(val);
  }
}

extern "C" void kernel_launch(void* const* d_in, const int* in_sizes, int n_in,
                              void* d_out, int out_size, void* d_ws, size_t ws_size,
                              hipStream_t stream) {
  const int* x     = (const int*)d_in[0];
  const int* eidx  = (const int*)d_in[1];
  const int* eattr = (const int*)d_in[2];
  const int* batch = (const int*)d_in[3];
  const void* atom_emb = d_in[4];
  const void* bond_emb = d_in[5];
  const void* W        = d_in[6];
  const void* att_src  = d_in[7];
  const void* att_dst  = d_in[8];
  const void* We       = d_in[9];
  const void* att_edge = d_in[10];
  const void* bias     = d_in[11];
  const void* W1 = d_in[12];
  const void* b1 = d_in[13];
  const void* W2 = d_in[14];
  const void* b2 = d_in[15];

  const int* src = eidx;
  const int* dst = eidx + NE;

  char* base = (char*)d_ws;
  size_t off = 0;
  auto alloc = [&](size_t bytes) -> char* {
    char* p = base + off; off += (bytes + 255) & ~(size_t)255; return p;
  };
  float* h    = (float*)alloc((size_t)NN*EMBD*4);
  float* xl   = (float*)alloc((size_t)NN*EMBD*4);
  float* hc   = (float*)alloc((size_t)NN*EMBD*4);
  unsigned short* hbf = (unsigned short*)alloc((size_t)NN*EMBD*2);
  unsigned short* wt  = (unsigned short*)alloc((size_t)NLAY*EMBD*EMBD*2);
  float* e_enc = (float*)alloc((size_t)NE*3*4);
  float* alpha = (float*)alloc((size_t)NE*4);
  float* deg   = (float*)alloc((size_t)NN*4);
  float* loop3 = (float*)alloc((size_t)NN*3*4);
  float* as_   = (float*)alloc((size_t)NN*4);
  float* ad_   = (float*)alloc((size_t)NN*4);
  float* mmax  = (float*)alloc((size_t)NN*4);
  float* denom = (float*)alloc((size_t)NN*4);
  float* aself = (float*)alloc((size_t)NN*4);
  float* hg    = (float*)alloc((size_t)NG*EMBD*4);
  float* cnt   = (float*)alloc((size_t)NG*4);
  float* vvec  = (float*)alloc((size_t)EMBD*4);
  float* c0    = (float*)alloc(4);
  float* wa    = (float*)alloc(16);
  int*   flag  = (int*)alloc(4);
  // total ~117 MB of d_ws

  k_sniff<<<1, 256, 0, stream>>>((const unsigned short*)atom_emb, flag);
  k_transpose_w<<<NLAY*EMBD*EMBD/256, 256, 0, stream>>>(W, wt, flag);
  k_atom_enc<<<NN, 256, 0, stream>>>(x, atom_emb, h, hbf, flag);

  for (int l = 0; l < NLAY; ++l) {
    (void)hipMemsetAsync(hc, 0, (size_t)NN*EMBD*4, stream);
    k_init_layer<<<(NN+255)/256, 256, 0, stream>>>(deg, loop3, mmax, denom, wa,
                                                   We, att_edge, l, flag);
    k_bond_scatter<<<(NE+255)/256, 256, 0, stream>>>(eattr, dst, bond_emb, l,
                                                     e_enc, deg, loop3, flag);
    k_loop_div<<<(NN+255)/256, 256, 0, stream>>>(loop3, deg);
    k_gemm_xl<<<(NN/16)*(EMBD/64)/4, 256, 0, stream>>>(hbf, wt + (size_t)l*EMBD*EMBD, xl);
    k_node_dots<<<NN, 64, 0, stream>>>(xl, att_src, att_dst, l, as_, ad_, flag);
    k_alpha_edge<<<(NE+255)/256, 256, 0, stream>>>(src, dst, e_enc, as_, ad_, wa, alpha, mmax);
    k_alpha_self<<<(NN+255)/256, 256, 0, stream>>>(loop3, as_, ad_, wa, aself, mmax);
    k_p_edge<<<(NE+255)/256, 256, 0, stream>>>(dst, mmax, alpha, denom);
    k_p_self<<<(NN+255)/256, 256, 0, stream>>>(mmax, aself, denom);
    k_agg_edge<<<NE/4, 256, 0, stream>>>(src, dst, alpha, denom, xl, hc);
    k_finalize<<<NN, 256, 0, stream>>>(hc, xl, aself, denom, bias, l, h, hbf,
                                       (l < NLAY-1) ? 1 : 0, flag);
  }

  (void)hipMemsetAsync(hg, 0, (size_t)NG*EMBD*4, stream);
  (void)hipMemsetAsync(cnt, 0, (size_t)NG*4, stream);
  k_pool<<<NN/4, 256, 0, stream>>>(h, batch, hg, cnt);
  k_head_v<<<1, 256, 0, stream>>>(W1, b1, W2, b2, vvec, c0, flag);
  k_head_out<<<NG, 64, 0, stream>>>(hg, cnt, vvec, c0, d_out, flag);
}

// Round 8
// 1295.401 us; speedup vs baseline: 4.6552x; 4.6552x over previous
//
#include <hip/hip_runtime.h>
#include <hip/hip_bf16.h>

#define NN   30000
#define NE   480000
#define EMBD 256
#define NG   512
#define NLAY 3
#define LEAK 0.2f

typedef __attribute__((ext_vector_type(8))) short bf16x8;
typedef __attribute__((ext_vector_type(4))) float f32x4;
typedef __attribute__((ext_vector_type(4))) unsigned short us4;

__device__ __forceinline__ float bf2f(unsigned short u) {
  union { unsigned int i; float f; } v; v.i = ((unsigned int)u) << 16; return v.f;
}
__device__ __forceinline__ unsigned short f2bf(float f) {
  union { float f; unsigned int i; } v; v.f = f;
  unsigned int u = v.i;
  u += 0x7fffu + ((u >> 16) & 1u);
  return (unsigned short)(u >> 16);
}
__device__ __forceinline__ float rdw(const void* p, size_t i, int f32) {
  return f32 ? ((const float*)p)[i] : bf2f(((const unsigned short*)p)[i]);
}
__device__ __forceinline__ void atomic_max_f32(float* addr, float val) {
  int* ia = (int*)addr;
  int cur = *ia;
  while (__int_as_float(cur) < val) {
    int assumed = cur;
    cur = atomicCAS(ia, assumed, __float_as_int(val));
    if (cur == assumed) break;
  }
}

// ---------------- dtype sniff ----------------
__global__ void k_sniff(const unsigned short* __restrict__ w, int* flag) {
  __shared__ int cnt;
  if (threadIdx.x == 0) cnt = 0;
  __syncthreads();
  int local = 0;
  for (int i = threadIdx.x * 2; i < 65536; i += 512) {
    unsigned short u = w[i];
    if (((u >> 7) & 0xFF) == 0xFF) local++;
  }
  atomicAdd(&cnt, local);
  __syncthreads();
  if (threadIdx.x == 0) *flag = (cnt >= 4) ? 1 : 0;
}

// ---------------- CSR build (once; graph static across layers) ----------------

__global__ void k_hist(const int* __restrict__ dst, int* cnt_i) {
  int e = blockIdx.x * 256 + threadIdx.x;
  if (e >= NE) return;
  atomicAdd(&cnt_i[dst[e]], 1);
}

// single-block exclusive scan over NN counts -> row_ptr[NN+1], cursor copy
__global__ __launch_bounds__(1024) void k_scan(const int* __restrict__ cnt_i,
                                               int* row_ptr, int* cursor) {
  __shared__ int part[1024];
  const int CH = (NN + 1023) / 1024;   // 30
  int t = threadIdx.x;
  int base = t * CH;
  int s = 0;
  for (int i = 0; i < CH; ++i) { int idx = base + i; if (idx < NN) s += cnt_i[idx]; }
  part[t] = s;
  __syncthreads();
  for (int off = 1; off < 1024; off <<= 1) {
    int tmp = (t >= off) ? part[t - off] : 0;
    __syncthreads();
    part[t] += tmp;
    __syncthreads();
  }
  int run = part[t] - s;   // exclusive prefix for this thread's chunk
  for (int i = 0; i < CH; ++i) {
    int idx = base + i;
    if (idx < NN) { row_ptr[idx] = run; cursor[idx] = run; run += cnt_i[idx]; }
  }
  if (t == 1023) row_ptr[NN] = run;    // == NE
}

__global__ void k_fill(const int* __restrict__ src, const int* __restrict__ dst,
                       int* cursor, int* col_src, int* col_eid) {
  int e = blockIdx.x * 256 + threadIdx.x;
  if (e >= NE) return;
  int pos = atomicAdd(&cursor[dst[e]], 1);
  col_src[pos] = src[e];
  col_eid[pos] = e;
}

// ---------------- setup kernels ----------------

__global__ void k_transpose_w(const void* __restrict__ W, unsigned short* __restrict__ Wt,
                              const int* __restrict__ flagp) {
  int f32 = *flagp;
  int t = blockIdx.x * 256 + threadIdx.x;
  int l = t >> 16;
  int k = (t >> 8) & 255;
  int c = t & 255;
  Wt[(l << 16) + (c << 8) + k] = f2bf(rdw(W, t, f32));
}

__global__ void k_atom_enc(const int* __restrict__ x, const void* __restrict__ emb,
                           float* __restrict__ h, unsigned short* __restrict__ hbf,
                           const int* __restrict__ flagp) {
  int f32 = *flagp;
  int n = blockIdx.x, c = threadIdx.x;
  float s = 0.f;
  #pragma unroll
  for (int i = 0; i < 9; ++i) {
    int xi = x[n * 9 + i];
    s += rdw(emb, (size_t)(i * 128 + xi) * 256 + c, f32);
  }
  h[n * 256 + c] = s;
  hbf[n * 256 + c] = f2bf(s);
}

// ---------------- per-layer kernels ----------------

__global__ void k_init_layer(float* mmax, float* denom,
                             float* wa, const void* __restrict__ We,
                             const void* __restrict__ ae, int l,
                             const int* __restrict__ flagp) {
  int t = blockIdx.x * 256 + threadIdx.x;
  if (t < NN) { mmax[t] = -1e30f; denom[t] = 0.f; }
  if (blockIdx.x == 0 && t < 3) {
    int f32 = *flagp;
    float s = 0.f;
    for (int c = 0; c < 256; ++c)
      s += rdw(We, (size_t)l*3*256 + t*256 + c, f32) * rdw(ae, (size_t)l*256 + c, f32);
    wa[t] = s;
  }
}

// e_enc only (loop_attr now via CSR)
__global__ void k_bond_enc(const int* __restrict__ eattr, const void* __restrict__ bemb,
                           int l, float* __restrict__ e_enc, const int* __restrict__ flagp) {
  int f32 = *flagp;
  int e = blockIdx.x * 256 + threadIdx.x;
  if (e >= NE) return;
  float v0 = 0.f, v1 = 0.f, v2 = 0.f;
  #pragma unroll
  for (int t = 0; t < 3; ++t) {
    int a = eattr[e*3 + t];
    size_t base = (size_t)l*144 + (size_t)(t*16 + a)*3;
    v0 += rdw(bemb, base+0, f32);
    v1 += rdw(bemb, base+1, f32);
    v2 += rdw(bemb, base+2, f32);
  }
  e_enc[e*3] = v0; e_enc[e*3+1] = v1; e_enc[e*3+2] = v2;
}

// loop_attr[n] = mean of incoming e_enc (0 if none) via CSR
__global__ void k_loop_csr(const int* __restrict__ row_ptr, const int* __restrict__ col_eid,
                           const float* __restrict__ e_enc, float* __restrict__ loop3) {
  int n = blockIdx.x * 256 + threadIdx.x;
  if (n >= NN) return;
  int beg = row_ptr[n], end = row_ptr[n+1];
  float v0 = 0.f, v1 = 0.f, v2 = 0.f;
  for (int j = beg; j < end; ++j) {
    int e = col_eid[j];
    v0 += e_enc[e*3]; v1 += e_enc[e*3+1]; v2 += e_enc[e*3+2];
  }
  float inv = 1.f / fmaxf((float)(end - beg), 1.f);
  loop3[n*3] = v0*inv; loop3[n*3+1] = v1*inv; loop3[n*3+2] = v2*inv;
}

// xl = h_bf16 @ W[l]
__global__ __launch_bounds__(256) void k_gemm_xl(const unsigned short* __restrict__ A,
                                                 const unsigned short* __restrict__ Bt,
                                                 float* __restrict__ C) {
  int wid  = blockIdx.x * 4 + (threadIdx.x >> 6);
  int lane = threadIdx.x & 63;
  int m0 = (wid >> 2) * 16;
  int c0 = (wid & 3) * 64;
  int lr = lane & 15;
  int lk = (lane >> 4) * 8;
  f32x4 acc0 = {0.f,0.f,0.f,0.f}, acc1 = {0.f,0.f,0.f,0.f};
  f32x4 acc2 = {0.f,0.f,0.f,0.f}, acc3 = {0.f,0.f,0.f,0.f};
  const unsigned short* arow = A  + (size_t)(m0 + lr) * 256 + lk;
  const unsigned short* b0   = Bt + (size_t)(c0 + lr) * 256 + lk;
  #pragma unroll
  for (int k = 0; k < 256; k += 32) {
    bf16x8 a = *(const bf16x8*)(arow + k);
    acc0 = __builtin_amdgcn_mfma_f32_16x16x32_bf16(a, *(const bf16x8*)(b0 + k),          acc0, 0,0,0);
    acc1 = __builtin_amdgcn_mfma_f32_16x16x32_bf16(a, *(const bf16x8*)(b0 + 16*256 + k), acc1, 0,0,0);
    acc2 = __builtin_amdgcn_mfma_f32_16x16x32_bf16(a, *(const bf16x8*)(b0 + 32*256 + k), acc2, 0,0,0);
    acc3 = __builtin_amdgcn_mfma_f32_16x16x32_bf16(a, *(const bf16x8*)(b0 + 48*256 + k), acc3, 0,0,0);
  }
  float* crow = C + (size_t)(m0 + (lane >> 4) * 4) * 256 + c0 + lr;
  #pragma unroll
  for (int r = 0; r < 4; ++r) {
    crow[r*256 +  0] = acc0[r];
    crow[r*256 + 16] = acc1[r];
    crow[r*256 + 32] = acc2[r];
    crow[r*256 + 48] = acc3[r];
  }
}

__global__ void k_node_dots(const float* __restrict__ xl, const void* __restrict__ as_w,
                            const void* __restrict__ ad_w, int l,
                            float* __restrict__ as_, float* __restrict__ ad_,
                            const int* __restrict__ flagp) {
  int f32 = *flagp;
  int n = blockIdx.x;
  int lane = threadIdx.x;
  float s = 0.f, d = 0.f;
  #pragma unroll
  for (int c = lane; c < 256; c += 64) {
    float xv = xl[n*256 + c];
    s += xv * rdw(as_w, (size_t)l*256 + c, f32);
    d += xv * rdw(ad_w, (size_t)l*256 + c, f32);
  }
  #pragma unroll
  for (int o = 32; o > 0; o >>= 1) { s += __shfl_down(s, o); d += __shfl_down(d, o); }
  if (lane == 0) { as_[n] = s; ad_[n] = d; }
}

__global__ void k_alpha_edge(const int* __restrict__ src, const int* __restrict__ dst,
                             const float* __restrict__ e_enc, const float* __restrict__ as_,
                             const float* __restrict__ ad_, const float* __restrict__ wa,
                             float* __restrict__ alpha, float* mmax) {
  int e = blockIdx.x * 256 + threadIdx.x;
  if (e >= NE) return;
  int d = dst[e];
  float a = as_[src[e]] + ad_[d]
          + e_enc[e*3]*wa[0] + e_enc[e*3+1]*wa[1] + e_enc[e*3+2]*wa[2];
  a = (a >= 0.f) ? a : LEAK * a;
  alpha[e] = a;
  atomic_max_f32(&mmax[d], a);
}

__global__ void k_alpha_self(const float* __restrict__ loop3, const float* __restrict__ as_,
                             const float* __restrict__ ad_, const float* __restrict__ wa,
                             float* __restrict__ aself, float* mmax) {
  int n = blockIdx.x * 256 + threadIdx.x;
  if (n >= NN) return;
  float a = as_[n] + ad_[n]
          + loop3[n*3]*wa[0] + loop3[n*3+1]*wa[1] + loop3[n*3+2]*wa[2];
  a = (a >= 0.f) ? a : LEAK * a;
  aself[n] = a;
  atomic_max_f32(&mmax[n], a);
}

__global__ void k_p_edge(const int* __restrict__ dst, const float* __restrict__ mmax,
                         float* __restrict__ alpha, float* denom) {
  int e = blockIdx.x * 256 + threadIdx.x;
  if (e >= NE) return;
  int d = dst[e];
  float p = __expf(alpha[e] - mmax[d]);
  alpha[e] = p;
  unsafeAtomicAdd(&denom[d], p);
}

__global__ void k_p_self(const float* __restrict__ mmax, float* __restrict__ aself, float* denom) {
  int n = blockIdx.x * 256 + threadIdx.x;
  if (n >= NN) return;
  float p = __expf(aself[n] - mmax[n]);
  aself[n] = p;
  unsafeAtomicAdd(&denom[n], p);
}

// CSR gather-aggregate, fused with finalize (self-loop + bias + relu + residual)
__global__ __launch_bounds__(256) void k_agg_csr(const int* __restrict__ row_ptr,
                                                 const int* __restrict__ col_src,
                                                 const int* __restrict__ col_eid,
                                                 const float* __restrict__ p,
                                                 const float* __restrict__ denom,
                                                 const float* __restrict__ aself,
                                                 const float* __restrict__ xl,
                                                 const void* __restrict__ bias, int l,
                                                 float* __restrict__ h,
                                                 unsigned short* __restrict__ hbf,
                                                 int do_relu, const int* __restrict__ flagp) {
  int n = blockIdx.x * 4 + (threadIdx.x >> 6);   // 7500 blocks x 4 waves, NN exact
  int lane = threadIdx.x & 63;
  int beg = row_ptr[n], end = row_ptr[n+1];
  float inv_d = 1.f / denom[n];
  float ax = 0.f, ay = 0.f, az = 0.f, aw = 0.f;
  for (int j = beg; j < end; ++j) {
    int s = col_src[j];
    float w = p[col_eid[j]] * inv_d;
    float4 xv = *(const float4*)(xl + (size_t)s*256 + lane*4);
    ax += w*xv.x; ay += w*xv.y; az += w*xv.z; aw += w*xv.w;
  }
  // self loop
  {
    float w = aself[n] * inv_d;
    float4 xv = *(const float4*)(xl + (size_t)n*256 + lane*4);
    ax += w*xv.x; ay += w*xv.y; az += w*xv.z; aw += w*xv.w;
  }
  int f32 = *flagp;
  int c0 = lane*4;
  float b0 = rdw(bias, (size_t)l*256 + c0+0, f32);
  float b1 = rdw(bias, (size_t)l*256 + c0+1, f32);
  float b2 = rdw(bias, (size_t)l*256 + c0+2, f32);
  float b3 = rdw(bias, (size_t)l*256 + c0+3, f32);
  ax += b0; ay += b1; az += b2; aw += b3;
  if (do_relu) {
    ax = fmaxf(ax, 0.f); ay = fmaxf(ay, 0.f);
    az = fmaxf(az, 0.f); aw = fmaxf(aw, 0.f);
  }
  float* hp = h + (size_t)n*256 + c0;
  float4 hv = *(const float4*)hp;
  float h0 = ax + hv.x, h1 = ay + hv.y, h2 = az + hv.z, h3 = aw + hv.w;
  *(float4*)hp = make_float4(h0, h1, h2, h3);
  us4 q = { f2bf(h0), f2bf(h1), f2bf(h2), f2bf(h3) };
  *(us4*)(hbf + (size_t)n*256 + c0) = q;
}

// ---------------- pooling + head ----------------

__global__ void k_pool(const float* __restrict__ h, const int* __restrict__ batch,
                       float* hg, float* cnt) {
  int t = blockIdx.x * 256 + threadIdx.x;
  int n = t >> 6;
  if (n >= NN) return;
  int lane = t & 63;
  int b = batch[n];
  float4 v = *(const float4*)(h + (size_t)n*256 + lane*4);
  float* o = hg + (size_t)b*256 + lane*4;
  unsafeAtomicAdd(o+0, v.x);
  unsafeAtomicAdd(o+1, v.y);
  unsafeAtomicAdd(o+2, v.z);
  unsafeAtomicAdd(o+3, v.w);
  if (lane == 0) unsafeAtomicAdd(&cnt[b], 1.f);
}

__global__ void k_head_v(const void* __restrict__ W1, const void* __restrict__ b1,
                         const void* __restrict__ W2, const void* __restrict__ b2,
                         float* __restrict__ v, float* __restrict__ c0,
                         const int* __restrict__ flagp) {
  int f32 = *flagp;
  int k = threadIdx.x;
  float s = 0.f;
  for (int c = 0; c < 256; ++c) s += rdw(W1, (size_t)k*256 + c, f32) * rdw(W2, c, f32);
  v[k] = s;
  if (k == 0) {
    float t = 0.f;
    for (int c = 0; c < 256; ++c) t += rdw(b1, c, f32) * rdw(W2, c, f32);
    *c0 = t + rdw(b2, 0, f32);
  }
}

__global__ void k_head_out(const float* __restrict__ hg, const float* __restrict__ cnt,
                           const float* __restrict__ v, const float* __restrict__ c0,
                           void* __restrict__ out, const int* __restrict__ flagp) {
  int g = blockIdx.x;
  int lane = threadIdx.x;
  float s = 0.f;
  #pragma unroll
  for (int c = lane; c < 256; c += 64) s += hg[g*256 + c] * v[c];
  #pragma unroll
  for (int o = 32; o > 0; o >>= 1) s += __shfl_down(s, o);
  if (lane == 0) {
    float inv = 1.f / fmaxf(cnt[g], 1.f);
    float val = s * inv + *c0;
    if (*flagp) ((float*)out)[g] = val;
    else        ((unsigned short*)out)[g] = f2bf(val);
  }
}

extern "C" void kernel_launch(void* const* d_in, const int* in_sizes, int n_in,
                              void* d_out, int out_size, void* d_ws, size_t ws_size,
                              hipStream_t stream) {
  const int* x     = (const int*)d_in[0];
  const int* eidx  = (const int*)d_in[1];
  const int* eattr = (const int*)d_in[2];
  const int* batch = (const int*)d_in[3];
  const void* atom_emb = d_in[4];
  const void* bond_emb = d_in[5];
  const void* W        = d_in[6];
  const void* att_src  = d_in[7];
  const void* att_dst  = d_in[8];
  const void* We       = d_in[9];
  const void* att_edge = d_in[10];
  const void* bias     = d_in[11];
  const void* W1 = d_in[12];
  const void* b1 = d_in[13];
  const void* W2 = d_in[14];
  const void* b2 = d_in[15];

  const int* src = eidx;
  const int* dst = eidx + NE;

  char* base = (char*)d_ws;
  size_t off = 0;
  auto alloc = [&](size_t bytes) -> char* {
    char* p = base + off; off += (bytes + 255) & ~(size_t)255; return p;
  };
  float* h    = (float*)alloc((size_t)NN*EMBD*4);
  float* xl   = (float*)alloc((size_t)NN*EMBD*4);
  unsigned short* hbf = (unsigned short*)alloc((size_t)NN*EMBD*2);
  unsigned short* wt  = (unsigned short*)alloc((size_t)NLAY*EMBD*EMBD*2);
  float* e_enc = (float*)alloc((size_t)NE*3*4);
  float* alpha = (float*)alloc((size_t)NE*4);
  float* loop3 = (float*)alloc((size_t)NN*3*4);
  float* as_   = (float*)alloc((size_t)NN*4);
  float* ad_   = (float*)alloc((size_t)NN*4);
  float* mmax  = (float*)alloc((size_t)NN*4);
  float* denom = (float*)alloc((size_t)NN*4);
  float* aself = (float*)alloc((size_t)NN*4);
  float* hg    = (float*)alloc((size_t)NG*EMBD*4);
  float* cnt   = (float*)alloc((size_t)NG*4);
  float* vvec  = (float*)alloc((size_t)EMBD*4);
  float* c0    = (float*)alloc(4);
  float* wa    = (float*)alloc(16);
  int*   flag  = (int*)alloc(4);
  // CSR
  int* cnt_i   = (int*)alloc((size_t)NN*4);
  int* row_ptr = (int*)alloc((size_t)(NN+1)*4);
  int* cursor  = (int*)alloc((size_t)NN*4);
  int* col_src = (int*)alloc((size_t)NE*4);
  int* col_eid = (int*)alloc((size_t)NE*4);

  // dtype sniff + CSR build (graph static across layers)
  k_sniff<<<1, 256, 0, stream>>>((const unsigned short*)atom_emb, flag);
  (void)hipMemsetAsync(cnt_i, 0, (size_t)NN*4, stream);
  k_hist<<<(NE+255)/256, 256, 0, stream>>>(dst, cnt_i);
  k_scan<<<1, 1024, 0, stream>>>(cnt_i, row_ptr, cursor);
  k_fill<<<(NE+255)/256, 256, 0, stream>>>(src, dst, cursor, col_src, col_eid);

  k_transpose_w<<<NLAY*EMBD*EMBD/256, 256, 0, stream>>>(W, wt, flag);
  k_atom_enc<<<NN, 256, 0, stream>>>(x, atom_emb, h, hbf, flag);

  for (int l = 0; l < NLAY; ++l) {
    k_init_layer<<<(NN+255)/256, 256, 0, stream>>>(mmax, denom, wa, We, att_edge, l, flag);
    k_bond_enc<<<(NE+255)/256, 256, 0, stream>>>(eattr, bond_emb, l, e_enc, flag);
    k_loop_csr<<<(NN+255)/256, 256, 0, stream>>>(row_ptr, col_eid, e_enc, loop3);
    k_gemm_xl<<<(NN/16)*(EMBD/64)/4, 256, 0, stream>>>(hbf, wt + (size_t)l*EMBD*EMBD, xl);
    k_node_dots<<<NN, 64, 0, stream>>>(xl, att_src, att_dst, l, as_, ad_, flag);
    k_alpha_edge<<<(NE+255)/256, 256, 0, stream>>>(src, dst, e_enc, as_, ad_, wa, alpha, mmax);
    k_alpha_self<<<(NN+255)/256, 256, 0, stream>>>(loop3, as_, ad_, wa, aself, mmax);
    k_p_edge<<<(NE+255)/256, 256, 0, stream>>>(dst, mmax, alpha, denom);
    k_p_self<<<(NN+255)/256, 256, 0, stream>>>(mmax, aself, denom);
    k_agg_csr<<<NN/4, 256, 0, stream>>>(row_ptr, col_src, col_eid, alpha, denom, aself,
                                        xl, bias, l, h, hbf, (l < NLAY-1) ? 1 : 0, flag);
  }

  (void)hipMemsetAsync(hg, 0, (size_t)NG*EMBD*4, stream);
  (void)hipMemsetAsync(cnt, 0, (size_t)NG*4, stream);
  k_pool<<<NN/4, 256, 0, stream>>>(h, batch, hg, cnt);
  k_head_v<<<1, 256, 0, stream>>>(W1, b1, W2, b2, vvec, c0, flag);
  k_head_out<<<NG, 64, 0, stream>>>(hg, cnt, vvec, c0, d_out, flag);
}

// Round 9
// 741.747 us; speedup vs baseline: 8.1300x; 1.7464x over previous
//
#include <hip/hip_runtime.h>
#include <hip/hip_bf16.h>

#define NN   30000
#define NE   480000
#define EMBD 256
#define NG   512
#define NLAY 3
#define LEAK 0.2f

typedef __attribute__((ext_vector_type(8))) short bf16x8;
typedef __attribute__((ext_vector_type(4))) float f32x4;
typedef __attribute__((ext_vector_type(4))) unsigned short us4;

__device__ __forceinline__ float bf2f(unsigned short u) {
  union { unsigned int i; float f; } v; v.i = ((unsigned int)u) << 16; return v.f;
}
__device__ __forceinline__ unsigned short f2bf(float f) {
  union { float f; unsigned int i; } v; v.f = f;
  unsigned int u = v.i;
  u += 0x7fffu + ((u >> 16) & 1u);
  return (unsigned short)(u >> 16);
}
__device__ __forceinline__ float rdw(const void* p, size_t i, int f32) {
  return f32 ? ((const float*)p)[i] : bf2f(((const unsigned short*)p)[i]);
}

// ---------------- dtype sniff ----------------
__global__ void k_sniff(const unsigned short* __restrict__ w, int* flag) {
  __shared__ int cnt;
  if (threadIdx.x == 0) cnt = 0;
  __syncthreads();
  int local = 0;
  for (int i = threadIdx.x * 2; i < 65536; i += 512) {
    unsigned short u = w[i];
    if (((u >> 7) & 0xFF) == 0xFF) local++;
  }
  atomicAdd(&cnt, local);
  __syncthreads();
  if (threadIdx.x == 0) *flag = (cnt >= 4) ? 1 : 0;
}

// ---------------- CSR build (once; graph static across layers) ----------------

__global__ void k_hist(const int* __restrict__ dst, int* cnt_i) {
  int e = blockIdx.x * 256 + threadIdx.x;
  if (e >= NE) return;
  atomicAdd(&cnt_i[dst[e]], 1);
}

__global__ __launch_bounds__(1024) void k_scan(const int* __restrict__ cnt_i,
                                               int* row_ptr, int* cursor) {
  __shared__ int part[1024];
  const int CH = (NN + 1023) / 1024;   // 30
  int t = threadIdx.x;
  int base = t * CH;
  int s = 0;
  for (int i = 0; i < CH; ++i) { int idx = base + i; if (idx < NN) s += cnt_i[idx]; }
  part[t] = s;
  __syncthreads();
  for (int off = 1; off < 1024; off <<= 1) {
    int tmp = (t >= off) ? part[t - off] : 0;
    __syncthreads();
    part[t] += tmp;
    __syncthreads();
  }
  int run = part[t] - s;
  for (int i = 0; i < CH; ++i) {
    int idx = base + i;
    if (idx < NN) { row_ptr[idx] = run; cursor[idx] = run; run += cnt_i[idx]; }
  }
  if (t == 1023) row_ptr[NN] = run;
}

__global__ void k_fill(const int* __restrict__ src, const int* __restrict__ dst,
                       int* cursor, int* col_src, int* col_eid) {
  int e = blockIdx.x * 256 + threadIdx.x;
  if (e >= NE) return;
  int pos = atomicAdd(&cursor[dst[e]], 1);
  col_src[pos] = src[e];
  col_eid[pos] = e;
}

// ---------------- setup kernels ----------------

__global__ void k_transpose_w(const void* __restrict__ W, unsigned short* __restrict__ Wt,
                              const int* __restrict__ flagp) {
  int f32 = *flagp;
  int t = blockIdx.x * 256 + threadIdx.x;
  int l = t >> 16;
  int k = (t >> 8) & 255;
  int c = t & 255;
  Wt[(l << 16) + (c << 8) + k] = f2bf(rdw(W, t, f32));
}

__global__ void k_atom_enc(const int* __restrict__ x, const void* __restrict__ emb,
                           float* __restrict__ h, unsigned short* __restrict__ hbf,
                           const int* __restrict__ flagp) {
  int f32 = *flagp;
  int n = blockIdx.x, c = threadIdx.x;
  float s = 0.f;
  #pragma unroll
  for (int i = 0; i < 9; ++i) {
    int xi = x[n * 9 + i];
    s += rdw(emb, (size_t)(i * 128 + xi) * 256 + c, f32);
  }
  h[n * 256 + c] = s;
  hbf[n * 256 + c] = f2bf(s);
}

// wa_all[l*3+j] = sum_c We[l,j,c] * att_edge[l,c]   (all 3 layers, once)
__global__ void k_wa(const void* __restrict__ We, const void* __restrict__ ae,
                     float* __restrict__ wa_all, const int* __restrict__ flagp) {
  int t = threadIdx.x;
  if (t >= 9) return;
  int f32 = *flagp;
  int l = t / 3, j = t % 3;
  float s = 0.f;
  for (int c = 0; c < 256; ++c)
    s += rdw(We, (size_t)l*768 + j*256 + c, f32) * rdw(ae, (size_t)l*256 + c, f32);
  wa_all[t] = s;
}

// we_csr[l][j] = e_enc(eid(j)) . wa[l]  for all 3 layers, CSR edge order
__global__ void k_bond_we(const int* __restrict__ eattr, const int* __restrict__ col_eid,
                          const void* __restrict__ bemb, const float* __restrict__ wa_all,
                          float* __restrict__ we_csr, const int* __restrict__ flagp) {
  int j = blockIdx.x * 256 + threadIdx.x;
  if (j >= NE) return;
  int f32 = *flagp;
  int e = col_eid[j];
  int a0 = eattr[e*3], a1 = eattr[e*3+1], a2 = eattr[e*3+2];
  #pragma unroll
  for (int l = 0; l < NLAY; ++l) {
    size_t lb = (size_t)l * 144;
    float e0 = rdw(bemb, lb + (0*16+a0)*3+0, f32) + rdw(bemb, lb + (1*16+a1)*3+0, f32)
             + rdw(bemb, lb + (2*16+a2)*3+0, f32);
    float e1 = rdw(bemb, lb + (0*16+a0)*3+1, f32) + rdw(bemb, lb + (1*16+a1)*3+1, f32)
             + rdw(bemb, lb + (2*16+a2)*3+1, f32);
    float e2 = rdw(bemb, lb + (0*16+a0)*3+2, f32) + rdw(bemb, lb + (1*16+a1)*3+2, f32)
             + rdw(bemb, lb + (2*16+a2)*3+2, f32);
    we_csr[(size_t)l*NE + j] = e0*wa_all[l*3+0] + e1*wa_all[l*3+1] + e2*wa_all[l*3+2];
  }
}

// ---------------- per-layer kernels ----------------

// xl = h_bf16 @ W[l]
__global__ __launch_bounds__(256) void k_gemm_xl(const unsigned short* __restrict__ A,
                                                 const unsigned short* __restrict__ Bt,
                                                 float* __restrict__ C) {
  int wid  = blockIdx.x * 4 + (threadIdx.x >> 6);
  int lane = threadIdx.x & 63;
  int m0 = (wid >> 2) * 16;
  int c0 = (wid & 3) * 64;
  int lr = lane & 15;
  int lk = (lane >> 4) * 8;
  f32x4 acc0 = {0.f,0.f,0.f,0.f}, acc1 = {0.f,0.f,0.f,0.f};
  f32x4 acc2 = {0.f,0.f,0.f,0.f}, acc3 = {0.f,0.f,0.f,0.f};
  const unsigned short* arow = A  + (size_t)(m0 + lr) * 256 + lk;
  const unsigned short* b0   = Bt + (size_t)(c0 + lr) * 256 + lk;
  #pragma unroll
  for (int k = 0; k < 256; k += 32) {
    bf16x8 a = *(const bf16x8*)(arow + k);
    acc0 = __builtin_amdgcn_mfma_f32_16x16x32_bf16(a, *(const bf16x8*)(b0 + k),          acc0, 0,0,0);
    acc1 = __builtin_amdgcn_mfma_f32_16x16x32_bf16(a, *(const bf16x8*)(b0 + 16*256 + k), acc1, 0,0,0);
    acc2 = __builtin_amdgcn_mfma_f32_16x16x32_bf16(a, *(const bf16x8*)(b0 + 32*256 + k), acc2, 0,0,0);
    acc3 = __builtin_amdgcn_mfma_f32_16x16x32_bf16(a, *(const bf16x8*)(b0 + 48*256 + k), acc3, 0,0,0);
  }
  float* crow = C + (size_t)(m0 + (lane >> 4) * 4) * 256 + c0 + lr;
  #pragma unroll
  for (int r = 0; r < 4; ++r) {
    crow[r*256 +  0] = acc0[r];
    crow[r*256 + 16] = acc1[r];
    crow[r*256 + 32] = acc2[r];
    crow[r*256 + 48] = acc3[r];
  }
}

__global__ void k_node_dots(const float* __restrict__ xl, const void* __restrict__ as_w,
                            const void* __restrict__ ad_w, int l,
                            float* __restrict__ as_, float* __restrict__ ad_,
                            const int* __restrict__ flagp) {
  int f32 = *flagp;
  int n = blockIdx.x;
  int lane = threadIdx.x;
  float s = 0.f, d = 0.f;
  #pragma unroll
  for (int c = lane; c < 256; c += 64) {
    float xv = xl[n*256 + c];
    s += xv * rdw(as_w, (size_t)l*256 + c, f32);
    d += xv * rdw(ad_w, (size_t)l*256 + c, f32);
  }
  #pragma unroll
  for (int o = 32; o > 0; o >>= 1) { s += __shfl_down(s, o); d += __shfl_down(d, o); }
  if (lane == 0) { as_[n] = s; ad_[n] = d; }
}

// fused per-node: online segment-softmax over CSR edges + self-loop +
// weighted aggregation + bias + relu + residual + bf16 recast.
__global__ __launch_bounds__(256) void k_fused(const int* __restrict__ row_ptr,
                                               const int* __restrict__ col_src,
                                               const float* __restrict__ we_csr,
                                               const float* __restrict__ as_,
                                               const float* __restrict__ ad_,
                                               const float* __restrict__ xl,
                                               const void* __restrict__ bias, int l,
                                               float* __restrict__ h,
                                               unsigned short* __restrict__ hbf,
                                               int do_relu, const int* __restrict__ flagp) {
  int n = blockIdx.x * 4 + (threadIdx.x >> 6);   // wave per node, NN = 7500*4 exact
  int lane = threadIdx.x & 63;
  int beg = row_ptr[n], end = row_ptr[n+1];
  int deg = end - beg;
  float ad_n = ad_[n];

  float m = -1e30f, dsum = 0.f, wesum = 0.f;
  float ax = 0.f, ay = 0.f, az = 0.f, aw = 0.f;

  for (int cb = beg; cb < end; cb += 64) {
    int j = cb + lane;
    bool valid = (j < end);
    int s = valid ? col_src[j] : 0;
    float we = valid ? we_csr[j] : 0.f;
    wesum += we;
    float a;
    if (valid) {
      a = as_[s] + ad_n + we;
      a = (a >= 0.f) ? a : LEAK * a;
    } else {
      a = -1e30f;
    }
    // chunk max
    float cm = a;
    #pragma unroll
    for (int o = 32; o > 0; o >>= 1) cm = fmaxf(cm, __shfl_xor(cm, o));
    float m_new = fmaxf(m, cm);
    float r = __expf(m - m_new);
    float p = valid ? __expf(a - m_new) : 0.f;
    float cs = p;
    #pragma unroll
    for (int o = 32; o > 0; o >>= 1) cs += __shfl_xor(cs, o);
    dsum = dsum * r + cs;
    ax *= r; ay *= r; az *= r; aw *= r;
    m = m_new;
    int cl = end - cb; if (cl > 64) cl = 64;
    for (int jj = 0; jj < cl; ++jj) {
      float w  = __shfl(p, jj);
      int   ss = __shfl(s, jj);
      float4 xv = *(const float4*)(xl + (size_t)ss*256 + lane*4);
      ax += w*xv.x; ay += w*xv.y; az += w*xv.z; aw += w*xv.w;
    }
  }
  // total we sum across lanes (covers all chunks)
  #pragma unroll
  for (int o = 32; o > 0; o >>= 1) wesum += __shfl_xor(wesum, o);

  // self loop: loop_attr . wa == (sum we)/clip(deg,1)
  float a_self = as_[n] + ad_n + wesum / fmaxf((float)deg, 1.f);
  a_self = (a_self >= 0.f) ? a_self : LEAK * a_self;
  float m_f = fmaxf(m, a_self);
  float r = __expf(m - m_f);
  float p_self = __expf(a_self - m_f);
  dsum = dsum * r + p_self;
  ax *= r; ay *= r; az *= r; aw *= r;
  {
    float4 xv = *(const float4*)(xl + (size_t)n*256 + lane*4);
    ax += p_self*xv.x; ay += p_self*xv.y; az += p_self*xv.z; aw += p_self*xv.w;
  }
  float inv_d = 1.f / dsum;
  ax *= inv_d; ay *= inv_d; az *= inv_d; aw *= inv_d;

  int f32 = *flagp;
  int c0 = lane * 4;
  ax += rdw(bias, (size_t)l*256 + c0+0, f32);
  ay += rdw(bias, (size_t)l*256 + c0+1, f32);
  az += rdw(bias, (size_t)l*256 + c0+2, f32);
  aw += rdw(bias, (size_t)l*256 + c0+3, f32);
  if (do_relu) {
    ax = fmaxf(ax, 0.f); ay = fmaxf(ay, 0.f);
    az = fmaxf(az, 0.f); aw = fmaxf(aw, 0.f);
  }
  float* hp = h + (size_t)n*256 + c0;
  float4 hv = *(const float4*)hp;
  float h0 = ax + hv.x, h1 = ay + hv.y, h2 = az + hv.z, h3 = aw + hv.w;
  *(float4*)hp = make_float4(h0, h1, h2, h3);
  us4 q = { f2bf(h0), f2bf(h1), f2bf(h2), f2bf(h3) };
  *(us4*)(hbf + (size_t)n*256 + c0) = q;
}

// ---------------- pooling + head (fused; batch is sorted) ----------------

__global__ void k_head_v(const void* __restrict__ W1, const void* __restrict__ b1,
                         const void* __restrict__ W2, const void* __restrict__ b2,
                         float* __restrict__ v, float* __restrict__ c0,
                         const int* __restrict__ flagp) {
  int f32 = *flagp;
  int k = threadIdx.x;
  float s = 0.f;
  for (int c = 0; c < 256; ++c) s += rdw(W1, (size_t)k*256 + c, f32) * rdw(W2, c, f32);
  v[k] = s;
  if (k == 0) {
    float t = 0.f;
    for (int c = 0; c < 256; ++c) t += rdw(b1, c, f32) * rdw(W2, c, f32);
    *c0 = t + rdw(b2, 0, f32);
  }
}

__global__ __launch_bounds__(256) void k_pool_head(const float* __restrict__ h,
                                                   const int* __restrict__ batch,
                                                   const float* __restrict__ v,
                                                   const float* __restrict__ c0,
                                                   void* __restrict__ out,
                                                   const int* __restrict__ flagp) {
  int g = blockIdx.x;
  // binary search group boundaries in sorted batch
  int lo = 0, hi = NN;
  while (lo < hi) { int mid = (lo + hi) >> 1; if (batch[mid] < g) lo = mid + 1; else hi = mid; }
  int start = lo;
  lo = 0; hi = NN;
  while (lo < hi) { int mid = (lo + hi) >> 1; if (batch[mid] < g + 1) lo = mid + 1; else hi = mid; }
  int endn = lo;

  int c = threadIdx.x;
  float s = 0.f;
  for (int n = start; n < endn; ++n) s += h[(size_t)n*256 + c];
  __shared__ float red[256];
  red[c] = s * v[c];
  __syncthreads();
  for (int off = 128; off > 0; off >>= 1) {
    if (c < off) red[c] += red[c + off];
    __syncthreads();
  }
  if (c == 0) {
    float cntf = (float)(endn - start);
    float val = red[0] / fmaxf(cntf, 1.f) + *c0;
    if (*flagp) ((float*)out)[g] = val;
    else        ((unsigned short*)out)[g] = f2bf(val);
  }
}

extern "C" void kernel_launch(void* const* d_in, const int* in_sizes, int n_in,
                              void* d_out, int out_size, void* d_ws, size_t ws_size,
                              hipStream_t stream) {
  const int* x     = (const int*)d_in[0];
  const int* eidx  = (const int*)d_in[1];
  const int* eattr = (const int*)d_in[2];
  const int* batch = (const int*)d_in[3];
  const void* atom_emb = d_in[4];
  const void* bond_emb = d_in[5];
  const void* W        = d_in[6];
  const void* att_src  = d_in[7];
  const void* att_dst  = d_in[8];
  const void* We       = d_in[9];
  const void* att_edge = d_in[10];
  const void* bias     = d_in[11];
  const void* W1 = d_in[12];
  const void* b1 = d_in[13];
  const void* W2 = d_in[14];
  const void* b2 = d_in[15];

  const int* src = eidx;
  const int* dst = eidx + NE;

  char* base = (char*)d_ws;
  size_t off = 0;
  auto alloc = [&](size_t bytes) -> char* {
    char* p = base + off; off += (bytes + 255) & ~(size_t)255; return p;
  };
  float* h    = (float*)alloc((size_t)NN*EMBD*4);
  float* xl   = (float*)alloc((size_t)NN*EMBD*4);
  unsigned short* hbf = (unsigned short*)alloc((size_t)NN*EMBD*2);
  unsigned short* wt  = (unsigned short*)alloc((size_t)NLAY*EMBD*EMBD*2);
  float* we_csr = (float*)alloc((size_t)NLAY*NE*4);
  float* as_   = (float*)alloc((size_t)NN*4);
  float* ad_   = (float*)alloc((size_t)NN*4);
  float* vvec  = (float*)alloc((size_t)EMBD*4);
  float* c0    = (float*)alloc(4);
  float* wa_all= (float*)alloc(64);
  int*   flag  = (int*)alloc(4);
  // CSR
  int* cnt_i   = (int*)alloc((size_t)NN*4);
  int* row_ptr = (int*)alloc((size_t)(NN+1)*4);
  int* cursor  = (int*)alloc((size_t)NN*4);
  int* col_src = (int*)alloc((size_t)NE*4);
  int* col_eid = (int*)alloc((size_t)NE*4);

  // setup: dtype sniff, CSR, weights, atom enc, edge scalars
  k_sniff<<<1, 256, 0, stream>>>((const unsigned short*)atom_emb, flag);
  (void)hipMemsetAsync(cnt_i, 0, (size_t)NN*4, stream);
  k_hist<<<(NE+255)/256, 256, 0, stream>>>(dst, cnt_i);
  k_scan<<<1, 1024, 0, stream>>>(cnt_i, row_ptr, cursor);
  k_fill<<<(NE+255)/256, 256, 0, stream>>>(src, dst, cursor, col_src, col_eid);
  k_transpose_w<<<NLAY*EMBD*EMBD/256, 256, 0, stream>>>(W, wt, flag);
  k_atom_enc<<<NN, 256, 0, stream>>>(x, atom_emb, h, hbf, flag);
  k_wa<<<1, 64, 0, stream>>>(We, att_edge, wa_all, flag);
  k_bond_we<<<(NE+255)/256, 256, 0, stream>>>(eattr, col_eid, bond_emb, wa_all, we_csr, flag);

  for (int l = 0; l < NLAY; ++l) {
    k_gemm_xl<<<(NN/16)*(EMBD/64)/4, 256, 0, stream>>>(hbf, wt + (size_t)l*EMBD*EMBD, xl);
    k_node_dots<<<NN, 64, 0, stream>>>(xl, att_src, att_dst, l, as_, ad_, flag);
    k_fused<<<NN/4, 256, 0, stream>>>(row_ptr, col_src, we_csr + (size_t)l*NE,
                                      as_, ad_, xl, bias, l, h, hbf,
                                      (l < NLAY-1) ? 1 : 0, flag);
  }

  k_head_v<<<1, 256, 0, stream>>>(W1, b1, W2, b2, vvec, c0, flag);
  k_pool_head<<<NG, 256, 0, stream>>>(h, batch, vvec, c0, d_out, flag);
}

// Round 11
// 640.815 us; speedup vs baseline: 9.4105x; 1.1575x over previous
//
#include <hip/hip_runtime.h>
#include <hip/hip_bf16.h>

#define NN   30000
#define NE   480000
#define EMBD 256
#define NG   512
#define NLAY 3
#define LEAK 0.2f

typedef __attribute__((ext_vector_type(8))) short bf16x8;
typedef __attribute__((ext_vector_type(4))) float f32x4;
typedef __attribute__((ext_vector_type(4))) unsigned short us4;
typedef __attribute__((ext_vector_type(8))) unsigned short us8;

__device__ __forceinline__ float bf2f(unsigned short u) {
  union { unsigned int i; float f; } v; v.i = ((unsigned int)u) << 16; return v.f;
}
__device__ __forceinline__ unsigned short f2bf(float f) {
  union { float f; unsigned int i; } v; v.f = f;
  unsigned int u = v.i;
  u += 0x7fffu + ((u >> 16) & 1u);
  return (unsigned short)(u >> 16);
}
__device__ __forceinline__ float rdw(const void* p, size_t i, int f32) {
  return f32 ? ((const float*)p)[i] : bf2f(((const unsigned short*)p)[i]);
}

// ---------------- dtype sniff ----------------
__global__ void k_sniff(const unsigned short* __restrict__ w, int* flag) {
  __shared__ int cnt;
  if (threadIdx.x == 0) cnt = 0;
  __syncthreads();
  int local = 0;
  for (int i = threadIdx.x * 2; i < 65536; i += 512) {
    unsigned short u = w[i];
    if (((u >> 7) & 0xFF) == 0xFF) local++;
  }
  atomicAdd(&cnt, local);
  __syncthreads();
  if (threadIdx.x == 0) *flag = (cnt >= 4) ? 1 : 0;
}

// ---------------- CSR build (once; graph static across layers) ----------------

__global__ void k_hist(const int* __restrict__ dst, int* cnt_i) {
  int e = blockIdx.x * 256 + threadIdx.x;
  if (e >= NE) return;
  atomicAdd(&cnt_i[dst[e]], 1);
}

__global__ __launch_bounds__(1024) void k_scan(const int* __restrict__ cnt_i,
                                               int* row_ptr, int* cursor) {
  __shared__ int part[1024];
  const int CH = (NN + 1023) / 1024;   // 30
  int t = threadIdx.x;
  int base = t * CH;
  int s = 0;
  for (int i = 0; i < CH; ++i) { int idx = base + i; if (idx < NN) s += cnt_i[idx]; }
  part[t] = s;
  __syncthreads();
  for (int off = 1; off < 1024; off <<= 1) {
    int tmp = (t >= off) ? part[t - off] : 0;
    __syncthreads();
    part[t] += tmp;
    __syncthreads();
  }
  int run = part[t] - s;
  for (int i = 0; i < CH; ++i) {
    int idx = base + i;
    if (idx < NN) { row_ptr[idx] = run; cursor[idx] = run; run += cnt_i[idx]; }
  }
  if (t == 1023) row_ptr[NN] = run;
}

__global__ void k_fill(const int* __restrict__ src, const int* __restrict__ dst,
                       int* cursor, int* col_src, int* col_eid) {
  int e = blockIdx.x * 256 + threadIdx.x;
  if (e >= NE) return;
  int pos = atomicAdd(&cursor[dst[e]], 1);
  col_src[pos] = src[e];
  col_eid[pos] = e;
}

// ---------------- setup kernels ----------------

__global__ void k_transpose_w(const void* __restrict__ W, unsigned short* __restrict__ Wt,
                              const int* __restrict__ flagp) {
  int f32 = *flagp;
  int t = blockIdx.x * 256 + threadIdx.x;
  int l = t >> 16;
  int k = (t >> 8) & 255;
  int c = t & 255;
  Wt[(l << 16) + (c << 8) + k] = f2bf(rdw(W, t, f32));
}

__global__ void k_atom_enc(const int* __restrict__ x, const void* __restrict__ emb,
                           float* __restrict__ h, unsigned short* __restrict__ hbf,
                           const int* __restrict__ flagp) {
  int f32 = *flagp;
  int n = blockIdx.x, c = threadIdx.x;
  float s = 0.f;
  #pragma unroll
  for (int i = 0; i < 9; ++i) {
    int xi = x[n * 9 + i];
    s += rdw(emb, (size_t)(i * 128 + xi) * 256 + c, f32);
  }
  h[n * 256 + c] = s;
  hbf[n * 256 + c] = f2bf(s);
}

// wa_all[l*3+j] = sum_c We[l,j,c] * att_edge[l,c]
__global__ void k_wa(const void* __restrict__ We, const void* __restrict__ ae,
                     float* __restrict__ wa_all, const int* __restrict__ flagp) {
  int t = threadIdx.x;
  if (t >= 9) return;
  int f32 = *flagp;
  int l = t / 3, j = t % 3;
  float s = 0.f;
  for (int c = 0; c < 256; ++c)
    s += rdw(We, (size_t)l*768 + j*256 + c, f32) * rdw(ae, (size_t)l*256 + c, f32);
  wa_all[t] = s;
}

// we_csr[l][j] = e_enc(eid(j)) . wa[l] for all layers, CSR edge order
__global__ void k_bond_we(const int* __restrict__ eattr, const int* __restrict__ col_eid,
                          const void* __restrict__ bemb, const float* __restrict__ wa_all,
                          float* __restrict__ we_csr, const int* __restrict__ flagp) {
  int j = blockIdx.x * 256 + threadIdx.x;
  if (j >= NE) return;
  int f32 = *flagp;
  int e = col_eid[j];
  int a0 = eattr[e*3], a1 = eattr[e*3+1], a2 = eattr[e*3+2];
  #pragma unroll
  for (int l = 0; l < NLAY; ++l) {
    size_t lb = (size_t)l * 144;
    float e0 = rdw(bemb, lb + (0*16+a0)*3+0, f32) + rdw(bemb, lb + (1*16+a1)*3+0, f32)
             + rdw(bemb, lb + (2*16+a2)*3+0, f32);
    float e1 = rdw(bemb, lb + (0*16+a0)*3+1, f32) + rdw(bemb, lb + (1*16+a1)*3+1, f32)
             + rdw(bemb, lb + (2*16+a2)*3+1, f32);
    float e2 = rdw(bemb, lb + (0*16+a0)*3+2, f32) + rdw(bemb, lb + (1*16+a1)*3+2, f32)
             + rdw(bemb, lb + (2*16+a2)*3+2, f32);
    we_csr[(size_t)l*NE + j] = e0*wa_all[l*3+0] + e1*wa_all[l*3+1] + e2*wa_all[l*3+2];
  }
}

// ---------------- per-layer kernels ----------------

// xlbf = bf16(h_bf @ W[l]); also as_[n]=xl.att_src, ad_[n]=xl.att_dst from fp32 acc.
__global__ __launch_bounds__(256) void k_gemm_fused(const unsigned short* __restrict__ A,
                                                    const unsigned short* __restrict__ Bt,
                                                    const void* __restrict__ as_w,
                                                    const void* __restrict__ ad_w, int l,
                                                    unsigned short* __restrict__ xlbf,
                                                    float* __restrict__ as_,
                                                    float* __restrict__ ad_,
                                                    const int* __restrict__ flagp) {
  __shared__ unsigned short xtile[16][256];
  __shared__ float sred[4][4][4], dred[4][4][4];   // [wave][g][r]
  int b = blockIdx.x;
  int w = threadIdx.x >> 6;
  int lane = threadIdx.x & 63;
  int m0 = b * 16;
  int c0 = w * 64;
  int lr = lane & 15;
  int g  = lane >> 4;
  int lk = g * 8;
  f32x4 acc0 = {0.f,0.f,0.f,0.f}, acc1 = {0.f,0.f,0.f,0.f};
  f32x4 acc2 = {0.f,0.f,0.f,0.f}, acc3 = {0.f,0.f,0.f,0.f};
  const unsigned short* arow = A  + (size_t)(m0 + lr) * 256 + lk;
  const unsigned short* b0   = Bt + (size_t)(c0 + lr) * 256 + lk;
  #pragma unroll
  for (int k = 0; k < 256; k += 32) {
    bf16x8 a = *(const bf16x8*)(arow + k);
    acc0 = __builtin_amdgcn_mfma_f32_16x16x32_bf16(a, *(const bf16x8*)(b0 + k),          acc0, 0,0,0);
    acc1 = __builtin_amdgcn_mfma_f32_16x16x32_bf16(a, *(const bf16x8*)(b0 + 16*256 + k), acc1, 0,0,0);
    acc2 = __builtin_amdgcn_mfma_f32_16x16x32_bf16(a, *(const bf16x8*)(b0 + 32*256 + k), acc2, 0,0,0);
    acc3 = __builtin_amdgcn_mfma_f32_16x16x32_bf16(a, *(const bf16x8*)(b0 + 48*256 + k), acc3, 0,0,0);
  }
  // acc{q}[r] = xl[m0 + g*4 + r][c0 + lr + 16q]
  int f32 = *flagp;
  float asw0 = rdw(as_w, (size_t)l*256 + c0 + lr +  0, f32);
  float asw1 = rdw(as_w, (size_t)l*256 + c0 + lr + 16, f32);
  float asw2 = rdw(as_w, (size_t)l*256 + c0 + lr + 32, f32);
  float asw3 = rdw(as_w, (size_t)l*256 + c0 + lr + 48, f32);
  float adw0 = rdw(ad_w, (size_t)l*256 + c0 + lr +  0, f32);
  float adw1 = rdw(ad_w, (size_t)l*256 + c0 + lr + 16, f32);
  float adw2 = rdw(ad_w, (size_t)l*256 + c0 + lr + 32, f32);
  float adw3 = rdw(ad_w, (size_t)l*256 + c0 + lr + 48, f32);
  #pragma unroll
  for (int r = 0; r < 4; ++r) {
    float sv = acc0[r]*asw0 + acc1[r]*asw1 + acc2[r]*asw2 + acc3[r]*asw3;
    float dv = acc0[r]*adw0 + acc1[r]*adw1 + acc2[r]*adw2 + acc3[r]*adw3;
    #pragma unroll
    for (int o = 1; o < 16; o <<= 1) { sv += __shfl_xor(sv, o); dv += __shfl_xor(dv, o); }
    if (lr == 0) { sred[w][g][r] = sv; dred[w][g][r] = dv; }
    int row = g*4 + r;
    xtile[row][c0 + lr +  0] = f2bf(acc0[r]);
    xtile[row][c0 + lr + 16] = f2bf(acc1[r]);
    xtile[row][c0 + lr + 32] = f2bf(acc2[r]);
    xtile[row][c0 + lr + 48] = f2bf(acc3[r]);
  }
  __syncthreads();
  int t = threadIdx.x;
  if (t < 16) {
    int gg = t >> 2, rr = t & 3;
    float s = sred[0][gg][rr] + sred[1][gg][rr] + sred[2][gg][rr] + sred[3][gg][rr];
    float d = dred[0][gg][rr] + dred[1][gg][rr] + dred[2][gg][rr] + dred[3][gg][rr];
    as_[m0 + gg*4 + rr] = s;
    ad_[m0 + gg*4 + rr] = d;
  }
  {
    int row = t >> 4;              // 0..15
    int seg = t & 15;              // 0..15
    us8* dstp = (us8*)(xlbf + (size_t)(m0 + row) * 256);
    const us8* srcp = (const us8*)&xtile[row][0];
    dstp[seg]      = srcp[seg];
    dstp[seg + 16] = srcp[seg + 16];
  }
}

// fused per-node: online segment-softmax over CSR edges + self-loop +
// weighted aggregation (bf16 xl) + bias + relu + residual + bf16 recast.
__global__ __launch_bounds__(256) void k_fused(const int* __restrict__ row_ptr,
                                               const int* __restrict__ col_src,
                                               const float* __restrict__ we_csr,
                                               const float* __restrict__ as_,
                                               const float* __restrict__ ad_,
                                               const unsigned short* __restrict__ xlbf,
                                               const void* __restrict__ bias, int l,
                                               float* __restrict__ h,
                                               unsigned short* __restrict__ hbf,
                                               int do_relu, const int* __restrict__ flagp) {
  int n = blockIdx.x * 4 + (threadIdx.x >> 6);
  int lane = threadIdx.x & 63;
  int beg = row_ptr[n], end = row_ptr[n+1];
  int deg = end - beg;
  float ad_n = ad_[n];

  float m = -1e30f, dsum = 0.f, wesum = 0.f;
  float ax = 0.f, ay = 0.f, az = 0.f, aw = 0.f;

  for (int cb = beg; cb < end; cb += 64) {
    int j = cb + lane;
    bool valid = (j < end);
    int s = valid ? col_src[j] : 0;
    float we = valid ? we_csr[j] : 0.f;
    wesum += we;
    float a;
    if (valid) {
      a = as_[s] + ad_n + we;
      a = (a >= 0.f) ? a : LEAK * a;
    } else {
      a = -1e30f;
    }
    float cm = a;
    #pragma unroll
    for (int o = 32; o > 0; o >>= 1) cm = fmaxf(cm, __shfl_xor(cm, o));
    float m_new = fmaxf(m, cm);
    float r = __expf(m - m_new);
    float p = valid ? __expf(a - m_new) : 0.f;
    float cs = p;
    #pragma unroll
    for (int o = 32; o > 0; o >>= 1) cs += __shfl_xor(cs, o);
    dsum = dsum * r + cs;
    ax *= r; ay *= r; az *= r; aw *= r;
    m = m_new;
    int cl = end - cb; if (cl > 64) cl = 64;
    for (int jj = 0; jj < cl; ++jj) {
      float w  = __shfl(p, jj);
      int   ss = __shfl(s, jj);
      us4 xv = *(const us4*)(xlbf + (size_t)ss*256 + lane*4);
      ax += w*bf2f(xv.x); ay += w*bf2f(xv.y);
      az += w*bf2f(xv.z); aw += w*bf2f(xv.w);
    }
  }
  #pragma unroll
  for (int o = 32; o > 0; o >>= 1) wesum += __shfl_xor(wesum, o);

  float a_self = as_[n] + ad_n + wesum / fmaxf((float)deg, 1.f);
  a_self = (a_self >= 0.f) ? a_self : LEAK * a_self;
  float m_f = fmaxf(m, a_self);
  float r = __expf(m - m_f);
  float p_self = __expf(a_self - m_f);
  dsum = dsum * r + p_self;
  ax *= r; ay *= r; az *= r; aw *= r;
  {
    us4 xv = *(const us4*)(xlbf + (size_t)n*256 + lane*4);
    ax += p_self*bf2f(xv.x); ay += p_self*bf2f(xv.y);
    az += p_self*bf2f(xv.z); aw += p_self*bf2f(xv.w);
  }
  float inv_d = 1.f / dsum;
  ax *= inv_d; ay *= inv_d; az *= inv_d; aw *= inv_d;

  int f32 = *flagp;
  int c0 = lane * 4;
  ax += rdw(bias, (size_t)l*256 + c0+0, f32);
  ay += rdw(bias, (size_t)l*256 + c0+1, f32);
  az += rdw(bias, (size_t)l*256 + c0+2, f32);
  aw += rdw(bias, (size_t)l*256 + c0+3, f32);
  if (do_relu) {
    ax = fmaxf(ax, 0.f); ay = fmaxf(ay, 0.f);
    az = fmaxf(az, 0.f); aw = fmaxf(aw, 0.f);
  }
  float* hp = h + (size_t)n*256 + c0;
  float4 hv = *(const float4*)hp;
  float h0 = ax + hv.x, h1 = ay + hv.y, h2 = az + hv.z, h3 = aw + hv.w;
  *(float4*)hp = make_float4(h0, h1, h2, h3);
  us4 q = { f2bf(h0), f2bf(h1), f2bf(h2), f2bf(h3) };
  *(us4*)(hbf + (size_t)n*256 + c0) = q;
}

// ---------------- pooling + head (fused; batch is sorted) ----------------

__global__ void k_head_v(const void* __restrict__ W1, const void* __restrict__ b1,
                         const void* __restrict__ W2, const void* __restrict__ b2,
                         float* __restrict__ v, float* __restrict__ c0,
                         const int* __restrict__ flagp) {
  int f32 = *flagp;
  int k = threadIdx.x;
  float s = 0.f;
  for (int c = 0; c < 256; ++c) s += rdw(W1, (size_t)k*256 + c, f32) * rdw(W2, c, f32);
  v[k] = s;
  if (k == 0) {
    float t = 0.f;
    for (int c = 0; c < 256; ++c) t += rdw(b1, c, f32) * rdw(W2, c, f32);
    *c0 = t + rdw(b2, 0, f32);
  }
}

__global__ __launch_bounds__(256) void k_pool_head(const float* __restrict__ h,
                                                   const int* __restrict__ batch,
                                                   const float* __restrict__ v,
                                                   const float* __restrict__ c0,
                                                   void* __restrict__ out,
                                                   const int* __restrict__ flagp) {
  int g = blockIdx.x;
  int lo = 0, hi = NN;
  while (lo < hi) { int mid = (lo + hi) >> 1; if (batch[mid] < g) lo = mid + 1; else hi = mid; }
  int start = lo;
  lo = 0; hi = NN;
  while (lo < hi) { int mid = (lo + hi) >> 1; if (batch[mid] < g + 1) lo = mid + 1; else hi = mid; }
  int endn = lo;

  int c = threadIdx.x;
  float s = 0.f;
  for (int n = start; n < endn; ++n) s += h[(size_t)n*256 + c];
  __shared__ float red[256];
  red[c] = s * v[c];
  __syncthreads();
  for (int off = 128; off > 0; off >>= 1) {
    if (c < off) red[c] += red[c + off];
    __syncthreads();
  }
  if (c == 0) {
    float cntf = (float)(endn - start);
    float val = red[0] / fmaxf(cntf, 1.f) + *c0;
    if (*flagp) ((float*)out)[g] = val;
    else        ((unsigned short*)out)[g] = f2bf(val);
  }
}

extern "C" void kernel_launch(void* const* d_in, const int* in_sizes, int n_in,
                              void* d_out, int out_size, void* d_ws, size_t ws_size,
                              hipStream_t stream) {
  const int* x     = (const int*)d_in[0];
  const int* eidx  = (const int*)d_in[1];
  const int* eattr = (const int*)d_in[2];
  const int* batch = (const int*)d_in[3];
  const void* atom_emb = d_in[4];
  const void* bond_emb = d_in[5];
  const void* W        = d_in[6];
  const void* att_src  = d_in[7];
  const void* att_dst  = d_in[8];
  const void* We       = d_in[9];
  const void* att_edge = d_in[10];
  const void* bias     = d_in[11];
  const void* W1 = d_in[12];
  const void* b1 = d_in[13];
  const void* W2 = d_in[14];
  const void* b2 = d_in[15];

  const int* src = eidx;
  const int* dst = eidx + NE;

  char* base = (char*)d_ws;
  size_t off = 0;
  auto alloc = [&](size_t bytes) -> char* {
    char* p = base + off; off += (bytes + 255) & ~(size_t)255; return p;
  };
  float* h    = (float*)alloc((size_t)NN*EMBD*4);
  unsigned short* xlbf = (unsigned short*)alloc((size_t)NN*EMBD*2);
  unsigned short* hbf  = (unsigned short*)alloc((size_t)NN*EMBD*2);
  unsigned short* wt   = (unsigned short*)alloc((size_t)NLAY*EMBD*EMBD*2);
  float* we_csr = (float*)alloc((size_t)NLAY*NE*4);
  float* as_   = (float*)alloc((size_t)NN*4);
  float* ad_   = (float*)alloc((size_t)NN*4);
  float* vvec  = (float*)alloc((size_t)EMBD*4);
  float* c0    = (float*)alloc(4);
  float* wa_all= (float*)alloc(64);
  int*   flag  = (int*)alloc(4);
  int* cnt_i   = (int*)alloc((size_t)NN*4);
  int* row_ptr = (int*)alloc((size_t)(NN+1)*4);
  int* cursor  = (int*)alloc((size_t)NN*4);
  int* col_src = (int*)alloc((size_t)NE*4);
  int* col_eid = (int*)alloc((size_t)NE*4);

  k_sniff<<<1, 256, 0, stream>>>((const unsigned short*)atom_emb, flag);
  (void)hipMemsetAsync(cnt_i, 0, (size_t)NN*4, stream);
  k_hist<<<(NE+255)/256, 256, 0, stream>>>(dst, cnt_i);
  k_scan<<<1, 1024, 0, stream>>>(cnt_i, row_ptr, cursor);
  k_fill<<<(NE+255)/256, 256, 0, stream>>>(src, dst, cursor, col_src, col_eid);
  k_transpose_w<<<NLAY*EMBD*EMBD/256, 256, 0, stream>>>(W, wt, flag);
  k_atom_enc<<<NN, 256, 0, stream>>>(x, atom_emb, h, hbf, flag);
  k_wa<<<1, 64, 0, stream>>>(We, att_edge, wa_all, flag);
  k_bond_we<<<(NE+255)/256, 256, 0, stream>>>(eattr, col_eid, bond_emb, wa_all, we_csr, flag);

  for (int l = 0; l < NLAY; ++l) {
    k_gemm_fused<<<NN/16, 256, 0, stream>>>(hbf, wt + (size_t)l*EMBD*EMBD,
                                            att_src, att_dst, l, xlbf, as_, ad_, flag);
    k_fused<<<NN/4, 256, 0, stream>>>(row_ptr, col_src, we_csr + (size_t)l*NE,
                                      as_, ad_, xlbf, bias, l, h, hbf,
                                      (l < NLAY-1) ? 1 : 0, flag);
  }

  k_head_v<<<1, 256, 0, stream>>>(W1, b1, W2, b2, vvec, c0, flag);
  k_pool_head<<<NG, 256, 0, stream>>>(h, batch, vvec, c0, d_out, flag);
}

// Round 13
// 579.656 us; speedup vs baseline: 10.4034x; 1.1055x over previous
//
#include <hip/hip_runtime.h>
#include <hip/hip_bf16.h>

#define NN   30000
#define NE   480000
#define EMBD 256
#define NG   512
#define NLAY 3
#define LEAK 0.2f
#define NBLK_SCAN 118   // ceil(NN/256)

typedef __attribute__((ext_vector_type(8))) short bf16x8;
typedef __attribute__((ext_vector_type(4))) float f32x4;
typedef __attribute__((ext_vector_type(4))) unsigned short us4;
typedef __attribute__((ext_vector_type(8))) unsigned short us8;

__device__ __forceinline__ float bf2f(unsigned short u) {
  union { unsigned int i; float f; } v; v.i = ((unsigned int)u) << 16; return v.f;
}
__device__ __forceinline__ unsigned short f2bf(float f) {
  union { float f; unsigned int i; } v; v.f = f;
  unsigned int u = v.i;
  u += 0x7fffu + ((u >> 16) & 1u);
  return (unsigned short)(u >> 16);
}
__device__ __forceinline__ float rdw(const void* p, size_t i, int f32) {
  return f32 ? ((const float*)p)[i] : bf2f(((const unsigned short*)p)[i]);
}

// ---------------- merged tiny setup: dtype sniff + wa + head vector ----------------
__global__ __launch_bounds__(256) void k_setup_small(
    const unsigned short* __restrict__ w,            // atom_emb as u16
    const void* __restrict__ We, const void* __restrict__ ae,
    const void* __restrict__ W1, const void* __restrict__ b1,
    const void* __restrict__ W2, const void* __restrict__ b2,
    int* flag, float* __restrict__ wa_all,
    float* __restrict__ v, float* __restrict__ c0) {
  __shared__ int cnt;
  __shared__ int f32s;
  int t = threadIdx.x;
  if (t == 0) cnt = 0;
  __syncthreads();
  int local = 0;
  for (int i = t * 2; i < 65536; i += 512) {
    unsigned short u = w[i];
    if (((u >> 7) & 0xFF) == 0xFF) local++;
  }
  atomicAdd(&cnt, local);
  __syncthreads();
  if (t == 0) { f32s = (cnt >= 4) ? 1 : 0; *flag = f32s; }
  __syncthreads();
  int f32 = f32s;
  if (t < 9) {
    int l = t / 3, j = t % 3;
    float s = 0.f;
    for (int c = 0; c < 256; ++c)
      s += rdw(We, (size_t)l*768 + j*256 + c, f32) * rdw(ae, (size_t)l*256 + c, f32);
    wa_all[t] = s;
  }
  {
    float s = 0.f;
    for (int c = 0; c < 256; ++c) s += rdw(W1, (size_t)t*256 + c, f32) * rdw(W2, c, f32);
    v[t] = s;
  }
  if (t == 0) {
    float s = 0.f;
    for (int c = 0; c < 256; ++c) s += rdw(b1, c, f32) * rdw(W2, c, f32);
    *c0 = s + rdw(b2, 0, f32);
  }
}

// ---------------- CSR build (once; graph static across layers) ----------------

__global__ void k_hist(const int* __restrict__ dst, int* cnt_i) {
  int e = blockIdx.x * 256 + threadIdx.x;
  if (e >= NE) return;
  atomicAdd(&cnt_i[dst[e]], 1);
}

__global__ __launch_bounds__(256) void k_scan_part(const int* __restrict__ cnt_i,
                                                   int* row_ptr, int* part) {
  __shared__ int sh[256];
  int b = blockIdx.x, t = threadIdx.x;
  int i = b * 256 + t;
  int v = (i < NN) ? cnt_i[i] : 0;
  sh[t] = v;
  __syncthreads();
  for (int off = 1; off < 256; off <<= 1) {
    int tmp = (t >= off) ? sh[t - off] : 0;
    __syncthreads();
    sh[t] += tmp;
    __syncthreads();
  }
  if (i < NN) row_ptr[i] = sh[t] - v;   // local exclusive prefix
  if (t == 255) part[b] = sh[255];
}

__global__ __launch_bounds__(128) void k_scan_mid(const int* __restrict__ part,
                                                  int* __restrict__ offs) {
  __shared__ int sh[128];
  int t = threadIdx.x;
  int v = (t < NBLK_SCAN) ? part[t] : 0;
  sh[t] = v;
  __syncthreads();
  for (int off = 1; off < 128; off <<= 1) {
    int tmp = (t >= off) ? sh[t - off] : 0;
    __syncthreads();
    sh[t] += tmp;
    __syncthreads();
  }
  if (t < NBLK_SCAN) offs[t] = sh[t] - v;  // exclusive
}

__global__ void k_scan_add(int* row_ptr, const int* __restrict__ offs, int* cursor) {
  int b = blockIdx.x, t = threadIdx.x;
  int i = b * 256 + t;
  if (i < NN) {
    int v = row_ptr[i] + offs[b];
    row_ptr[i] = v;
    cursor[i]  = v;
  }
  if (i == 0) row_ptr[NN] = NE;
}

__global__ void k_fill(const int* __restrict__ src, const int* __restrict__ dst,
                       int* cursor, int* col_src, int* col_eid) {
  int e = blockIdx.x * 256 + threadIdx.x;
  if (e >= NE) return;
  int pos = atomicAdd(&cursor[dst[e]], 1);
  col_src[pos] = src[e];
  col_eid[pos] = e;
}

// ---------------- merged prep: W transpose (blocks 0..767) + bond we (768..) ----

__global__ __launch_bounds__(256) void k_prep(const void* __restrict__ W,
                                              unsigned short* __restrict__ Wt,
                                              const int* __restrict__ eattr,
                                              const int* __restrict__ col_eid,
                                              const void* __restrict__ bemb,
                                              const float* __restrict__ wa_all,
                                              float* __restrict__ we_csr,
                                              const int* __restrict__ flagp) {
  int f32 = *flagp;
  int b = blockIdx.x;
  if (b < 768) {
    int t = b * 256 + threadIdx.x;           // 0..196607 = 3*65536
    int l = t >> 16;
    int k = (t >> 8) & 255;
    int c = t & 255;
    Wt[(l << 16) + (c << 8) + k] = f2bf(rdw(W, t, f32));
  } else {
    int j = (b - 768) * 256 + threadIdx.x;   // 0..479999
    if (j >= NE) return;
    int e = col_eid[j];
    int a0 = eattr[e*3], a1 = eattr[e*3+1], a2 = eattr[e*3+2];
    #pragma unroll
    for (int l = 0; l < NLAY; ++l) {
      size_t lb = (size_t)l * 144;
      float e0 = rdw(bemb, lb + (0*16+a0)*3+0, f32) + rdw(bemb, lb + (1*16+a1)*3+0, f32)
               + rdw(bemb, lb + (2*16+a2)*3+0, f32);
      float e1 = rdw(bemb, lb + (0*16+a0)*3+1, f32) + rdw(bemb, lb + (1*16+a1)*3+1, f32)
               + rdw(bemb, lb + (2*16+a2)*3+1, f32);
      float e2 = rdw(bemb, lb + (0*16+a0)*3+2, f32) + rdw(bemb, lb + (1*16+a1)*3+2, f32)
               + rdw(bemb, lb + (2*16+a2)*3+2, f32);
      we_csr[(size_t)l*NE + j] = e0*wa_all[l*3+0] + e1*wa_all[l*3+1] + e2*wa_all[l*3+2];
    }
  }
}

__global__ void k_atom_enc(const int* __restrict__ x, const void* __restrict__ emb,
                           float* __restrict__ h, unsigned short* __restrict__ hbf,
                           const int* __restrict__ flagp) {
  int f32 = *flagp;
  int n = blockIdx.x, c = threadIdx.x;
  float s = 0.f;
  #pragma unroll
  for (int i = 0; i < 9; ++i) {
    int xi = x[n * 9 + i];
    s += rdw(emb, (size_t)(i * 128 + xi) * 256 + c, f32);
  }
  h[n * 256 + c] = s;
  hbf[n * 256 + c] = f2bf(s);
}

// ---------------- per-layer kernels ----------------

__global__ __launch_bounds__(256) void k_gemm_fused(const unsigned short* __restrict__ A,
                                                    const unsigned short* __restrict__ Bt,
                                                    const void* __restrict__ as_w,
                                                    const void* __restrict__ ad_w, int l,
                                                    unsigned short* __restrict__ xlbf,
                                                    float* __restrict__ as_,
                                                    float* __restrict__ ad_,
                                                    const int* __restrict__ flagp) {
  __shared__ unsigned short xtile[16][256];
  __shared__ float sred[4][4][4], dred[4][4][4];   // [wave][g][r]
  int b = blockIdx.x;
  int w = threadIdx.x >> 6;
  int lane = threadIdx.x & 63;
  int m0 = b * 16;
  int c0 = w * 64;
  int lr = lane & 15;
  int g  = lane >> 4;
  int lk = g * 8;
  f32x4 acc0 = {0.f,0.f,0.f,0.f}, acc1 = {0.f,0.f,0.f,0.f};
  f32x4 acc2 = {0.f,0.f,0.f,0.f}, acc3 = {0.f,0.f,0.f,0.f};
  const unsigned short* arow = A  + (size_t)(m0 + lr) * 256 + lk;
  const unsigned short* b0   = Bt + (size_t)(c0 + lr) * 256 + lk;
  #pragma unroll
  for (int k = 0; k < 256; k += 32) {
    bf16x8 a = *(const bf16x8*)(arow + k);
    acc0 = __builtin_amdgcn_mfma_f32_16x16x32_bf16(a, *(const bf16x8*)(b0 + k),          acc0, 0,0,0);
    acc1 = __builtin_amdgcn_mfma_f32_16x16x32_bf16(a, *(const bf16x8*)(b0 + 16*256 + k), acc1, 0,0,0);
    acc2 = __builtin_amdgcn_mfma_f32_16x16x32_bf16(a, *(const bf16x8*)(b0 + 32*256 + k), acc2, 0,0,0);
    acc3 = __builtin_amdgcn_mfma_f32_16x16x32_bf16(a, *(const bf16x8*)(b0 + 48*256 + k), acc3, 0,0,0);
  }
  int f32 = *flagp;
  float asw0 = rdw(as_w, (size_t)l*256 + c0 + lr +  0, f32);
  float asw1 = rdw(as_w, (size_t)l*256 + c0 + lr + 16, f32);
  float asw2 = rdw(as_w, (size_t)l*256 + c0 + lr + 32, f32);
  float asw3 = rdw(as_w, (size_t)l*256 + c0 + lr + 48, f32);
  float adw0 = rdw(ad_w, (size_t)l*256 + c0 + lr +  0, f32);
  float adw1 = rdw(ad_w, (size_t)l*256 + c0 + lr + 16, f32);
  float adw2 = rdw(ad_w, (size_t)l*256 + c0 + lr + 32, f32);
  float adw3 = rdw(ad_w, (size_t)l*256 + c0 + lr + 48, f32);
  #pragma unroll
  for (int r = 0; r < 4; ++r) {
    float sv = acc0[r]*asw0 + acc1[r]*asw1 + acc2[r]*asw2 + acc3[r]*asw3;
    float dv = acc0[r]*adw0 + acc1[r]*adw1 + acc2[r]*adw2 + acc3[r]*adw3;
    #pragma unroll
    for (int o = 1; o < 16; o <<= 1) { sv += __shfl_xor(sv, o); dv += __shfl_xor(dv, o); }
    if (lr == 0) { sred[w][g][r] = sv; dred[w][g][r] = dv; }
    int row = g*4 + r;
    xtile[row][c0 + lr +  0] = f2bf(acc0[r]);
    xtile[row][c0 + lr + 16] = f2bf(acc1[r]);
    xtile[row][c0 + lr + 32] = f2bf(acc2[r]);
    xtile[row][c0 + lr + 48] = f2bf(acc3[r]);
  }
  __syncthreads();
  int t = threadIdx.x;
  if (t < 16) {
    int gg = t >> 2, rr = t & 3;
    float s = sred[0][gg][rr] + sred[1][gg][rr] + sred[2][gg][rr] + sred[3][gg][rr];
    float d = dred[0][gg][rr] + dred[1][gg][rr] + dred[2][gg][rr] + dred[3][gg][rr];
    as_[m0 + gg*4 + rr] = s;
    ad_[m0 + gg*4 + rr] = d;
  }
  {
    int row = t >> 4;
    int seg = t & 15;
    us8* dstp = (us8*)(xlbf + (size_t)(m0 + row) * 256);
    const us8* srcp = (const us8*)&xtile[row][0];
    dstp[seg]      = srcp[seg];
    dstp[seg + 16] = srcp[seg + 16];
  }
}

__global__ __launch_bounds__(256) void k_fused(const int* __restrict__ row_ptr,
                                               const int* __restrict__ col_src,
                                               const float* __restrict__ we_csr,
                                               const float* __restrict__ as_,
                                               const float* __restrict__ ad_,
                                               const unsigned short* __restrict__ xlbf,
                                               const void* __restrict__ bias, int l,
                                               float* __restrict__ h,
                                               unsigned short* __restrict__ hbf,
                                               int do_relu, const int* __restrict__ flagp) {
  int n = blockIdx.x * 4 + (threadIdx.x >> 6);
  int lane = threadIdx.x & 63;
  int beg = row_ptr[n], end = row_ptr[n+1];
  int deg = end - beg;
  float ad_n = ad_[n];

  float m = -1e30f, dsum = 0.f, wesum = 0.f;
  float ax = 0.f, ay = 0.f, az = 0.f, aw = 0.f;

  for (int cb = beg; cb < end; cb += 64) {
    int j = cb + lane;
    bool valid = (j < end);
    int s = valid ? col_src[j] : 0;
    float we = valid ? we_csr[j] : 0.f;
    wesum += we;
    float a;
    if (valid) {
      a = as_[s] + ad_n + we;
      a = (a >= 0.f) ? a : LEAK * a;
    } else {
      a = -1e30f;
    }
    float cm = a;
    #pragma unroll
    for (int o = 32; o > 0; o >>= 1) cm = fmaxf(cm, __shfl_xor(cm, o));
    float m_new = fmaxf(m, cm);
    float r = __expf(m - m_new);
    float p = valid ? __expf(a - m_new) : 0.f;
    float cs = p;
    #pragma unroll
    for (int o = 32; o > 0; o >>= 1) cs += __shfl_xor(cs, o);
    dsum = dsum * r + cs;
    ax *= r; ay *= r; az *= r; aw *= r;
    m = m_new;
    int cl = end - cb; if (cl > 64) cl = 64;
    for (int jj = 0; jj < cl; ++jj) {
      float w  = __shfl(p, jj);
      int   ss = __shfl(s, jj);
      us4 xv = *(const us4*)(xlbf + (size_t)ss*256 + lane*4);
      ax += w*bf2f(xv.x); ay += w*bf2f(xv.y);
      az += w*bf2f(xv.z); aw += w*bf2f(xv.w);
    }
  }
  #pragma unroll
  for (int o = 32; o > 0; o >>= 1) wesum += __shfl_xor(wesum, o);

  float a_self = as_[n] + ad_n + wesum / fmaxf((float)deg, 1.f);
  a_self = (a_self >= 0.f) ? a_self : LEAK * a_self;
  float m_f = fmaxf(m, a_self);
  float r = __expf(m - m_f);
  float p_self = __expf(a_self - m_f);
  dsum = dsum * r + p_self;
  ax *= r; ay *= r; az *= r; aw *= r;
  {
    us4 xv = *(const us4*)(xlbf + (size_t)n*256 + lane*4);
    ax += p_self*bf2f(xv.x); ay += p_self*bf2f(xv.y);
    az += p_self*bf2f(xv.z); aw += p_self*bf2f(xv.w);
  }
  float inv_d = 1.f / dsum;
  ax *= inv_d; ay *= inv_d; az *= inv_d; aw *= inv_d;

  int f32 = *flagp;
  int c0 = lane * 4;
  ax += rdw(bias, (size_t)l*256 + c0+0, f32);
  ay += rdw(bias, (size_t)l*256 + c0+1, f32);
  az += rdw(bias, (size_t)l*256 + c0+2, f32);
  aw += rdw(bias, (size_t)l*256 + c0+3, f32);
  if (do_relu) {
    ax = fmaxf(ax, 0.f); ay = fmaxf(ay, 0.f);
    az = fmaxf(az, 0.f); aw = fmaxf(aw, 0.f);
  }
  float* hp = h + (size_t)n*256 + c0;
  float4 hv = *(const float4*)hp;
  float h0 = ax + hv.x, h1 = ay + hv.y, h2 = az + hv.z, h3 = aw + hv.w;
  *(float4*)hp = make_float4(h0, h1, h2, h3);
  us4 q = { f2bf(h0), f2bf(h1), f2bf(h2), f2bf(h3) };
  *(us4*)(hbf + (size_t)n*256 + c0) = q;
}

// ---------------- pooling + head (batch is sorted) ----------------

__global__ __launch_bounds__(256) void k_pool_head(const float* __restrict__ h,
                                                   const int* __restrict__ batch,
                                                   const float* __restrict__ v,
                                                   const float* __restrict__ c0,
                                                   void* __restrict__ out,
                                                   const int* __restrict__ flagp) {
  int g = blockIdx.x;
  int lo = 0, hi = NN;
  while (lo < hi) { int mid = (lo + hi) >> 1; if (batch[mid] < g) lo = mid + 1; else hi = mid; }
  int start = lo;
  lo = 0; hi = NN;
  while (lo < hi) { int mid = (lo + hi) >> 1; if (batch[mid] < g + 1) lo = mid + 1; else hi = mid; }
  int endn = lo;

  int c = threadIdx.x;
  float s = 0.f;
  for (int n = start; n < endn; ++n) s += h[(size_t)n*256 + c];
  __shared__ float red[256];
  red[c] = s * v[c];
  __syncthreads();
  for (int off = 128; off > 0; off >>= 1) {
    if (c < off) red[c] += red[c + off];
    __syncthreads();
  }
  if (c == 0) {
    float cntf = (float)(endn - start);
    float val = red[0] / fmaxf(cntf, 1.f) + *c0;
    if (*flagp) ((float*)out)[g] = val;
    else        ((unsigned short*)out)[g] = f2bf(val);
  }
}

extern "C" void kernel_launch(void* const* d_in, const int* in_sizes, int n_in,
                              void* d_out, int out_size, void* d_ws, size_t ws_size,
                              hipStream_t stream) {
  const int* x     = (const int*)d_in[0];
  const int* eidx  = (const int*)d_in[1];
  const int* eattr = (const int*)d_in[2];
  const int* batch = (const int*)d_in[3];
  const void* atom_emb = d_in[4];
  const void* bond_emb = d_in[5];
  const void* W        = d_in[6];
  const void* att_src  = d_in[7];
  const void* att_dst  = d_in[8];
  const void* We       = d_in[9];
  const void* att_edge = d_in[10];
  const void* bias     = d_in[11];
  const void* W1 = d_in[12];
  const void* b1 = d_in[13];
  const void* W2 = d_in[14];
  const void* b2 = d_in[15];

  const int* src = eidx;
  const int* dst = eidx + NE;

  char* base = (char*)d_ws;
  size_t off = 0;
  auto alloc = [&](size_t bytes) -> char* {
    char* p = base + off; off += (bytes + 255) & ~(size_t)255; return p;
  };
  float* h    = (float*)alloc((size_t)NN*EMBD*4);
  unsigned short* xlbf = (unsigned short*)alloc((size_t)NN*EMBD*2);
  unsigned short* hbf  = (unsigned short*)alloc((size_t)NN*EMBD*2);
  unsigned short* wt   = (unsigned short*)alloc((size_t)NLAY*EMBD*EMBD*2);
  float* we_csr = (float*)alloc((size_t)NLAY*NE*4);
  float* as_   = (float*)alloc((size_t)NN*4);
  float* ad_   = (float*)alloc((size_t)NN*4);
  float* vvec  = (float*)alloc((size_t)EMBD*4);
  float* c0    = (float*)alloc(4);
  float* wa_all= (float*)alloc(64);
  int*   flag  = (int*)alloc(4);
  int* cnt_i   = (int*)alloc((size_t)NN*4);
  int* row_ptr = (int*)alloc((size_t)(NN+1)*4);
  int* cursor  = (int*)alloc((size_t)NN*4);
  int* col_src = (int*)alloc((size_t)NE*4);
  int* col_eid = (int*)alloc((size_t)NE*4);
  int* part    = (int*)alloc((size_t)NBLK_SCAN*4);
  int* offs    = (int*)alloc((size_t)NBLK_SCAN*4);

  k_setup_small<<<1, 256, 0, stream>>>((const unsigned short*)atom_emb, We, att_edge,
                                       W1, b1, W2, b2, flag, wa_all, vvec, c0);
  (void)hipMemsetAsync(cnt_i, 0, (size_t)NN*4, stream);
  k_hist<<<(NE+255)/256, 256, 0, stream>>>(dst, cnt_i);
  k_scan_part<<<NBLK_SCAN, 256, 0, stream>>>(cnt_i, row_ptr, part);
  k_scan_mid<<<1, 128, 0, stream>>>(part, offs);
  k_scan_add<<<NBLK_SCAN, 256, 0, stream>>>(row_ptr, offs, cursor);
  k_fill<<<(NE+255)/256, 256, 0, stream>>>(src, dst, cursor, col_src, col_eid);
  k_atom_enc<<<NN, 256, 0, stream>>>(x, atom_emb, h, hbf, flag);
  k_prep<<<768 + (NE+255)/256, 256, 0, stream>>>(W, wt, eattr, col_eid, bond_emb,
                                                 wa_all, we_csr, flag);

  for (int l = 0; l < NLAY; ++l) {
    k_gemm_fused<<<NN/16, 256, 0, stream>>>(hbf, wt + (size_t)l*EMBD*EMBD,
                                            att_src, att_dst, l, xlbf, as_, ad_, flag);
    k_fused<<<NN/4, 256, 0, stream>>>(row_ptr, col_src, we_csr + (size_t)l*NE,
                                      as_, ad_, xlbf, bias, l, h, hbf,
                                      (l < NLAY-1) ? 1 : 0, flag);
  }

  k_pool_head<<<NG, 256, 0, stream>>>(h, batch, vvec, c0, d_out, flag);
}

// Round 14
// 497.873 us; speedup vs baseline: 12.1123x; 1.1643x over previous
//
#include <hip/hip_runtime.h>
#include <hip/hip_bf16.h>

#define NN   30000
#define NE   480000
#define EMBD 256
#define NG   512
#define NLAY 3
#define LEAK 0.2f
#define NBLK_SCAN 118   // ceil(NN/256)

typedef __attribute__((ext_vector_type(8))) short bf16x8;
typedef __attribute__((ext_vector_type(4))) float f32x4;
typedef __attribute__((ext_vector_type(4))) unsigned short us4;
typedef __attribute__((ext_vector_type(8))) unsigned short us8;

__device__ __forceinline__ float bf2f(unsigned short u) {
  union { unsigned int i; float f; } v; v.i = ((unsigned int)u) << 16; return v.f;
}
__device__ __forceinline__ unsigned short f2bf(float f) {
  union { float f; unsigned int i; } v; v.f = f;
  unsigned int u = v.i;
  u += 0x7fffu + ((u >> 16) & 1u);
  return (unsigned short)(u >> 16);
}
__device__ __forceinline__ float rdw(const void* p, size_t i, int f32) {
  return f32 ? ((const float*)p)[i] : bf2f(((const unsigned short*)p)[i]);
}

// ---------------- dtype sniff: 16 blocks, atomic count into global ----------------
__global__ __launch_bounds__(256) void k_sniff_multi(const unsigned short* __restrict__ w,
                                                     int* cnt) {
  __shared__ int sh;
  if (threadIdx.x == 0) sh = 0;
  __syncthreads();
  int local = 0;
  // even-indexed u16 of 65536; 16 blocks x 256 threads
  for (int i = (blockIdx.x * 256 + threadIdx.x) * 2; i < 65536; i += 16 * 256 * 2) {
    unsigned short u = w[i];
    if (((u >> 7) & 0xFF) == 0xFF) local++;
  }
  atomicAdd(&sh, local);
  __syncthreads();
  if (threadIdx.x == 0 && sh) atomicAdd(cnt, sh);
}

// ---------------- all small dot products: one wave per dot ----------------
// wid 0..255: v[wid] = W1[wid,:].W2   wid 256..264: wa_all   wid 265: c0
__global__ __launch_bounds__(256) void k_dots(const void* __restrict__ We,
                                              const void* __restrict__ ae,
                                              const void* __restrict__ W1,
                                              const void* __restrict__ b1,
                                              const void* __restrict__ W2,
                                              const void* __restrict__ b2,
                                              const int* __restrict__ cntp,
                                              float* __restrict__ wa_all,
                                              float* __restrict__ v,
                                              float* __restrict__ c0) {
  int f32 = (*cntp >= 4) ? 1 : 0;
  int wid  = blockIdx.x * 4 + (threadIdx.x >> 6);
  int lane = threadIdx.x & 63;
  if (wid >= 266) return;
  float s = 0.f;
  if (wid < 256) {
    for (int c = lane; c < 256; c += 64)
      s += rdw(W1, (size_t)wid*256 + c, f32) * rdw(W2, c, f32);
  } else if (wid < 265) {
    int t = wid - 256;
    int l = t / 3, j = t % 3;
    for (int c = lane; c < 256; c += 64)
      s += rdw(We, (size_t)l*768 + j*256 + c, f32) * rdw(ae, (size_t)l*256 + c, f32);
  } else {
    for (int c = lane; c < 256; c += 64)
      s += rdw(b1, c, f32) * rdw(W2, c, f32);
  }
  #pragma unroll
  for (int o = 32; o > 0; o >>= 1) s += __shfl_down(s, o);
  if (lane == 0) {
    if (wid < 256)      v[wid] = s;
    else if (wid < 265) wa_all[wid - 256] = s;
    else                *c0 = s + rdw(b2, 0, f32);
  }
}

// ---------------- CSR build (once; graph static across layers) ----------------

__global__ void k_hist(const int* __restrict__ dst, int* cnt_i) {
  int e = blockIdx.x * 256 + threadIdx.x;
  if (e >= NE) return;
  atomicAdd(&cnt_i[dst[e]], 1);
}

__global__ __launch_bounds__(256) void k_scan_part(const int* __restrict__ cnt_i,
                                                   int* row_ptr, int* part) {
  __shared__ int sh[256];
  int b = blockIdx.x, t = threadIdx.x;
  int i = b * 256 + t;
  int v = (i < NN) ? cnt_i[i] : 0;
  sh[t] = v;
  __syncthreads();
  for (int off = 1; off < 256; off <<= 1) {
    int tmp = (t >= off) ? sh[t - off] : 0;
    __syncthreads();
    sh[t] += tmp;
    __syncthreads();
  }
  if (i < NN) row_ptr[i] = sh[t] - v;   // local exclusive prefix
  if (t == 255) part[b] = sh[255];
}

__global__ __launch_bounds__(128) void k_scan_mid(const int* __restrict__ part,
                                                  int* __restrict__ offs) {
  __shared__ int sh[128];
  int t = threadIdx.x;
  int v = (t < NBLK_SCAN) ? part[t] : 0;
  sh[t] = v;
  __syncthreads();
  for (int off = 1; off < 128; off <<= 1) {
    int tmp = (t >= off) ? sh[t - off] : 0;
    __syncthreads();
    sh[t] += tmp;
    __syncthreads();
  }
  if (t < NBLK_SCAN) offs[t] = sh[t] - v;  // exclusive
}

__global__ void k_scan_add(int* row_ptr, const int* __restrict__ offs, int* cursor) {
  int b = blockIdx.x, t = threadIdx.x;
  int i = b * 256 + t;
  if (i < NN) {
    int v = row_ptr[i] + offs[b];
    row_ptr[i] = v;
    cursor[i]  = v;
  }
  if (i == 0) row_ptr[NN] = NE;
}

__global__ void k_fill(const int* __restrict__ src, const int* __restrict__ dst,
                       int* cursor, int* col_src, int* col_eid) {
  int e = blockIdx.x * 256 + threadIdx.x;
  if (e >= NE) return;
  int pos = atomicAdd(&cursor[dst[e]], 1);
  col_src[pos] = src[e];
  col_eid[pos] = e;
}

// ---------------- merged prep: W transpose (blocks 0..767) + bond we (768..) ----

__global__ __launch_bounds__(256) void k_prep(const void* __restrict__ W,
                                              unsigned short* __restrict__ Wt,
                                              const int* __restrict__ eattr,
                                              const int* __restrict__ col_eid,
                                              const void* __restrict__ bemb,
                                              const float* __restrict__ wa_all,
                                              float* __restrict__ we_csr,
                                              const int* __restrict__ cntp) {
  int f32 = (*cntp >= 4) ? 1 : 0;
  int b = blockIdx.x;
  if (b < 768) {
    int t = b * 256 + threadIdx.x;           // 0..196607 = 3*65536
    int l = t >> 16;
    int k = (t >> 8) & 255;
    int c = t & 255;
    Wt[(l << 16) + (c << 8) + k] = f2bf(rdw(W, t, f32));
  } else {
    int j = (b - 768) * 256 + threadIdx.x;   // 0..479999
    if (j >= NE) return;
    int e = col_eid[j];
    int a0 = eattr[e*3], a1 = eattr[e*3+1], a2 = eattr[e*3+2];
    #pragma unroll
    for (int l = 0; l < NLAY; ++l) {
      size_t lb = (size_t)l * 144;
      float e0 = rdw(bemb, lb + (0*16+a0)*3+0, f32) + rdw(bemb, lb + (1*16+a1)*3+0, f32)
               + rdw(bemb, lb + (2*16+a2)*3+0, f32);
      float e1 = rdw(bemb, lb + (0*16+a0)*3+1, f32) + rdw(bemb, lb + (1*16+a1)*3+1, f32)
               + rdw(bemb, lb + (2*16+a2)*3+1, f32);
      float e2 = rdw(bemb, lb + (0*16+a0)*3+2, f32) + rdw(bemb, lb + (1*16+a1)*3+2, f32)
               + rdw(bemb, lb + (2*16+a2)*3+2, f32);
      we_csr[(size_t)l*NE + j] = e0*wa_all[l*3+0] + e1*wa_all[l*3+1] + e2*wa_all[l*3+2];
    }
  }
}

__global__ void k_atom_enc(const int* __restrict__ x, const void* __restrict__ emb,
                           float* __restrict__ h, unsigned short* __restrict__ hbf,
                           const int* __restrict__ cntp) {
  int f32 = (*cntp >= 4) ? 1 : 0;
  int n = blockIdx.x, c = threadIdx.x;
  float s = 0.f;
  #pragma unroll
  for (int i = 0; i < 9; ++i) {
    int xi = x[n * 9 + i];
    s += rdw(emb, (size_t)(i * 128 + xi) * 256 + c, f32);
  }
  h[n * 256 + c] = s;
  hbf[n * 256 + c] = f2bf(s);
}

// ---------------- per-layer kernels ----------------

__global__ __launch_bounds__(256) void k_gemm_fused(const unsigned short* __restrict__ A,
                                                    const unsigned short* __restrict__ Bt,
                                                    const void* __restrict__ as_w,
                                                    const void* __restrict__ ad_w, int l,
                                                    unsigned short* __restrict__ xlbf,
                                                    float* __restrict__ as_,
                                                    float* __restrict__ ad_,
                                                    const int* __restrict__ cntp) {
  __shared__ unsigned short xtile[16][256];
  __shared__ float sred[4][4][4], dred[4][4][4];   // [wave][g][r]
  int b = blockIdx.x;
  int w = threadIdx.x >> 6;
  int lane = threadIdx.x & 63;
  int m0 = b * 16;
  int c0 = w * 64;
  int lr = lane & 15;
  int g  = lane >> 4;
  int lk = g * 8;
  f32x4 acc0 = {0.f,0.f,0.f,0.f}, acc1 = {0.f,0.f,0.f,0.f};
  f32x4 acc2 = {0.f,0.f,0.f,0.f}, acc3 = {0.f,0.f,0.f,0.f};
  const unsigned short* arow = A  + (size_t)(m0 + lr) * 256 + lk;
  const unsigned short* b0   = Bt + (size_t)(c0 + lr) * 256 + lk;
  #pragma unroll
  for (int k = 0; k < 256; k += 32) {
    bf16x8 a = *(const bf16x8*)(arow + k);
    acc0 = __builtin_amdgcn_mfma_f32_16x16x32_bf16(a, *(const bf16x8*)(b0 + k),          acc0, 0,0,0);
    acc1 = __builtin_amdgcn_mfma_f32_16x16x32_bf16(a, *(const bf16x8*)(b0 + 16*256 + k), acc1, 0,0,0);
    acc2 = __builtin_amdgcn_mfma_f32_16x16x32_bf16(a, *(const bf16x8*)(b0 + 32*256 + k), acc2, 0,0,0);
    acc3 = __builtin_amdgcn_mfma_f32_16x16x32_bf16(a, *(const bf16x8*)(b0 + 48*256 + k), acc3, 0,0,0);
  }
  int f32 = (*cntp >= 4) ? 1 : 0;
  float asw0 = rdw(as_w, (size_t)l*256 + c0 + lr +  0, f32);
  float asw1 = rdw(as_w, (size_t)l*256 + c0 + lr + 16, f32);
  float asw2 = rdw(as_w, (size_t)l*256 + c0 + lr + 32, f32);
  float asw3 = rdw(as_w, (size_t)l*256 + c0 + lr + 48, f32);
  float adw0 = rdw(ad_w, (size_t)l*256 + c0 + lr +  0, f32);
  float adw1 = rdw(ad_w, (size_t)l*256 + c0 + lr + 16, f32);
  float adw2 = rdw(ad_w, (size_t)l*256 + c0 + lr + 32, f32);
  float adw3 = rdw(ad_w, (size_t)l*256 + c0 + lr + 48, f32);
  #pragma unroll
  for (int r = 0; r < 4; ++r) {
    float sv = acc0[r]*asw0 + acc1[r]*asw1 + acc2[r]*asw2 + acc3[r]*asw3;
    float dv = acc0[r]*adw0 + acc1[r]*adw1 + acc2[r]*adw2 + acc3[r]*adw3;
    #pragma unroll
    for (int o = 1; o < 16; o <<= 1) { sv += __shfl_xor(sv, o); dv += __shfl_xor(dv, o); }
    if (lr == 0) { sred[w][g][r] = sv; dred[w][g][r] = dv; }
    int row = g*4 + r;
    xtile[row][c0 + lr +  0] = f2bf(acc0[r]);
    xtile[row][c0 + lr + 16] = f2bf(acc1[r]);
    xtile[row][c0 + lr + 32] = f2bf(acc2[r]);
    xtile[row][c0 + lr + 48] = f2bf(acc3[r]);
  }
  __syncthreads();
  int t = threadIdx.x;
  if (t < 16) {
    int gg = t >> 2, rr = t & 3;
    float s = sred[0][gg][rr] + sred[1][gg][rr] + sred[2][gg][rr] + sred[3][gg][rr];
    float d = dred[0][gg][rr] + dred[1][gg][rr] + dred[2][gg][rr] + dred[3][gg][rr];
    as_[m0 + gg*4 + rr] = s;
    ad_[m0 + gg*4 + rr] = d;
  }
  {
    int row = t >> 4;
    int seg = t & 15;
    us8* dstp = (us8*)(xlbf + (size_t)(m0 + row) * 256);
    const us8* srcp = (const us8*)&xtile[row][0];
    dstp[seg]      = srcp[seg];
    dstp[seg + 16] = srcp[seg + 16];
  }
}

__global__ __launch_bounds__(256) void k_fused(const int* __restrict__ row_ptr,
                                               const int* __restrict__ col_src,
                                               const float* __restrict__ we_csr,
                                               const float* __restrict__ as_,
                                               const float* __restrict__ ad_,
                                               const unsigned short* __restrict__ xlbf,
                                               const void* __restrict__ bias, int l,
                                               float* __restrict__ h,
                                               unsigned short* __restrict__ hbf,
                                               int do_relu, const int* __restrict__ cntp) {
  int n = blockIdx.x * 4 + (threadIdx.x >> 6);
  int lane = threadIdx.x & 63;
  int beg = row_ptr[n], end = row_ptr[n+1];
  int deg = end - beg;
  float ad_n = ad_[n];

  float m = -1e30f, dsum = 0.f, wesum = 0.f;
  float ax = 0.f, ay = 0.f, az = 0.f, aw = 0.f;

  for (int cb = beg; cb < end; cb += 64) {
    int j = cb + lane;
    bool valid = (j < end);
    int s = valid ? col_src[j] : 0;
    float we = valid ? we_csr[j] : 0.f;
    wesum += we;
    float a;
    if (valid) {
      a = as_[s] + ad_n + we;
      a = (a >= 0.f) ? a : LEAK * a;
    } else {
      a = -1e30f;
    }
    float cm = a;
    #pragma unroll
    for (int o = 32; o > 0; o >>= 1) cm = fmaxf(cm, __shfl_xor(cm, o));
    float m_new = fmaxf(m, cm);
    float r = __expf(m - m_new);
    float p = valid ? __expf(a - m_new) : 0.f;
    float cs = p;
    #pragma unroll
    for (int o = 32; o > 0; o >>= 1) cs += __shfl_xor(cs, o);
    dsum = dsum * r + cs;
    ax *= r; ay *= r; az *= r; aw *= r;
    m = m_new;
    int cl = end - cb; if (cl > 64) cl = 64;
    for (int jj = 0; jj < cl; ++jj) {
      float w  = __shfl(p, jj);
      int   ss = __shfl(s, jj);
      us4 xv = *(const us4*)(xlbf + (size_t)ss*256 + lane*4);
      ax += w*bf2f(xv.x); ay += w*bf2f(xv.y);
      az += w*bf2f(xv.z); aw += w*bf2f(xv.w);
    }
  }
  #pragma unroll
  for (int o = 32; o > 0; o >>= 1) wesum += __shfl_xor(wesum, o);

  float a_self = as_[n] + ad_n + wesum / fmaxf((float)deg, 1.f);
  a_self = (a_self >= 0.f) ? a_self : LEAK * a_self;
  float m_f = fmaxf(m, a_self);
  float r = __expf(m - m_f);
  float p_self = __expf(a_self - m_f);
  dsum = dsum * r + p_self;
  ax *= r; ay *= r; az *= r; aw *= r;
  {
    us4 xv = *(const us4*)(xlbf + (size_t)n*256 + lane*4);
    ax += p_self*bf2f(xv.x); ay += p_self*bf2f(xv.y);
    az += p_self*bf2f(xv.z); aw += p_self*bf2f(xv.w);
  }
  float inv_d = 1.f / dsum;
  ax *= inv_d; ay *= inv_d; az *= inv_d; aw *= inv_d;

  int f32 = (*cntp >= 4) ? 1 : 0;
  int c0 = lane * 4;
  ax += rdw(bias, (size_t)l*256 + c0+0, f32);
  ay += rdw(bias, (size_t)l*256 + c0+1, f32);
  az += rdw(bias, (size_t)l*256 + c0+2, f32);
  aw += rdw(bias, (size_t)l*256 + c0+3, f32);
  if (do_relu) {
    ax = fmaxf(ax, 0.f); ay = fmaxf(ay, 0.f);
    az = fmaxf(az, 0.f); aw = fmaxf(aw, 0.f);
  }
  float* hp = h + (size_t)n*256 + c0;
  float4 hv = *(const float4*)hp;
  float h0 = ax + hv.x, h1 = ay + hv.y, h2 = az + hv.z, h3 = aw + hv.w;
  *(float4*)hp = make_float4(h0, h1, h2, h3);
  us4 q = { f2bf(h0), f2bf(h1), f2bf(h2), f2bf(h3) };
  *(us4*)(hbf + (size_t)n*256 + c0) = q;
}

// ---------------- pooling + head (batch is sorted) ----------------

__global__ __launch_bounds__(256) void k_pool_head(const float* __restrict__ h,
                                                   const int* __restrict__ batch,
                                                   const float* __restrict__ v,
                                                   const float* __restrict__ c0,
                                                   void* __restrict__ out,
                                                   const int* __restrict__ cntp) {
  int g = blockIdx.x;
  int lo = 0, hi = NN;
  while (lo < hi) { int mid = (lo + hi) >> 1; if (batch[mid] < g) lo = mid + 1; else hi = mid; }
  int start = lo;
  lo = 0; hi = NN;
  while (lo < hi) { int mid = (lo + hi) >> 1; if (batch[mid] < g + 1) lo = mid + 1; else hi = mid; }
  int endn = lo;

  int c = threadIdx.x;
  float s = 0.f;
  for (int n = start; n < endn; ++n) s += h[(size_t)n*256 + c];
  __shared__ float red[256];
  red[c] = s * v[c];
  __syncthreads();
  for (int off = 128; off > 0; off >>= 1) {
    if (c < off) red[c] += red[c + off];
    __syncthreads();
  }
  if (c == 0) {
    float cntf = (float)(endn - start);
    float val = red[0] / fmaxf(cntf, 1.f) + *c0;
    if (*cntp >= 4) ((float*)out)[g] = val;
    else            ((unsigned short*)out)[g] = f2bf(val);
  }
}

extern "C" void kernel_launch(void* const* d_in, const int* in_sizes, int n_in,
                              void* d_out, int out_size, void* d_ws, size_t ws_size,
                              hipStream_t stream) {
  const int* x     = (const int*)d_in[0];
  const int* eidx  = (const int*)d_in[1];
  const int* eattr = (const int*)d_in[2];
  const int* batch = (const int*)d_in[3];
  const void* atom_emb = d_in[4];
  const void* bond_emb = d_in[5];
  const void* W        = d_in[6];
  const void* att_src  = d_in[7];
  const void* att_dst  = d_in[8];
  const void* We       = d_in[9];
  const void* att_edge = d_in[10];
  const void* bias     = d_in[11];
  const void* W1 = d_in[12];
  const void* b1 = d_in[13];
  const void* W2 = d_in[14];
  const void* b2 = d_in[15];

  const int* src = eidx;
  const int* dst = eidx + NE;

  char* base = (char*)d_ws;
  size_t off = 0;
  auto alloc = [&](size_t bytes) -> char* {
    char* p = base + off; off += (bytes + 255) & ~(size_t)255; return p;
  };
  float* h    = (float*)alloc((size_t)NN*EMBD*4);
  unsigned short* xlbf = (unsigned short*)alloc((size_t)NN*EMBD*2);
  unsigned short* hbf  = (unsigned short*)alloc((size_t)NN*EMBD*2);
  unsigned short* wt   = (unsigned short*)alloc((size_t)NLAY*EMBD*EMBD*2);
  float* we_csr = (float*)alloc((size_t)NLAY*NE*4);
  float* as_   = (float*)alloc((size_t)NN*4);
  float* ad_   = (float*)alloc((size_t)NN*4);
  float* vvec  = (float*)alloc((size_t)EMBD*4);
  float* c0    = (float*)alloc(4);
  float* wa_all= (float*)alloc(64);
  int*   cnt   = (int*)alloc(4);
  int* cnt_i   = (int*)alloc((size_t)NN*4);
  int* row_ptr = (int*)alloc((size_t)(NN+1)*4);
  int* cursor  = (int*)alloc((size_t)NN*4);
  int* col_src = (int*)alloc((size_t)NE*4);
  int* col_eid = (int*)alloc((size_t)NE*4);
  int* part    = (int*)alloc((size_t)NBLK_SCAN*4);
  int* offs    = (int*)alloc((size_t)NBLK_SCAN*4);

  (void)hipMemsetAsync(cnt, 0, 4, stream);
  (void)hipMemsetAsync(cnt_i, 0, (size_t)NN*4, stream);
  k_sniff_multi<<<16, 256, 0, stream>>>((const unsigned short*)atom_emb, cnt);
  k_hist<<<(NE+255)/256, 256, 0, stream>>>(dst, cnt_i);
  k_scan_part<<<NBLK_SCAN, 256, 0, stream>>>(cnt_i, row_ptr, part);
  k_scan_mid<<<1, 128, 0, stream>>>(part, offs);
  k_scan_add<<<NBLK_SCAN, 256, 0, stream>>>(row_ptr, offs, cursor);
  k_fill<<<(NE+255)/256, 256, 0, stream>>>(src, dst, cursor, col_src, col_eid);
  k_dots<<<67, 256, 0, stream>>>(We, att_edge, W1, b1, W2, b2, cnt, wa_all, vvec, c0);
  k_atom_enc<<<NN, 256, 0, stream>>>(x, atom_emb, h, hbf, cnt);
  k_prep<<<768 + (NE+255)/256, 256, 0, stream>>>(W, wt, eattr, col_eid, bond_emb,
                                                 wa_all, we_csr, cnt);

  for (int l = 0; l < NLAY; ++l) {
    k_gemm_fused<<<NN/16, 256, 0, stream>>>(hbf, wt + (size_t)l*EMBD*EMBD,
                                            att_src, att_dst, l, xlbf, as_, ad_, cnt);
    k_fused<<<NN/4, 256, 0, stream>>>(row_ptr, col_src, we_csr + (size_t)l*NE,
                                      as_, ad_, xlbf, bias, l, h, hbf,
                                      (l < NLAY-1) ? 1 : 0, cnt);
  }

  k_pool_head<<<NG, 256, 0, stream>>>(h, batch, vvec, c0, d_out, cnt);
}

// Round 15
// 451.976 us; speedup vs baseline: 13.3422x; 1.1015x over previous
//
#include <hip/hip_runtime.h>
#include <hip/hip_bf16.h>

#define NN   30000
#define NE   480000
#define EMBD 256
#define NG   512
#define NLAY 3
#define LEAK 0.2f
#define NBLK_SCAN 118   // ceil(NN/256)
#define GROWS 48        // gemm rows per block; 30000 = 625*48

typedef __attribute__((ext_vector_type(8))) short bf16x8;
typedef __attribute__((ext_vector_type(4))) float f32x4;
typedef __attribute__((ext_vector_type(4))) unsigned short us4;
typedef __attribute__((ext_vector_type(8))) unsigned short us8;

__device__ __forceinline__ float bf2f(unsigned short u) {
  union { unsigned int i; float f; } v; v.i = ((unsigned int)u) << 16; return v.f;
}
__device__ __forceinline__ unsigned short f2bf(float f) {
  union { float f; unsigned int i; } v; v.f = f;
  unsigned int u = v.i;
  u += 0x7fffu + ((u >> 16) & 1u);
  return (unsigned short)(u >> 16);
}
__device__ __forceinline__ float rdw(const void* p, size_t i, int f32) {
  return f32 ? ((const float*)p)[i] : bf2f(((const unsigned short*)p)[i]);
}

// ---------------- merged: dtype sniff (blocks 0..15) + degree hist (16..) ----------------
__global__ __launch_bounds__(256) void k_sniff_hist(const unsigned short* __restrict__ w,
                                                    int* cnt, const int* __restrict__ dst,
                                                    int* cnt_i) {
  int b = blockIdx.x;
  if (b < 16) {
    __shared__ int sh;
    if (threadIdx.x == 0) sh = 0;
    __syncthreads();
    int local = 0;
    for (int i = (b * 256 + threadIdx.x) * 2; i < 65536; i += 16 * 256 * 2) {
      unsigned short u = w[i];
      if (((u >> 7) & 0xFF) == 0xFF) local++;
    }
    atomicAdd(&sh, local);
    __syncthreads();
    if (threadIdx.x == 0 && sh) atomicAdd(cnt, sh);
  } else {
    int e = (b - 16) * 256 + threadIdx.x;
    if (e < NE) atomicAdd(&cnt_i[dst[e]], 1);
  }
}

// ---------------- merged: scan phase A (blocks 0..117) + small dots (118..) ----------------
// dots wid 0..255: v[wid]=W1[wid,:].W2 ; 256..264: wa_all ; 265: c0
__global__ __launch_bounds__(256) void k_scan_dots(const int* __restrict__ cnt_i,
                                                   int* row_ptr, int* part,
                                                   const void* __restrict__ We,
                                                   const void* __restrict__ ae,
                                                   const void* __restrict__ W1,
                                                   const void* __restrict__ b1,
                                                   const void* __restrict__ W2,
                                                   const void* __restrict__ b2,
                                                   const int* __restrict__ cntp,
                                                   float* __restrict__ wa_all,
                                                   float* __restrict__ v,
                                                   float* __restrict__ c0) {
  int b = blockIdx.x;
  if (b < NBLK_SCAN) {
    __shared__ int sh[256];
    int t = threadIdx.x;
    int i = b * 256 + t;
    int val = (i < NN) ? cnt_i[i] : 0;
    sh[t] = val;
    __syncthreads();
    for (int off = 1; off < 256; off <<= 1) {
      int tmp = (t >= off) ? sh[t - off] : 0;
      __syncthreads();
      sh[t] += tmp;
      __syncthreads();
    }
    if (i < NN) row_ptr[i] = sh[t] - val;
    if (t == 255) part[b] = sh[255];
  } else {
    int f32 = (*cntp >= 4) ? 1 : 0;
    int wid  = (b - NBLK_SCAN) * 4 + (threadIdx.x >> 6);
    int lane = threadIdx.x & 63;
    if (wid >= 266) return;
    float s = 0.f;
    if (wid < 256) {
      for (int c = lane; c < 256; c += 64)
        s += rdw(W1, (size_t)wid*256 + c, f32) * rdw(W2, c, f32);
    } else if (wid < 265) {
      int t = wid - 256;
      int l = t / 3, j = t % 3;
      for (int c = lane; c < 256; c += 64)
        s += rdw(We, (size_t)l*768 + j*256 + c, f32) * rdw(ae, (size_t)l*256 + c, f32);
    } else {
      for (int c = lane; c < 256; c += 64)
        s += rdw(b1, c, f32) * rdw(W2, c, f32);
    }
    #pragma unroll
    for (int o = 32; o > 0; o >>= 1) s += __shfl_down(s, o);
    if (lane == 0) {
      if (wid < 256)      v[wid] = s;
      else if (wid < 265) wa_all[wid - 256] = s;
      else                *c0 = s + rdw(b2, 0, f32);
    }
  }
}

__global__ __launch_bounds__(128) void k_scan_mid(const int* __restrict__ part,
                                                  int* __restrict__ offs) {
  __shared__ int sh[128];
  int t = threadIdx.x;
  int v = (t < NBLK_SCAN) ? part[t] : 0;
  sh[t] = v;
  __syncthreads();
  for (int off = 1; off < 128; off <<= 1) {
    int tmp = (t >= off) ? sh[t - off] : 0;
    __syncthreads();
    sh[t] += tmp;
    __syncthreads();
  }
  if (t < NBLK_SCAN) offs[t] = sh[t] - v;  // exclusive
}

__global__ void k_scan_add(int* row_ptr, const int* __restrict__ offs, int* cursor) {
  int b = blockIdx.x, t = threadIdx.x;
  int i = b * 256 + t;
  if (i < NN) {
    int v = row_ptr[i] + offs[b];
    row_ptr[i] = v;
    cursor[i]  = v;
  }
  if (i == 0) row_ptr[NN] = NE;
}

__global__ void k_fill(const int* __restrict__ src, const int* __restrict__ dst,
                       int* cursor, int* col_src, int* col_eid) {
  int e = blockIdx.x * 256 + threadIdx.x;
  if (e >= NE) return;
  int pos = atomicAdd(&cursor[dst[e]], 1);
  col_src[pos] = src[e];
  col_eid[pos] = e;
}

// ---------------- merged: atom encoder (blocks 0..29999) + W transpose (30000..) ----------------
__global__ __launch_bounds__(256) void k_atom_prep(const int* __restrict__ x,
                                                   const void* __restrict__ emb,
                                                   float* __restrict__ h,
                                                   unsigned short* __restrict__ hbf,
                                                   const void* __restrict__ W,
                                                   unsigned short* __restrict__ Wt,
                                                   const int* __restrict__ cntp) {
  int f32 = (*cntp >= 4) ? 1 : 0;
  int b = blockIdx.x;
  if (b < NN) {
    int c = threadIdx.x;
    float s = 0.f;
    #pragma unroll
    for (int i = 0; i < 9; ++i) {
      int xi = x[b * 9 + i];
      s += rdw(emb, (size_t)(i * 128 + xi) * 256 + c, f32);
    }
    h[(size_t)b * 256 + c] = s;
    hbf[(size_t)b * 256 + c] = f2bf(s);
  } else {
    int t = (b - NN) * 256 + threadIdx.x;    // 0..196607 = 3*65536
    int l = t >> 16;
    int k = (t >> 8) & 255;
    int c = t & 255;
    Wt[(l << 16) + (c << 8) + k] = f2bf(rdw(W, t, f32));
  }
}

// we_csr[l][j] = e_enc(eid(j)) . wa[l], CSR order (needs col_eid)
__global__ __launch_bounds__(256) void k_we(const int* __restrict__ eattr,
                                            const int* __restrict__ col_eid,
                                            const void* __restrict__ bemb,
                                            const float* __restrict__ wa_all,
                                            float* __restrict__ we_csr,
                                            const int* __restrict__ cntp) {
  int f32 = (*cntp >= 4) ? 1 : 0;
  int j = blockIdx.x * 256 + threadIdx.x;
  if (j >= NE) return;
  int e = col_eid[j];
  int a0 = eattr[e*3], a1 = eattr[e*3+1], a2 = eattr[e*3+2];
  #pragma unroll
  for (int l = 0; l < NLAY; ++l) {
    size_t lb = (size_t)l * 144;
    float e0 = rdw(bemb, lb + (0*16+a0)*3+0, f32) + rdw(bemb, lb + (1*16+a1)*3+0, f32)
             + rdw(bemb, lb + (2*16+a2)*3+0, f32);
    float e1 = rdw(bemb, lb + (0*16+a0)*3+1, f32) + rdw(bemb, lb + (1*16+a1)*3+1, f32)
             + rdw(bemb, lb + (2*16+a2)*3+1, f32);
    float e2 = rdw(bemb, lb + (0*16+a0)*3+2, f32) + rdw(bemb, lb + (1*16+a1)*3+2, f32)
             + rdw(bemb, lb + (2*16+a2)*3+2, f32);
    we_csr[(size_t)l*NE + j] = e0*wa_all[l*3+0] + e1*wa_all[l*3+1] + e2*wa_all[l*3+2];
  }
}

// ---------------- per-layer kernels ----------------

// 48 rows/block, 4 waves = 4 col-slices of 64; B frags reused across 3 row-groups.
__global__ __launch_bounds__(256) void k_gemm_fused(const unsigned short* __restrict__ A,
                                                    const unsigned short* __restrict__ Bt,
                                                    const void* __restrict__ as_w,
                                                    const void* __restrict__ ad_w, int l,
                                                    unsigned short* __restrict__ xlbf,
                                                    float* __restrict__ as_,
                                                    float* __restrict__ ad_,
                                                    const int* __restrict__ cntp) {
  __shared__ unsigned short xtile[GROWS][256];
  __shared__ float sred[4][3][16], dred[4][3][16];   // [wave][rg][row-in-group]
  int b = blockIdx.x;
  int w = threadIdx.x >> 6;
  int lane = threadIdx.x & 63;
  int m0 = b * GROWS;
  int c0 = w * 64;
  int lr = lane & 15;
  int g  = lane >> 4;
  int lk = g * 8;
  f32x4 acc[3][4];
  #pragma unroll
  for (int rg = 0; rg < 3; ++rg)
    #pragma unroll
    for (int q = 0; q < 4; ++q) acc[rg][q] = (f32x4){0.f,0.f,0.f,0.f};

  const unsigned short* brow  = Bt + (size_t)(c0 + lr) * 256 + lk;
  const unsigned short* arow0 = A  + (size_t)(m0 + lr) * 256 + lk;
  #pragma unroll
  for (int k = 0; k < 256; k += 32) {
    bf16x8 b0 = *(const bf16x8*)(brow + k);
    bf16x8 b1 = *(const bf16x8*)(brow + 16*256 + k);
    bf16x8 b2 = *(const bf16x8*)(brow + 32*256 + k);
    bf16x8 b3 = *(const bf16x8*)(brow + 48*256 + k);
    #pragma unroll
    for (int rg = 0; rg < 3; ++rg) {
      bf16x8 a = *(const bf16x8*)(arow0 + (size_t)rg*16*256 + k);
      acc[rg][0] = __builtin_amdgcn_mfma_f32_16x16x32_bf16(a, b0, acc[rg][0], 0,0,0);
      acc[rg][1] = __builtin_amdgcn_mfma_f32_16x16x32_bf16(a, b1, acc[rg][1], 0,0,0);
      acc[rg][2] = __builtin_amdgcn_mfma_f32_16x16x32_bf16(a, b2, acc[rg][2], 0,0,0);
      acc[rg][3] = __builtin_amdgcn_mfma_f32_16x16x32_bf16(a, b3, acc[rg][3], 0,0,0);
    }
  }
  // acc[rg][q][r] = xl[m0 + rg*16 + g*4 + r][c0 + 16q + lr]
  int f32 = (*cntp >= 4) ? 1 : 0;
  float asw[4], adw[4];
  #pragma unroll
  for (int q = 0; q < 4; ++q) {
    asw[q] = rdw(as_w, (size_t)l*256 + c0 + 16*q + lr, f32);
    adw[q] = rdw(ad_w, (size_t)l*256 + c0 + 16*q + lr, f32);
  }
  #pragma unroll
  for (int rg = 0; rg < 3; ++rg) {
    #pragma unroll
    for (int r = 0; r < 4; ++r) {
      float sv = acc[rg][0][r]*asw[0] + acc[rg][1][r]*asw[1]
               + acc[rg][2][r]*asw[2] + acc[rg][3][r]*asw[3];
      float dv = acc[rg][0][r]*adw[0] + acc[rg][1][r]*adw[1]
               + acc[rg][2][r]*adw[2] + acc[rg][3][r]*adw[3];
      #pragma unroll
      for (int o = 1; o < 16; o <<= 1) { sv += __shfl_xor(sv, o); dv += __shfl_xor(dv, o); }
      if (lr == 0) { sred[w][rg][g*4+r] = sv; dred[w][rg][g*4+r] = dv; }
      int row = rg*16 + g*4 + r;
      xtile[row][c0 + lr +  0] = f2bf(acc[rg][0][r]);
      xtile[row][c0 + lr + 16] = f2bf(acc[rg][1][r]);
      xtile[row][c0 + lr + 32] = f2bf(acc[rg][2][r]);
      xtile[row][c0 + lr + 48] = f2bf(acc[rg][3][r]);
    }
  }
  __syncthreads();
  int t = threadIdx.x;
  if (t < GROWS) {
    int rg = t >> 4, rr = t & 15;
    float s = sred[0][rg][rr] + sred[1][rg][rr] + sred[2][rg][rr] + sred[3][rg][rr];
    float d = dred[0][rg][rr] + dred[1][rg][rr] + dred[2][rg][rr] + dred[3][rg][rr];
    as_[m0 + t] = s;
    ad_[m0 + t] = d;
  }
  // flat coalesced copy: 48*256 ushorts = 1536 us8
  {
    const us8* srcp = (const us8*)&xtile[0][0];
    us8* dstp = (us8*)(xlbf + (size_t)m0 * 256);
    #pragma unroll
    for (int u = 0; u < 6; ++u) dstp[t + u*256] = srcp[t + u*256];
  }
}

// fused per-node attention: segment softmax (shift-free, clamped) + aggregation + epilogue.
__global__ __launch_bounds__(256) void k_fused(const int* __restrict__ row_ptr,
                                               const int* __restrict__ col_src,
                                               const float* __restrict__ we_csr,
                                               const float* __restrict__ as_,
                                               const float* __restrict__ ad_,
                                               const unsigned short* __restrict__ xlbf,
                                               const void* __restrict__ bias, int l,
                                               float* __restrict__ h,
                                               unsigned short* __restrict__ hbf,
                                               int do_relu, const int* __restrict__ cntp) {
  int n = blockIdx.x * 4 + (threadIdx.x >> 6);
  int lane = threadIdx.x & 63;
  int beg = row_ptr[n], end = row_ptr[n+1];
  int deg = end - beg;
  float ad_n = ad_[n];

  float dsum_l = 0.f, wesum_l = 0.f;
  float ax = 0.f, ay = 0.f, az = 0.f, aw = 0.f;

  for (int cb = beg; cb < end; cb += 64) {
    int j = cb + lane;
    bool valid = (j < end);
    int s = valid ? col_src[j] : 0;
    float we = valid ? we_csr[j] : 0.f;
    wesum_l += we;
    float p = 0.f;
    if (valid) {
      float a = as_[s] + ad_n + we;
      a = (a >= 0.f) ? a : LEAK * a;
      p = __expf(fmaxf(fminf(a, 60.f), -60.f));
    }
    dsum_l += p;
    int cl = end - cb; if (cl > 64) cl = 64;
    #pragma unroll 4
    for (int jj = 0; jj < cl; ++jj) {
      float ww = __shfl(p, jj);
      int   ss = __shfl(s, jj);
      us4 xv = *(const us4*)(xlbf + (size_t)ss*256 + lane*4);
      ax += ww*bf2f(xv.x); ay += ww*bf2f(xv.y);
      az += ww*bf2f(xv.z); aw += ww*bf2f(xv.w);
    }
  }
  // single reduce of dsum + wesum
  #pragma unroll
  for (int o = 32; o > 0; o >>= 1) {
    dsum_l  += __shfl_xor(dsum_l, o);
    wesum_l += __shfl_xor(wesum_l, o);
  }

  float a_self = as_[n] + ad_n + wesum_l / fmaxf((float)deg, 1.f);
  a_self = (a_self >= 0.f) ? a_self : LEAK * a_self;
  float p_self = __expf(fmaxf(fminf(a_self, 60.f), -60.f));
  float dsum = dsum_l + p_self;
  {
    us4 xv = *(const us4*)(xlbf + (size_t)n*256 + lane*4);
    ax += p_self*bf2f(xv.x); ay += p_self*bf2f(xv.y);
    az += p_self*bf2f(xv.z); aw += p_self*bf2f(xv.w);
  }
  float inv_d = 1.f / dsum;
  ax *= inv_d; ay *= inv_d; az *= inv_d; aw *= inv_d;

  int f32 = (*cntp >= 4) ? 1 : 0;
  int c0 = lane * 4;
  ax += rdw(bias, (size_t)l*256 + c0+0, f32);
  ay += rdw(bias, (size_t)l*256 + c0+1, f32);
  az += rdw(bias, (size_t)l*256 + c0+2, f32);
  aw += rdw(bias, (size_t)l*256 + c0+3, f32);
  if (do_relu) {
    ax = fmaxf(ax, 0.f); ay = fmaxf(ay, 0.f);
    az = fmaxf(az, 0.f); aw = fmaxf(aw, 0.f);
  }
  float* hp = h + (size_t)n*256 + c0;
  float4 hv = *(const float4*)hp;
  float h0 = ax + hv.x, h1 = ay + hv.y, h2 = az + hv.z, h3 = aw + hv.w;
  *(float4*)hp = make_float4(h0, h1, h2, h3);
  us4 q = { f2bf(h0), f2bf(h1), f2bf(h2), f2bf(h3) };
  *(us4*)(hbf + (size_t)n*256 + c0) = q;
}

// ---------------- pooling + head (batch is sorted) ----------------

__global__ __launch_bounds__(256) void k_pool_head(const float* __restrict__ h,
                                                   const int* __restrict__ batch,
                                                   const float* __restrict__ v,
                                                   const float* __restrict__ c0,
                                                   void* __restrict__ out,
                                                   const int* __restrict__ cntp) {
  int g = blockIdx.x;
  int lo = 0, hi = NN;
  while (lo < hi) { int mid = (lo + hi) >> 1; if (batch[mid] < g) lo = mid + 1; else hi = mid; }
  int start = lo;
  lo = 0; hi = NN;
  while (lo < hi) { int mid = (lo + hi) >> 1; if (batch[mid] < g + 1) lo = mid + 1; else hi = mid; }
  int endn = lo;

  int c = threadIdx.x;
  float s = 0.f;
  for (int n = start; n < endn; ++n) s += h[(size_t)n*256 + c];
  __shared__ float red[256];
  red[c] = s * v[c];
  __syncthreads();
  for (int off = 128; off > 0; off >>= 1) {
    if (c < off) red[c] += red[c + off];
    __syncthreads();
  }
  if (c == 0) {
    float cntf = (float)(endn - start);
    float val = red[0] / fmaxf(cntf, 1.f) + *c0;
    if (*cntp >= 4) ((float*)out)[g] = val;
    else            ((unsigned short*)out)[g] = f2bf(val);
  }
}

extern "C" void kernel_launch(void* const* d_in, const int* in_sizes, int n_in,
                              void* d_out, int out_size, void* d_ws, size_t ws_size,
                              hipStream_t stream) {
  const int* x     = (const int*)d_in[0];
  const int* eidx  = (const int*)d_in[1];
  const int* eattr = (const int*)d_in[2];
  const int* batch = (const int*)d_in[3];
  const void* atom_emb = d_in[4];
  const void* bond_emb = d_in[5];
  const void* W        = d_in[6];
  const void* att_src  = d_in[7];
  const void* att_dst  = d_in[8];
  const void* We       = d_in[9];
  const void* att_edge = d_in[10];
  const void* bias     = d_in[11];
  const void* W1 = d_in[12];
  const void* b1 = d_in[13];
  const void* W2 = d_in[14];
  const void* b2 = d_in[15];

  const int* src = eidx;
  const int* dst = eidx + NE;

  char* base = (char*)d_ws;
  size_t off = 0;
  auto alloc = [&](size_t bytes) -> char* {
    char* p = base + off; off += (bytes + 255) & ~(size_t)255; return p;
  };
  float* h    = (float*)alloc((size_t)NN*EMBD*4);
  unsigned short* xlbf = (unsigned short*)alloc((size_t)NN*EMBD*2);
  unsigned short* hbf  = (unsigned short*)alloc((size_t)NN*EMBD*2);
  unsigned short* wt   = (unsigned short*)alloc((size_t)NLAY*EMBD*EMBD*2);
  float* we_csr = (float*)alloc((size_t)NLAY*NE*4);
  float* as_   = (float*)alloc((size_t)NN*4);
  float* ad_   = (float*)alloc((size_t)NN*4);
  float* vvec  = (float*)alloc((size_t)EMBD*4);
  float* c0    = (float*)alloc(4);
  float* wa_all= (float*)alloc(64);
  int*   cnt   = (int*)alloc(4);
  int* cnt_i   = (int*)alloc((size_t)NN*4);
  int* row_ptr = (int*)alloc((size_t)(NN+1)*4);
  int* cursor  = (int*)alloc((size_t)NN*4);
  int* col_src = (int*)alloc((size_t)NE*4);
  int* col_eid = (int*)alloc((size_t)NE*4);
  int* part    = (int*)alloc((size_t)NBLK_SCAN*4);
  int* offs    = (int*)alloc((size_t)NBLK_SCAN*4);

  (void)hipMemsetAsync(cnt, 0, 4, stream);
  (void)hipMemsetAsync(cnt_i, 0, (size_t)NN*4, stream);
  k_sniff_hist<<<16 + (NE+255)/256, 256, 0, stream>>>((const unsigned short*)atom_emb,
                                                      cnt, dst, cnt_i);
  k_scan_dots<<<NBLK_SCAN + 67, 256, 0, stream>>>(cnt_i, row_ptr, part,
                                                  We, att_edge, W1, b1, W2, b2,
                                                  cnt, wa_all, vvec, c0);
  k_scan_mid<<<1, 128, 0, stream>>>(part, offs);
  k_scan_add<<<NBLK_SCAN, 256, 0, stream>>>(row_ptr, offs, cursor);
  k_fill<<<(NE+255)/256, 256, 0, stream>>>(src, dst, cursor, col_src, col_eid);
  k_atom_prep<<<NN + 768, 256, 0, stream>>>(x, atom_emb, h, hbf, W, wt, cnt);
  k_we<<<(NE+255)/256, 256, 0, stream>>>(eattr, col_eid, bond_emb, wa_all, we_csr, cnt);

  for (int l = 0; l < NLAY; ++l) {
    k_gemm_fused<<<NN/GROWS, 256, 0, stream>>>(hbf, wt + (size_t)l*EMBD*EMBD,
                                               att_src, att_dst, l, xlbf, as_, ad_, cnt);
    k_fused<<<NN/4, 256, 0, stream>>>(row_ptr, col_src, we_csr + (size_t)l*NE,
                                      as_, ad_, xlbf, bias, l, h, hbf,
                                      (l < NLAY-1) ? 1 : 0, cnt);
  }

  k_pool_head<<<NG, 256, 0, stream>>>(h, batch, vvec, c0, d_out, cnt);
}

// Round 17
// 440.063 us; speedup vs baseline: 13.7034x; 1.0271x over previous
//
#include <hip/hip_runtime.h>
#include <hip/hip_bf16.h>

#define NN   30000
#define NE   480000
#define EMBD 256
#define NG   512
#define NLAY 3
#define LEAK 0.2f
#define NBLK_SCAN 118   // ceil(NN/256)
#define GROWS 48        // gemm rows per block; 30000 = 625*48

typedef __attribute__((ext_vector_type(8))) short bf16x8;
typedef __attribute__((ext_vector_type(4))) float f32x4;
typedef __attribute__((ext_vector_type(4))) unsigned short us4;
typedef __attribute__((ext_vector_type(8))) unsigned short us8;

__device__ __forceinline__ float bf2f(unsigned short u) {
  union { unsigned int i; float f; } v; v.i = ((unsigned int)u) << 16; return v.f;
}
__device__ __forceinline__ unsigned short f2bf(float f) {
  union { float f; unsigned int i; } v; v.f = f;
  unsigned int u = v.i;
  u += 0x7fffu + ((u >> 16) & 1u);
  return (unsigned short)(u >> 16);
}
__device__ __forceinline__ float rdw(const void* p, size_t i, int f32) {
  return f32 ? ((const float*)p)[i] : bf2f(((const unsigned short*)p)[i]);
}

// ---------------- merged: dtype sniff (blocks 0..15) + degree hist (16..) ----------------
__global__ __launch_bounds__(256) void k_sniff_hist(const unsigned short* __restrict__ w,
                                                    int* cnt, const int* __restrict__ dst,
                                                    int* cnt_i) {
  int b = blockIdx.x;
  if (b < 16) {
    __shared__ int sh;
    if (threadIdx.x == 0) sh = 0;
    __syncthreads();
    int local = 0;
    for (int i = (b * 256 + threadIdx.x) * 2; i < 65536; i += 16 * 256 * 2) {
      unsigned short u = w[i];
      if (((u >> 7) & 0xFF) == 0xFF) local++;
    }
    atomicAdd(&sh, local);
    __syncthreads();
    if (threadIdx.x == 0 && sh) atomicAdd(cnt, sh);
  } else {
    int e = (b - 16) * 256 + threadIdx.x;
    if (e < NE) atomicAdd(&cnt_i[dst[e]], 1);
  }
}

// ---------------- merged: scan phase A (blocks 0..117) + small dots (118..) ----------------
__global__ __launch_bounds__(256) void k_scan_dots(const int* __restrict__ cnt_i,
                                                   int* row_ptr, int* part,
                                                   const void* __restrict__ We,
                                                   const void* __restrict__ ae,
                                                   const void* __restrict__ W1,
                                                   const void* __restrict__ b1,
                                                   const void* __restrict__ W2,
                                                   const void* __restrict__ b2,
                                                   const int* __restrict__ cntp,
                                                   float* __restrict__ wa_all,
                                                   float* __restrict__ v,
                                                   float* __restrict__ c0) {
  int b = blockIdx.x;
  if (b < NBLK_SCAN) {
    __shared__ int sh[256];
    int t = threadIdx.x;
    int i = b * 256 + t;
    int val = (i < NN) ? cnt_i[i] : 0;
    sh[t] = val;
    __syncthreads();
    for (int off = 1; off < 256; off <<= 1) {
      int tmp = (t >= off) ? sh[t - off] : 0;
      __syncthreads();
      sh[t] += tmp;
      __syncthreads();
    }
    if (i < NN) row_ptr[i] = sh[t] - val;
    if (t == 255) part[b] = sh[255];
  } else {
    int f32 = (*cntp >= 4) ? 1 : 0;
    int wid  = (b - NBLK_SCAN) * 4 + (threadIdx.x >> 6);
    int lane = threadIdx.x & 63;
    if (wid >= 266) return;
    float s = 0.f;
    if (wid < 256) {
      for (int c = lane; c < 256; c += 64)
        s += rdw(W1, (size_t)wid*256 + c, f32) * rdw(W2, c, f32);
    } else if (wid < 265) {
      int t = wid - 256;
      int l = t / 3, j = t % 3;
      for (int c = lane; c < 256; c += 64)
        s += rdw(We, (size_t)l*768 + j*256 + c, f32) * rdw(ae, (size_t)l*256 + c, f32);
    } else {
      for (int c = lane; c < 256; c += 64)
        s += rdw(b1, c, f32) * rdw(W2, c, f32);
    }
    #pragma unroll
    for (int o = 32; o > 0; o >>= 1) s += __shfl_down(s, o);
    if (lane == 0) {
      if (wid < 256)      v[wid] = s;
      else if (wid < 265) wa_all[wid - 256] = s;
      else                *c0 = s + rdw(b2, 0, f32);
    }
  }
}

__global__ __launch_bounds__(128) void k_scan_mid(const int* __restrict__ part,
                                                  int* __restrict__ offs) {
  __shared__ int sh[128];
  int t = threadIdx.x;
  int v = (t < NBLK_SCAN) ? part[t] : 0;
  sh[t] = v;
  __syncthreads();
  for (int off = 1; off < 128; off <<= 1) {
    int tmp = (t >= off) ? sh[t - off] : 0;
    __syncthreads();
    sh[t] += tmp;
    __syncthreads();
  }
  if (t < NBLK_SCAN) offs[t] = sh[t] - v;  // exclusive
}

__global__ void k_scan_add(int* row_ptr, const int* __restrict__ offs, int* cursor) {
  int b = blockIdx.x, t = threadIdx.x;
  int i = b * 256 + t;
  if (i < NN) {
    int v = row_ptr[i] + offs[b];
    row_ptr[i] = v;
    cursor[i]  = v;
  }
  if (i == 0) row_ptr[NN] = NE;
}

// fill CSR + compute per-edge attention scalars for all 3 layers (coalesced eattr read)
__global__ void k_fill_we(const int* __restrict__ src, const int* __restrict__ dst,
                          const int* __restrict__ eattr, const void* __restrict__ bemb,
                          const float* __restrict__ wa_all, int* cursor,
                          int* col_src, float* __restrict__ we_csr,
                          const int* __restrict__ cntp) {
  int e = blockIdx.x * 256 + threadIdx.x;
  if (e >= NE) return;
  int f32 = (*cntp >= 4) ? 1 : 0;
  int pos = atomicAdd(&cursor[dst[e]], 1);
  col_src[pos] = src[e];
  int a0 = eattr[e*3], a1 = eattr[e*3+1], a2 = eattr[e*3+2];
  #pragma unroll
  for (int l = 0; l < NLAY; ++l) {
    size_t lb = (size_t)l * 144;
    float e0 = rdw(bemb, lb + (0*16+a0)*3+0, f32) + rdw(bemb, lb + (1*16+a1)*3+0, f32)
             + rdw(bemb, lb + (2*16+a2)*3+0, f32);
    float e1 = rdw(bemb, lb + (0*16+a0)*3+1, f32) + rdw(bemb, lb + (1*16+a1)*3+1, f32)
             + rdw(bemb, lb + (2*16+a2)*3+1, f32);
    float e2 = rdw(bemb, lb + (0*16+a0)*3+2, f32) + rdw(bemb, lb + (1*16+a1)*3+2, f32)
             + rdw(bemb, lb + (2*16+a2)*3+2, f32);
    we_csr[(size_t)l*NE + pos] = e0*wa_all[l*3+0] + e1*wa_all[l*3+1] + e2*wa_all[l*3+2];
  }
}

// ---------------- merged: atom encoder (blocks 0..29999, bf16 out) + W transpose ----------------
__global__ __launch_bounds__(256) void k_atom_prep(const int* __restrict__ x,
                                                   const void* __restrict__ emb,
                                                   unsigned short* __restrict__ hbf,
                                                   const void* __restrict__ W,
                                                   unsigned short* __restrict__ Wt,
                                                   const int* __restrict__ cntp) {
  int f32 = (*cntp >= 4) ? 1 : 0;
  int b = blockIdx.x;
  if (b < NN) {
    int c = threadIdx.x;
    float s = 0.f;
    #pragma unroll
    for (int i = 0; i < 9; ++i) {
      int xi = x[b * 9 + i];
      s += rdw(emb, (size_t)(i * 128 + xi) * 256 + c, f32);
    }
    hbf[(size_t)b * 256 + c] = f2bf(s);
  } else {
    int t = (b - NN) * 256 + threadIdx.x;    // 0..196607 = 3*65536
    int l = t >> 16;
    int k = (t >> 8) & 255;
    int c = t & 255;
    Wt[(l << 16) + (c << 8) + k] = f2bf(rdw(W, t, f32));
  }
}

// ---------------- per-layer kernels ----------------

// 48 rows/block; B frags reused across 3 row-groups.
__global__ __launch_bounds__(256) void k_gemm_fused(const unsigned short* __restrict__ A,
                                                    const unsigned short* __restrict__ Bt,
                                                    const void* __restrict__ as_w,
                                                    const void* __restrict__ ad_w, int l,
                                                    unsigned short* __restrict__ xlbf,
                                                    float* __restrict__ as_,
                                                    float* __restrict__ ad_,
                                                    const int* __restrict__ cntp) {
  __shared__ unsigned short xtile[GROWS][256];
  __shared__ float sred[4][3][16], dred[4][3][16];   // [wave][rg][row-in-group]
  int b = blockIdx.x;
  int w = threadIdx.x >> 6;
  int lane = threadIdx.x & 63;
  int m0 = b * GROWS;
  int c0 = w * 64;
  int lr = lane & 15;
  int g  = lane >> 4;
  int lk = g * 8;
  f32x4 acc[3][4];
  #pragma unroll
  for (int rg = 0; rg < 3; ++rg)
    #pragma unroll
    for (int q = 0; q < 4; ++q) acc[rg][q] = (f32x4){0.f,0.f,0.f,0.f};

  const unsigned short* brow  = Bt + (size_t)(c0 + lr) * 256 + lk;
  const unsigned short* arow0 = A  + (size_t)(m0 + lr) * 256 + lk;
  #pragma unroll
  for (int k = 0; k < 256; k += 32) {
    bf16x8 b0 = *(const bf16x8*)(brow + k);
    bf16x8 b1 = *(const bf16x8*)(brow + 16*256 + k);
    bf16x8 b2 = *(const bf16x8*)(brow + 32*256 + k);
    bf16x8 b3 = *(const bf16x8*)(brow + 48*256 + k);
    #pragma unroll
    for (int rg = 0; rg < 3; ++rg) {
      bf16x8 a = *(const bf16x8*)(arow0 + (size_t)rg*16*256 + k);
      acc[rg][0] = __builtin_amdgcn_mfma_f32_16x16x32_bf16(a, b0, acc[rg][0], 0,0,0);
      acc[rg][1] = __builtin_amdgcn_mfma_f32_16x16x32_bf16(a, b1, acc[rg][1], 0,0,0);
      acc[rg][2] = __builtin_amdgcn_mfma_f32_16x16x32_bf16(a, b2, acc[rg][2], 0,0,0);
      acc[rg][3] = __builtin_amdgcn_mfma_f32_16x16x32_bf16(a, b3, acc[rg][3], 0,0,0);
    }
  }
  int f32 = (*cntp >= 4) ? 1 : 0;
  float asw[4], adw[4];
  #pragma unroll
  for (int q = 0; q < 4; ++q) {
    asw[q] = rdw(as_w, (size_t)l*256 + c0 + 16*q + lr, f32);
    adw[q] = rdw(ad_w, (size_t)l*256 + c0 + 16*q + lr, f32);
  }
  #pragma unroll
  for (int rg = 0; rg < 3; ++rg) {
    #pragma unroll
    for (int r = 0; r < 4; ++r) {
      float sv = acc[rg][0][r]*asw[0] + acc[rg][1][r]*asw[1]
               + acc[rg][2][r]*asw[2] + acc[rg][3][r]*asw[3];
      float dv = acc[rg][0][r]*adw[0] + acc[rg][1][r]*adw[1]
               + acc[rg][2][r]*adw[2] + acc[rg][3][r]*adw[3];
      #pragma unroll
      for (int o = 1; o < 16; o <<= 1) { sv += __shfl_xor(sv, o); dv += __shfl_xor(dv, o); }
      if (lr == 0) { sred[w][rg][g*4+r] = sv; dred[w][rg][g*4+r] = dv; }
      int row = rg*16 + g*4 + r;
      xtile[row][c0 + lr +  0] = f2bf(acc[rg][0][r]);
      xtile[row][c0 + lr + 16] = f2bf(acc[rg][1][r]);
      xtile[row][c0 + lr + 32] = f2bf(acc[rg][2][r]);
      xtile[row][c0 + lr + 48] = f2bf(acc[rg][3][r]);
    }
  }
  __syncthreads();
  int t = threadIdx.x;
  if (t < GROWS) {
    int rg = t >> 4, rr = t & 15;
    float s = sred[0][rg][rr] + sred[1][rg][rr] + sred[2][rg][rr] + sred[3][rg][rr];
    float d = dred[0][rg][rr] + dred[1][rg][rr] + dred[2][rg][rr] + dred[3][rg][rr];
    as_[m0 + t] = s;
    ad_[m0 + t] = d;
  }
  {
    const us8* srcp = (const us8*)&xtile[0][0];
    us8* dstp = (us8*)(xlbf + (size_t)m0 * 256);
    #pragma unroll
    for (int u = 0; u < 6; ++u) dstp[t + u*256] = srcp[t + u*256];
  }
}

// fused per-node attention: clamped segment softmax + gather-aggregate + epilogue,
// residual stream kept in bf16 (hbf) only.
__global__ __launch_bounds__(256) void k_fused(const int* __restrict__ row_ptr,
                                               const int* __restrict__ col_src,
                                               const float* __restrict__ we_csr,
                                               const float* __restrict__ as_,
                                               const float* __restrict__ ad_,
                                               const unsigned short* __restrict__ xlbf,
                                               const void* __restrict__ bias, int l,
                                               unsigned short* __restrict__ hbf,
                                               int do_relu, const int* __restrict__ cntp) {
  int n = blockIdx.x * 4 + (threadIdx.x >> 6);
  int lane = threadIdx.x & 63;
  int beg = row_ptr[n], end = row_ptr[n+1];
  int deg = end - beg;
  float ad_n = ad_[n];

  float dsum_l = 0.f, wesum_l = 0.f;
  float ax = 0.f, ay = 0.f, az = 0.f, aw = 0.f;

  // software-pipelined edge metadata
  int s_cur = 0; float we_cur = 0.f;
  { int j = beg + lane; if (j < end) { s_cur = col_src[j]; we_cur = we_csr[j]; } }

  for (int cb = beg; cb < end; cb += 64) {
    int jn = cb + 64 + lane;
    int s_nxt = 0; float we_nxt = 0.f;
    if (jn < end) { s_nxt = col_src[jn]; we_nxt = we_csr[jn]; }

    bool valid = (cb + lane) < end;
    wesum_l += we_cur;
    float p = 0.f;
    if (valid) {
      float a = as_[s_cur] + ad_n + we_cur;
      a = (a >= 0.f) ? a : LEAK * a;
      p = __expf(fmaxf(fminf(a, 60.f), -60.f));
    }
    dsum_l += p;
    int cl = end - cb; if (cl > 64) cl = 64;
    #pragma unroll 4
    for (int jj = 0; jj < cl; ++jj) {
      float ww = __shfl(p, jj);
      int   ss = __shfl(s_cur, jj);
      us4 xv = *(const us4*)(xlbf + (size_t)ss*256 + lane*4);
      ax += ww*bf2f(xv.x); ay += ww*bf2f(xv.y);
      az += ww*bf2f(xv.z); aw += ww*bf2f(xv.w);
    }
    s_cur = s_nxt; we_cur = we_nxt;
  }
  #pragma unroll
  for (int o = 32; o > 0; o >>= 1) {
    dsum_l  += __shfl_xor(dsum_l, o);
    wesum_l += __shfl_xor(wesum_l, o);
  }

  float a_self = as_[n] + ad_n + wesum_l / fmaxf((float)deg, 1.f);
  a_self = (a_self >= 0.f) ? a_self : LEAK * a_self;
  float p_self = __expf(fmaxf(fminf(a_self, 60.f), -60.f));
  float dsum = dsum_l + p_self;
  {
    us4 xv = *(const us4*)(xlbf + (size_t)n*256 + lane*4);
    ax += p_self*bf2f(xv.x); ay += p_self*bf2f(xv.y);
    az += p_self*bf2f(xv.z); aw += p_self*bf2f(xv.w);
  }
  float inv_d = 1.f / dsum;
  ax *= inv_d; ay *= inv_d; az *= inv_d; aw *= inv_d;

  int f32 = (*cntp >= 4) ? 1 : 0;
  int c0 = lane * 4;
  ax += rdw(bias, (size_t)l*256 + c0+0, f32);
  ay += rdw(bias, (size_t)l*256 + c0+1, f32);
  az += rdw(bias, (size_t)l*256 + c0+2, f32);
  aw += rdw(bias, (size_t)l*256 + c0+3, f32);
  if (do_relu) {
    ax = fmaxf(ax, 0.f); ay = fmaxf(ay, 0.f);
    az = fmaxf(az, 0.f); aw = fmaxf(aw, 0.f);
  }
  unsigned short* hp = hbf + (size_t)n*256 + c0;
  us4 hv = *(const us4*)hp;
  float h0 = ax + bf2f(hv.x), h1 = ay + bf2f(hv.y);
  float h2 = az + bf2f(hv.z), h3 = aw + bf2f(hv.w);
  us4 q = { f2bf(h0), f2bf(h1), f2bf(h2), f2bf(h3) };
  *(us4*)hp = q;
}

// ---------------- pooling + head (batch is sorted; h stream is bf16) ----------------

__global__ __launch_bounds__(256) void k_pool_head(const unsigned short* __restrict__ hbf,
                                                   const int* __restrict__ batch,
                                                   const float* __restrict__ v,
                                                   const float* __restrict__ c0,
                                                   void* __restrict__ out,
                                                   const int* __restrict__ cntp) {
  int g = blockIdx.x;
  int lo = 0, hi = NN;
  while (lo < hi) { int mid = (lo + hi) >> 1; if (batch[mid] < g) lo = mid + 1; else hi = mid; }
  int start = lo;
  lo = 0; hi = NN;
  while (lo < hi) { int mid = (lo + hi) >> 1; if (batch[mid] < g + 1) lo = mid + 1; else hi = mid; }
  int endn = lo;

  int c = threadIdx.x;
  float s = 0.f;
  for (int n = start; n < endn; ++n) s += bf2f(hbf[(size_t)n*256 + c]);
  __shared__ float red[256];
  red[c] = s * v[c];
  __syncthreads();
  for (int off = 128; off > 0; off >>= 1) {
    if (c < off) red[c] += red[c + off];
    __syncthreads();
  }
  if (c == 0) {
    float cntf = (float)(endn - start);
    float val = red[0] / fmaxf(cntf, 1.f) + *c0;
    if (*cntp >= 4) ((float*)out)[g] = val;
    else            ((unsigned short*)out)[g] = f2bf(val);
  }
}

extern "C" void kernel_launch(void* const* d_in, const int* in_sizes, int n_in,
                              void* d_out, int out_size, void* d_ws, size_t ws_size,
                              hipStream_t stream) {
  const int* x     = (const int*)d_in[0];
  const int* eidx  = (const int*)d_in[1];
  const int* eattr = (const int*)d_in[2];
  const int* batch = (const int*)d_in[3];
  const void* atom_emb = d_in[4];
  const void* bond_emb = d_in[5];
  const void* W        = d_in[6];
  const void* att_src  = d_in[7];
  const void* att_dst  = d_in[8];
  const void* We       = d_in[9];
  const void* att_edge = d_in[10];
  const void* bias     = d_in[11];
  const void* W1 = d_in[12];
  const void* b1 = d_in[13];
  const void* W2 = d_in[14];
  const void* b2 = d_in[15];

  const int* src = eidx;
  const int* dst = eidx + NE;

  char* base = (char*)d_ws;
  size_t off = 0;
  auto alloc = [&](size_t bytes) -> char* {
    char* p = base + off; off += (bytes + 255) & ~(size_t)255; return p;
  };
  unsigned short* xlbf = (unsigned short*)alloc((size_t)NN*EMBD*2);
  unsigned short* hbf  = (unsigned short*)alloc((size_t)NN*EMBD*2);
  unsigned short* wt   = (unsigned short*)alloc((size_t)NLAY*EMBD*EMBD*2);
  float* we_csr = (float*)alloc((size_t)NLAY*NE*4);
  float* as_   = (float*)alloc((size_t)NN*4);
  float* ad_   = (float*)alloc((size_t)NN*4);
  float* vvec  = (float*)alloc((size_t)EMBD*4);
  float* c0    = (float*)alloc(4);
  float* wa_all= (float*)alloc(64);
  int*   cnt   = (int*)alloc(4);
  int* cnt_i   = (int*)alloc((size_t)NN*4);
  int* row_ptr = (int*)alloc((size_t)(NN+1)*4);
  int* cursor  = (int*)alloc((size_t)NN*4);
  int* col_src = (int*)alloc((size_t)NE*4);
  int* part    = (int*)alloc((size_t)NBLK_SCAN*4);
  int* offs    = (int*)alloc((size_t)NBLK_SCAN*4);

  (void)hipMemsetAsync(cnt, 0, 4, stream);
  (void)hipMemsetAsync(cnt_i, 0, (size_t)NN*4, stream);
  k_sniff_hist<<<16 + (NE+255)/256, 256, 0, stream>>>((const unsigned short*)atom_emb,
                                                      cnt, dst, cnt_i);
  k_scan_dots<<<NBLK_SCAN + 67, 256, 0, stream>>>(cnt_i, row_ptr, part,
                                                  We, att_edge, W1, b1, W2, b2,
                                                  cnt, wa_all, vvec, c0);
  k_scan_mid<<<1, 128, 0, stream>>>(part, offs);
  k_scan_add<<<NBLK_SCAN, 256, 0, stream>>>(row_ptr, offs, cursor);
  k_fill_we<<<(NE+255)/256, 256, 0, stream>>>(src, dst, eattr, bond_emb, wa_all,
                                              cursor, col_src, we_csr, cnt);
  k_atom_prep<<<NN + 768, 256, 0, stream>>>(x, atom_emb, hbf, W, wt, cnt);

  for (int l = 0; l < NLAY; ++l) {
    k_gemm_fused<<<NN/GROWS, 256, 0, stream>>>(hbf, wt + (size_t)l*EMBD*EMBD,
                                               att_src, att_dst, l, xlbf, as_, ad_, cnt);
    k_fused<<<NN/4, 256, 0, stream>>>(row_ptr, col_src, we_csr + (size_t)l*NE,
                                      as_, ad_, xlbf, bias, l, hbf,
                                      (l < NLAY-1) ? 1 : 0, cnt);
  }

  k_pool_head<<<NG, 256, 0, stream>>>(hbf, batch, vvec, c0, d_out, cnt);
}

// Round 18
// 430.316 us; speedup vs baseline: 14.0138x; 1.0227x over previous
//
#include <hip/hip_runtime.h>
#include <hip/hip_bf16.h>

#define NN   30000
#define NE   480000
#define EMBD 256
#define NG   512
#define NLAY 3
#define LEAK 0.2f
#define NBLK_SCAN 118   // ceil(NN/256)
#define GROWS 48        // gemm rows per block; 30000 = 625*48

typedef __attribute__((ext_vector_type(8))) short bf16x8;
typedef __attribute__((ext_vector_type(4))) float f32x4;
typedef __attribute__((ext_vector_type(4))) unsigned short us4;
typedef __attribute__((ext_vector_type(8))) unsigned short us8;

__device__ __forceinline__ float bf2f(unsigned short u) {
  union { unsigned int i; float f; } v; v.i = ((unsigned int)u) << 16; return v.f;
}
__device__ __forceinline__ unsigned short f2bf(float f) {
  union { float f; unsigned int i; } v; v.f = f;
  unsigned int u = v.i;
  u += 0x7fffu + ((u >> 16) & 1u);
  return (unsigned short)(u >> 16);
}
__device__ __forceinline__ float rdw(const void* p, size_t i, int f32) {
  return f32 ? ((const float*)p)[i] : bf2f(((const unsigned short*)p)[i]);
}

// ---------------- merged: dtype sniff (blocks 0..15) + degree hist (16..) ----------------
__global__ __launch_bounds__(256) void k_sniff_hist(const unsigned short* __restrict__ w,
                                                    int* cnt, const int* __restrict__ dst,
                                                    int* cnt_i) {
  int b = blockIdx.x;
  if (b < 16) {
    __shared__ int sh;
    if (threadIdx.x == 0) sh = 0;
    __syncthreads();
    int local = 0;
    for (int i = (b * 256 + threadIdx.x) * 2; i < 65536; i += 16 * 256 * 2) {
      unsigned short u = w[i];
      if (((u >> 7) & 0xFF) == 0xFF) local++;
    }
    atomicAdd(&sh, local);
    __syncthreads();
    if (threadIdx.x == 0 && sh) atomicAdd(cnt, sh);
  } else {
    int e = (b - 16) * 256 + threadIdx.x;
    if (e < NE) atomicAdd(&cnt_i[dst[e]], 1);
  }
}

// ---------------- merged: scan phase A (blocks 0..117) + small dots (118..) ----------------
__global__ __launch_bounds__(256) void k_scan_dots(const int* __restrict__ cnt_i,
                                                   int* row_ptr, int* part,
                                                   const void* __restrict__ We,
                                                   const void* __restrict__ ae,
                                                   const void* __restrict__ W1,
                                                   const void* __restrict__ b1,
                                                   const void* __restrict__ W2,
                                                   const void* __restrict__ b2,
                                                   const int* __restrict__ cntp,
                                                   float* __restrict__ wa_all,
                                                   float* __restrict__ v,
                                                   float* __restrict__ c0) {
  int b = blockIdx.x;
  if (b < NBLK_SCAN) {
    __shared__ int sh[256];
    int t = threadIdx.x;
    int i = b * 256 + t;
    int val = (i < NN) ? cnt_i[i] : 0;
    sh[t] = val;
    __syncthreads();
    for (int off = 1; off < 256; off <<= 1) {
      int tmp = (t >= off) ? sh[t - off] : 0;
      __syncthreads();
      sh[t] += tmp;
      __syncthreads();
    }
    if (i < NN) row_ptr[i] = sh[t] - val;
    if (t == 255) part[b] = sh[255];
  } else {
    int f32 = (*cntp >= 4) ? 1 : 0;
    int wid  = (b - NBLK_SCAN) * 4 + (threadIdx.x >> 6);
    int lane = threadIdx.x & 63;
    if (wid >= 266) return;
    float s = 0.f;
    if (wid < 256) {
      for (int c = lane; c < 256; c += 64)
        s += rdw(W1, (size_t)wid*256 + c, f32) * rdw(W2, c, f32);
    } else if (wid < 265) {
      int t = wid - 256;
      int l = t / 3, j = t % 3;
      for (int c = lane; c < 256; c += 64)
        s += rdw(We, (size_t)l*768 + j*256 + c, f32) * rdw(ae, (size_t)l*256 + c, f32);
    } else {
      for (int c = lane; c < 256; c += 64)
        s += rdw(b1, c, f32) * rdw(W2, c, f32);
    }
    #pragma unroll
    for (int o = 32; o > 0; o >>= 1) s += __shfl_down(s, o);
    if (lane == 0) {
      if (wid < 256)      v[wid] = s;
      else if (wid < 265) wa_all[wid - 256] = s;
      else                *c0 = s + rdw(b2, 0, f32);
    }
  }
}

__global__ __launch_bounds__(128) void k_scan_mid(const int* __restrict__ part,
                                                  int* __restrict__ offs) {
  __shared__ int sh[128];
  int t = threadIdx.x;
  int v = (t < NBLK_SCAN) ? part[t] : 0;
  sh[t] = v;
  __syncthreads();
  for (int off = 1; off < 128; off <<= 1) {
    int tmp = (t >= off) ? sh[t - off] : 0;
    __syncthreads();
    sh[t] += tmp;
    __syncthreads();
  }
  if (t < NBLK_SCAN) offs[t] = sh[t] - v;  // exclusive
}

__global__ void k_scan_add(int* row_ptr, const int* __restrict__ offs, int* cursor) {
  int b = blockIdx.x, t = threadIdx.x;
  int i = b * 256 + t;
  if (i < NN) {
    int v = row_ptr[i] + offs[b];
    row_ptr[i] = v;
    cursor[i]  = v;
  }
  if (i == 0) row_ptr[NN] = NE;
}

// fill CSR + per-edge record {src, we_l0, we_l1, we_l2} as ONE 16B store
__global__ void k_fill_we(const int* __restrict__ src, const int* __restrict__ dst,
                          const int* __restrict__ eattr, const void* __restrict__ bemb,
                          const float* __restrict__ wa_all, int* cursor,
                          float4* __restrict__ erec, const int* __restrict__ cntp) {
  int e = blockIdx.x * 256 + threadIdx.x;
  if (e >= NE) return;
  int f32 = (*cntp >= 4) ? 1 : 0;
  int pos = atomicAdd(&cursor[dst[e]], 1);
  int a0 = eattr[e*3], a1 = eattr[e*3+1], a2 = eattr[e*3+2];
  float we[NLAY];
  #pragma unroll
  for (int l = 0; l < NLAY; ++l) {
    size_t lb = (size_t)l * 144;
    float e0 = rdw(bemb, lb + (0*16+a0)*3+0, f32) + rdw(bemb, lb + (1*16+a1)*3+0, f32)
             + rdw(bemb, lb + (2*16+a2)*3+0, f32);
    float e1 = rdw(bemb, lb + (0*16+a0)*3+1, f32) + rdw(bemb, lb + (1*16+a1)*3+1, f32)
             + rdw(bemb, lb + (2*16+a2)*3+1, f32);
    float e2 = rdw(bemb, lb + (0*16+a0)*3+2, f32) + rdw(bemb, lb + (1*16+a1)*3+2, f32)
             + rdw(bemb, lb + (2*16+a2)*3+2, f32);
    we[l] = e0*wa_all[l*3+0] + e1*wa_all[l*3+1] + e2*wa_all[l*3+2];
  }
  float4 rec;
  rec.x = __int_as_float(src[e]);
  rec.y = we[0]; rec.z = we[1]; rec.w = we[2];
  erec[pos] = rec;
}

// ---------------- merged: atom encoder (blocks 0..29999, bf16 out) + W transpose ----------------
__global__ __launch_bounds__(256) void k_atom_prep(const int* __restrict__ x,
                                                   const void* __restrict__ emb,
                                                   unsigned short* __restrict__ hbf,
                                                   const void* __restrict__ W,
                                                   unsigned short* __restrict__ Wt,
                                                   const int* __restrict__ cntp) {
  int f32 = (*cntp >= 4) ? 1 : 0;
  int b = blockIdx.x;
  if (b < NN) {
    int c = threadIdx.x;
    float s = 0.f;
    #pragma unroll
    for (int i = 0; i < 9; ++i) {
      int xi = x[b * 9 + i];
      s += rdw(emb, (size_t)(i * 128 + xi) * 256 + c, f32);
    }
    hbf[(size_t)b * 256 + c] = f2bf(s);
  } else {
    int t = (b - NN) * 256 + threadIdx.x;    // 0..196607 = 3*65536
    int l = t >> 16;
    int k = (t >> 8) & 255;
    int c = t & 255;
    Wt[(l << 16) + (c << 8) + k] = f2bf(rdw(W, t, f32));
  }
}

// ---------------- per-layer kernels ----------------

// 48 rows/block; B frags reused across 3 row-groups.
__global__ __launch_bounds__(256) void k_gemm_fused(const unsigned short* __restrict__ A,
                                                    const unsigned short* __restrict__ Bt,
                                                    const void* __restrict__ as_w,
                                                    const void* __restrict__ ad_w, int l,
                                                    unsigned short* __restrict__ xlbf,
                                                    float* __restrict__ as_,
                                                    float* __restrict__ ad_,
                                                    const int* __restrict__ cntp) {
  __shared__ unsigned short xtile[GROWS][256];
  __shared__ float sred[4][3][16], dred[4][3][16];   // [wave][rg][row-in-group]
  int b = blockIdx.x;
  int w = threadIdx.x >> 6;
  int lane = threadIdx.x & 63;
  int m0 = b * GROWS;
  int c0 = w * 64;
  int lr = lane & 15;
  int g  = lane >> 4;
  int lk = g * 8;
  f32x4 acc[3][4];
  #pragma unroll
  for (int rg = 0; rg < 3; ++rg)
    #pragma unroll
    for (int q = 0; q < 4; ++q) acc[rg][q] = (f32x4){0.f,0.f,0.f,0.f};

  const unsigned short* brow  = Bt + (size_t)(c0 + lr) * 256 + lk;
  const unsigned short* arow0 = A  + (size_t)(m0 + lr) * 256 + lk;
  #pragma unroll
  for (int k = 0; k < 256; k += 32) {
    bf16x8 b0 = *(const bf16x8*)(brow + k);
    bf16x8 b1 = *(const bf16x8*)(brow + 16*256 + k);
    bf16x8 b2 = *(const bf16x8*)(brow + 32*256 + k);
    bf16x8 b3 = *(const bf16x8*)(brow + 48*256 + k);
    #pragma unroll
    for (int rg = 0; rg < 3; ++rg) {
      bf16x8 a = *(const bf16x8*)(arow0 + (size_t)rg*16*256 + k);
      acc[rg][0] = __builtin_amdgcn_mfma_f32_16x16x32_bf16(a, b0, acc[rg][0], 0,0,0);
      acc[rg][1] = __builtin_amdgcn_mfma_f32_16x16x32_bf16(a, b1, acc[rg][1], 0,0,0);
      acc[rg][2] = __builtin_amdgcn_mfma_f32_16x16x32_bf16(a, b2, acc[rg][2], 0,0,0);
      acc[rg][3] = __builtin_amdgcn_mfma_f32_16x16x32_bf16(a, b3, acc[rg][3], 0,0,0);
    }
  }
  int f32 = (*cntp >= 4) ? 1 : 0;
  float asw[4], adw[4];
  #pragma unroll
  for (int q = 0; q < 4; ++q) {
    asw[q] = rdw(as_w, (size_t)l*256 + c0 + 16*q + lr, f32);
    adw[q] = rdw(ad_w, (size_t)l*256 + c0 + 16*q + lr, f32);
  }
  #pragma unroll
  for (int rg = 0; rg < 3; ++rg) {
    #pragma unroll
    for (int r = 0; r < 4; ++r) {
      float sv = acc[rg][0][r]*asw[0] + acc[rg][1][r]*asw[1]
               + acc[rg][2][r]*asw[2] + acc[rg][3][r]*asw[3];
      float dv = acc[rg][0][r]*adw[0] + acc[rg][1][r]*adw[1]
               + acc[rg][2][r]*adw[2] + acc[rg][3][r]*adw[3];
      #pragma unroll
      for (int o = 1; o < 16; o <<= 1) { sv += __shfl_xor(sv, o); dv += __shfl_xor(dv, o); }
      if (lr == 0) { sred[w][rg][g*4+r] = sv; dred[w][rg][g*4+r] = dv; }
      int row = rg*16 + g*4 + r;
      xtile[row][c0 + lr +  0] = f2bf(acc[rg][0][r]);
      xtile[row][c0 + lr + 16] = f2bf(acc[rg][1][r]);
      xtile[row][c0 + lr + 32] = f2bf(acc[rg][2][r]);
      xtile[row][c0 + lr + 48] = f2bf(acc[rg][3][r]);
    }
  }
  __syncthreads();
  int t = threadIdx.x;
  if (t < GROWS) {
    int rg = t >> 4, rr = t & 15;
    float s = sred[0][rg][rr] + sred[1][rg][rr] + sred[2][rg][rr] + sred[3][rg][rr];
    float d = dred[0][rg][rr] + dred[1][rg][rr] + dred[2][rg][rr] + dred[3][rg][rr];
    as_[m0 + t] = s;
    ad_[m0 + t] = d;
  }
  {
    const us8* srcp = (const us8*)&xtile[0][0];
    us8* dstp = (us8*)(xlbf + (size_t)m0 * 256);
    #pragma unroll
    for (int u = 0; u < 6; ++u) dstp[t + u*256] = srcp[t + u*256];
  }
}

// fused per-node attention: clamped segment softmax + gather-aggregate + epilogue,
// bf16 residual stream; 16B AoS edge records.
__global__ __launch_bounds__(256) void k_fused(const int* __restrict__ row_ptr,
                                               const float4* __restrict__ erec,
                                               const float* __restrict__ as_,
                                               const float* __restrict__ ad_,
                                               const unsigned short* __restrict__ xlbf,
                                               const void* __restrict__ bias, int l,
                                               unsigned short* __restrict__ hbf,
                                               int do_relu, const int* __restrict__ cntp) {
  int n = blockIdx.x * 4 + (threadIdx.x >> 6);
  int lane = threadIdx.x & 63;
  int beg = row_ptr[n], end = row_ptr[n+1];
  int deg = end - beg;
  float ad_n = ad_[n];

  float dsum_l = 0.f, wesum_l = 0.f;
  float ax = 0.f, ay = 0.f, az = 0.f, aw = 0.f;

  // software-pipelined edge records
  int s_cur = 0; float we_cur = 0.f;
  {
    int j = beg + lane;
    if (j < end) {
      float4 rec = erec[j];
      s_cur = __float_as_int(rec.x);
      we_cur = (l == 0) ? rec.y : ((l == 1) ? rec.z : rec.w);
    }
  }

  for (int cb = beg; cb < end; cb += 64) {
    int jn = cb + 64 + lane;
    int s_nxt = 0; float we_nxt = 0.f;
    if (jn < end) {
      float4 rec = erec[jn];
      s_nxt = __float_as_int(rec.x);
      we_nxt = (l == 0) ? rec.y : ((l == 1) ? rec.z : rec.w);
    }

    bool valid = (cb + lane) < end;
    wesum_l += we_cur;
    float p = 0.f;
    if (valid) {
      float a = as_[s_cur] + ad_n + we_cur;
      a = (a >= 0.f) ? a : LEAK * a;
      p = __expf(fmaxf(fminf(a, 60.f), -60.f));
    }
    dsum_l += p;
    int cl = end - cb; if (cl > 64) cl = 64;
    #pragma unroll 4
    for (int jj = 0; jj < cl; ++jj) {
      float ww = __shfl(p, jj);
      int   ss = __shfl(s_cur, jj);
      us4 xv = *(const us4*)(xlbf + (size_t)ss*256 + lane*4);
      ax += ww*bf2f(xv.x); ay += ww*bf2f(xv.y);
      az += ww*bf2f(xv.z); aw += ww*bf2f(xv.w);
    }
    s_cur = s_nxt; we_cur = we_nxt;
  }
  #pragma unroll
  for (int o = 32; o > 0; o >>= 1) {
    dsum_l  += __shfl_xor(dsum_l, o);
    wesum_l += __shfl_xor(wesum_l, o);
  }

  float a_self = as_[n] + ad_n + wesum_l / fmaxf((float)deg, 1.f);
  a_self = (a_self >= 0.f) ? a_self : LEAK * a_self;
  float p_self = __expf(fmaxf(fminf(a_self, 60.f), -60.f));
  float dsum = dsum_l + p_self;
  {
    us4 xv = *(const us4*)(xlbf + (size_t)n*256 + lane*4);
    ax += p_self*bf2f(xv.x); ay += p_self*bf2f(xv.y);
    az += p_self*bf2f(xv.z); aw += p_self*bf2f(xv.w);
  }
  float inv_d = 1.f / dsum;
  ax *= inv_d; ay *= inv_d; az *= inv_d; aw *= inv_d;

  int f32 = (*cntp >= 4) ? 1 : 0;
  int c0 = lane * 4;
  ax += rdw(bias, (size_t)l*256 + c0+0, f32);
  ay += rdw(bias, (size_t)l*256 + c0+1, f32);
  az += rdw(bias, (size_t)l*256 + c0+2, f32);
  aw += rdw(bias, (size_t)l*256 + c0+3, f32);
  if (do_relu) {
    ax = fmaxf(ax, 0.f); ay = fmaxf(ay, 0.f);
    az = fmaxf(az, 0.f); aw = fmaxf(aw, 0.f);
  }
  unsigned short* hp = hbf + (size_t)n*256 + c0;
  us4 hv = *(const us4*)hp;
  float h0 = ax + bf2f(hv.x), h1 = ay + bf2f(hv.y);
  float h2 = az + bf2f(hv.z), h3 = aw + bf2f(hv.w);
  us4 q = { f2bf(h0), f2bf(h1), f2bf(h2), f2bf(h3) };
  *(us4*)hp = q;
}

// ---------------- pooling + head (batch is sorted; h stream is bf16) ----------------

__global__ __launch_bounds__(256) void k_pool_head(const unsigned short* __restrict__ hbf,
                                                   const int* __restrict__ batch,
                                                   const float* __restrict__ v,
                                                   const float* __restrict__ c0,
                                                   void* __restrict__ out,
                                                   const int* __restrict__ cntp) {
  int g = blockIdx.x;
  int lo = 0, hi = NN;
  while (lo < hi) { int mid = (lo + hi) >> 1; if (batch[mid] < g) lo = mid + 1; else hi = mid; }
  int start = lo;
  lo = 0; hi = NN;
  while (lo < hi) { int mid = (lo + hi) >> 1; if (batch[mid] < g + 1) lo = mid + 1; else hi = mid; }
  int endn = lo;

  int c = threadIdx.x;
  float s = 0.f;
  for (int n = start; n < endn; ++n) s += bf2f(hbf[(size_t)n*256 + c]);
  __shared__ float red[256];
  red[c] = s * v[c];
  __syncthreads();
  for (int off = 128; off > 0; off >>= 1) {
    if (c < off) red[c] += red[c + off];
    __syncthreads();
  }
  if (c == 0) {
    float cntf = (float)(endn - start);
    float val = red[0] / fmaxf(cntf, 1.f) + *c0;
    if (*cntp >= 4) ((float*)out)[g] = val;
    else            ((unsigned short*)out)[g] = f2bf(val);
  }
}

extern "C" void kernel_launch(void* const* d_in, const int* in_sizes, int n_in,
                              void* d_out, int out_size, void* d_ws, size_t ws_size,
                              hipStream_t stream) {
  const int* x     = (const int*)d_in[0];
  const int* eidx  = (const int*)d_in[1];
  const int* eattr = (const int*)d_in[2];
  const int* batch = (const int*)d_in[3];
  const void* atom_emb = d_in[4];
  const void* bond_emb = d_in[5];
  const void* W        = d_in[6];
  const void* att_src  = d_in[7];
  const void* att_dst  = d_in[8];
  const void* We       = d_in[9];
  const void* att_edge = d_in[10];
  const void* bias     = d_in[11];
  const void* W1 = d_in[12];
  const void* b1 = d_in[13];
  const void* W2 = d_in[14];
  const void* b2 = d_in[15];

  const int* src = eidx;
  const int* dst = eidx + NE;

  char* base = (char*)d_ws;
  size_t off = 0;
  auto alloc = [&](size_t bytes) -> char* {
    char* p = base + off; off += (bytes + 255) & ~(size_t)255; return p;
  };
  unsigned short* xlbf = (unsigned short*)alloc((size_t)NN*EMBD*2);
  unsigned short* hbf  = (unsigned short*)alloc((size_t)NN*EMBD*2);
  unsigned short* wt   = (unsigned short*)alloc((size_t)NLAY*EMBD*EMBD*2);
  float4* erec = (float4*)alloc((size_t)NE*16);
  float* as_   = (float*)alloc((size_t)NN*4);
  float* ad_   = (float*)alloc((size_t)NN*4);
  float* vvec  = (float*)alloc((size_t)EMBD*4);
  float* c0    = (float*)alloc(4);
  float* wa_all= (float*)alloc(64);
  int*   cnt   = (int*)alloc(4);
  int* cnt_i   = (int*)alloc((size_t)NN*4);
  int* row_ptr = (int*)alloc((size_t)(NN+1)*4);
  int* cursor  = (int*)alloc((size_t)NN*4);
  int* part    = (int*)alloc((size_t)NBLK_SCAN*4);
  int* offs    = (int*)alloc((size_t)NBLK_SCAN*4);

  (void)hipMemsetAsync(cnt, 0, 4, stream);
  (void)hipMemsetAsync(cnt_i, 0, (size_t)NN*4, stream);
  k_sniff_hist<<<16 + (NE+255)/256, 256, 0, stream>>>((const unsigned short*)atom_emb,
                                                      cnt, dst, cnt_i);
  k_scan_dots<<<NBLK_SCAN + 67, 256, 0, stream>>>(cnt_i, row_ptr, part,
                                                  We, att_edge, W1, b1, W2, b2,
                                                  cnt, wa_all, vvec, c0);
  k_scan_mid<<<1, 128, 0, stream>>>(part, offs);
  k_scan_add<<<NBLK_SCAN, 256, 0, stream>>>(row_ptr, offs, cursor);
  k_fill_we<<<(NE+255)/256, 256, 0, stream>>>(src, dst, eattr, bond_emb, wa_all,
                                              cursor, erec, cnt);
  k_atom_prep<<<NN + 768, 256, 0, stream>>>(x, atom_emb, hbf, W, wt, cnt);

  for (int l = 0; l < NLAY; ++l) {
    k_gemm_fused<<<NN/GROWS, 256, 0, stream>>>(hbf, wt + (size_t)l*EMBD*EMBD,
                                               att_src, att_dst, l, xlbf, as_, ad_, cnt);
    k_fused<<<NN/4, 256, 0, stream>>>(row_ptr, erec, as_, ad_, xlbf, bias, l, hbf,
                                      (l < NLAY-1) ? 1 : 0, cnt);
  }

  k_pool_head<<<NG, 256, 0, stream>>>(hbf, batch, vvec, c0, d_out, cnt);
}

// Round 19
// 417.978 us; speedup vs baseline: 14.4275x; 1.0295x over previous
//
#include <hip/hip_runtime.h>
#include <hip/hip_bf16.h>

#define NN   30000
#define NE   480000
#define EMBD 256
#define NG   512
#define NLAY 3
#define LEAK 0.2f
#define NBLK_SCAN 118   // ceil(NN/256)
#define GROWS 48        // gemm rows per block; 30000 = 625*48

typedef __attribute__((ext_vector_type(8))) short bf16x8;
typedef __attribute__((ext_vector_type(4))) float f32x4;
typedef __attribute__((ext_vector_type(4))) unsigned short us4;
typedef __attribute__((ext_vector_type(8))) unsigned short us8;

__device__ __forceinline__ float bf2f(unsigned short u) {
  union { unsigned int i; float f; } v; v.i = ((unsigned int)u) << 16; return v.f;
}
__device__ __forceinline__ unsigned short f2bf(float f) {
  union { float f; unsigned int i; } v; v.f = f;
  unsigned int u = v.i;
  u += 0x7fffu + ((u >> 16) & 1u);
  return (unsigned short)(u >> 16);
}
__device__ __forceinline__ float rdw(const void* p, size_t i, int f32) {
  return f32 ? ((const float*)p)[i] : bf2f(((const unsigned short*)p)[i]);
}

// ---------------- merged: dtype sniff (blocks 0..15) + degree hist (16..) ----------------
__global__ __launch_bounds__(256) void k_sniff_hist(const unsigned short* __restrict__ w,
                                                    int* cnt, const int* __restrict__ dst,
                                                    int* cnt_i) {
  int b = blockIdx.x;
  if (b < 16) {
    __shared__ int sh;
    if (threadIdx.x == 0) sh = 0;
    __syncthreads();
    int local = 0;
    for (int i = (b * 256 + threadIdx.x) * 2; i < 65536; i += 16 * 256 * 2) {
      unsigned short u = w[i];
      if (((u >> 7) & 0xFF) == 0xFF) local++;
    }
    atomicAdd(&sh, local);
    __syncthreads();
    if (threadIdx.x == 0 && sh) atomicAdd(cnt, sh);
  } else {
    int e = (b - 16) * 256 + threadIdx.x;
    if (e < NE) atomicAdd(&cnt_i[dst[e]], 1);
  }
}

// ---------------- merged: scan phase A (blocks 0..117) + small dots (118..) ----------------
__global__ __launch_bounds__(256) void k_scan_dots(const int* __restrict__ cnt_i,
                                                   int* row_ptr, int* part,
                                                   const void* __restrict__ We,
                                                   const void* __restrict__ ae,
                                                   const void* __restrict__ W1,
                                                   const void* __restrict__ b1,
                                                   const void* __restrict__ W2,
                                                   const void* __restrict__ b2,
                                                   const int* __restrict__ cntp,
                                                   float* __restrict__ wa_all,
                                                   float* __restrict__ v,
                                                   float* __restrict__ c0) {
  int b = blockIdx.x;
  if (b < NBLK_SCAN) {
    __shared__ int sh[256];
    int t = threadIdx.x;
    int i = b * 256 + t;
    int val = (i < NN) ? cnt_i[i] : 0;
    sh[t] = val;
    __syncthreads();
    for (int off = 1; off < 256; off <<= 1) {
      int tmp = (t >= off) ? sh[t - off] : 0;
      __syncthreads();
      sh[t] += tmp;
      __syncthreads();
    }
    if (i < NN) row_ptr[i] = sh[t] - val;
    if (t == 255) part[b] = sh[255];
  } else {
    int f32 = (*cntp >= 4) ? 1 : 0;
    int wid  = (b - NBLK_SCAN) * 4 + (threadIdx.x >> 6);
    int lane = threadIdx.x & 63;
    if (wid >= 266) return;
    float s = 0.f;
    if (wid < 256) {
      for (int c = lane; c < 256; c += 64)
        s += rdw(W1, (size_t)wid*256 + c, f32) * rdw(W2, c, f32);
    } else if (wid < 265) {
      int t = wid - 256;
      int l = t / 3, j = t % 3;
      for (int c = lane; c < 256; c += 64)
        s += rdw(We, (size_t)l*768 + j*256 + c, f32) * rdw(ae, (size_t)l*256 + c, f32);
    } else {
      for (int c = lane; c < 256; c += 64)
        s += rdw(b1, c, f32) * rdw(W2, c, f32);
    }
    #pragma unroll
    for (int o = 32; o > 0; o >>= 1) s += __shfl_down(s, o);
    if (lane == 0) {
      if (wid < 256)      v[wid] = s;
      else if (wid < 265) wa_all[wid - 256] = s;
      else                *c0 = s + rdw(b2, 0, f32);
    }
  }
}

__global__ __launch_bounds__(128) void k_scan_mid(const int* __restrict__ part,
                                                  int* __restrict__ offs) {
  __shared__ int sh[128];
  int t = threadIdx.x;
  int v = (t < NBLK_SCAN) ? part[t] : 0;
  sh[t] = v;
  __syncthreads();
  for (int off = 1; off < 128; off <<= 1) {
    int tmp = (t >= off) ? sh[t - off] : 0;
    __syncthreads();
    sh[t] += tmp;
    __syncthreads();
  }
  if (t < NBLK_SCAN) offs[t] = sh[t] - v;  // exclusive
}

__global__ void k_scan_add(int* row_ptr, const int* __restrict__ offs, int* cursor) {
  int b = blockIdx.x, t = threadIdx.x;
  int i = b * 256 + t;
  if (i < NN) {
    int v = row_ptr[i] + offs[b];
    row_ptr[i] = v;
    cursor[i]  = v;
  }
  if (i == 0) row_ptr[NN] = NE;
}

// fill CSR + per-edge record {src, we_l0, we_l1, we_l2} as ONE 16B store
__global__ void k_fill_we(const int* __restrict__ src, const int* __restrict__ dst,
                          const int* __restrict__ eattr, const void* __restrict__ bemb,
                          const float* __restrict__ wa_all, int* cursor,
                          float4* __restrict__ erec, const int* __restrict__ cntp) {
  int e = blockIdx.x * 256 + threadIdx.x;
  if (e >= NE) return;
  int f32 = (*cntp >= 4) ? 1 : 0;
  int pos = atomicAdd(&cursor[dst[e]], 1);
  int a0 = eattr[e*3], a1 = eattr[e*3+1], a2 = eattr[e*3+2];
  float we[NLAY];
  #pragma unroll
  for (int l = 0; l < NLAY; ++l) {
    size_t lb = (size_t)l * 144;
    float e0 = rdw(bemb, lb + (0*16+a0)*3+0, f32) + rdw(bemb, lb + (1*16+a1)*3+0, f32)
             + rdw(bemb, lb + (2*16+a2)*3+0, f32);
    float e1 = rdw(bemb, lb + (0*16+a0)*3+1, f32) + rdw(bemb, lb + (1*16+a1)*3+1, f32)
             + rdw(bemb, lb + (2*16+a2)*3+1, f32);
    float e2 = rdw(bemb, lb + (0*16+a0)*3+2, f32) + rdw(bemb, lb + (1*16+a1)*3+2, f32)
             + rdw(bemb, lb + (2*16+a2)*3+2, f32);
    we[l] = e0*wa_all[l*3+0] + e1*wa_all[l*3+1] + e2*wa_all[l*3+2];
  }
  float4 rec;
  rec.x = __int_as_float(src[e]);
  rec.y = we[0]; rec.z = we[1]; rec.w = we[2];
  erec[pos] = rec;
}

// ---------------- merged: atom encoder (blocks 0..29999, bf16 out) + W transpose ----------------
__global__ __launch_bounds__(256) void k_atom_prep(const int* __restrict__ x,
                                                   const void* __restrict__ emb,
                                                   unsigned short* __restrict__ hbf,
                                                   const void* __restrict__ W,
                                                   unsigned short* __restrict__ Wt,
                                                   const int* __restrict__ cntp) {
  int f32 = (*cntp >= 4) ? 1 : 0;
  int b = blockIdx.x;
  if (b < NN) {
    int c = threadIdx.x;
    float s = 0.f;
    #pragma unroll
    for (int i = 0; i < 9; ++i) {
      int xi = x[b * 9 + i];
      s += rdw(emb, (size_t)(i * 128 + xi) * 256 + c, f32);
    }
    hbf[(size_t)b * 256 + c] = f2bf(s);
  } else {
    int t = (b - NN) * 256 + threadIdx.x;    // 0..196607 = 3*65536
    int l = t >> 16;
    int k = (t >> 8) & 255;
    int c = t & 255;
    Wt[(l << 16) + (c << 8) + k] = f2bf(rdw(W, t, f32));
  }
}

// ---------------- per-layer kernels ----------------

// 48 rows/block; B frags reused across 3 row-groups.
__global__ __launch_bounds__(256) void k_gemm_fused(const unsigned short* __restrict__ A,
                                                    const unsigned short* __restrict__ Bt,
                                                    const void* __restrict__ as_w,
                                                    const void* __restrict__ ad_w, int l,
                                                    unsigned short* __restrict__ xlbf,
                                                    float* __restrict__ as_,
                                                    float* __restrict__ ad_,
                                                    const int* __restrict__ cntp) {
  __shared__ unsigned short xtile[GROWS][256];
  __shared__ float sred[4][3][16], dred[4][3][16];   // [wave][rg][row-in-group]
  int b = blockIdx.x;
  int w = threadIdx.x >> 6;
  int lane = threadIdx.x & 63;
  int m0 = b * GROWS;
  int c0 = w * 64;
  int lr = lane & 15;
  int g  = lane >> 4;
  int lk = g * 8;
  f32x4 acc[3][4];
  #pragma unroll
  for (int rg = 0; rg < 3; ++rg)
    #pragma unroll
    for (int q = 0; q < 4; ++q) acc[rg][q] = (f32x4){0.f,0.f,0.f,0.f};

  const unsigned short* brow  = Bt + (size_t)(c0 + lr) * 256 + lk;
  const unsigned short* arow0 = A  + (size_t)(m0 + lr) * 256 + lk;
  #pragma unroll
  for (int k = 0; k < 256; k += 32) {
    bf16x8 b0 = *(const bf16x8*)(brow + k);
    bf16x8 b1 = *(const bf16x8*)(brow + 16*256 + k);
    bf16x8 b2 = *(const bf16x8*)(brow + 32*256 + k);
    bf16x8 b3 = *(const bf16x8*)(brow + 48*256 + k);
    #pragma unroll
    for (int rg = 0; rg < 3; ++rg) {
      bf16x8 a = *(const bf16x8*)(arow0 + (size_t)rg*16*256 + k);
      acc[rg][0] = __builtin_amdgcn_mfma_f32_16x16x32_bf16(a, b0, acc[rg][0], 0,0,0);
      acc[rg][1] = __builtin_amdgcn_mfma_f32_16x16x32_bf16(a, b1, acc[rg][1], 0,0,0);
      acc[rg][2] = __builtin_amdgcn_mfma_f32_16x16x32_bf16(a, b2, acc[rg][2], 0,0,0);
      acc[rg][3] = __builtin_amdgcn_mfma_f32_16x16x32_bf16(a, b3, acc[rg][3], 0,0,0);
    }
  }
  int f32 = (*cntp >= 4) ? 1 : 0;
  float asw[4], adw[4];
  #pragma unroll
  for (int q = 0; q < 4; ++q) {
    asw[q] = rdw(as_w, (size_t)l*256 + c0 + 16*q + lr, f32);
    adw[q] = rdw(ad_w, (size_t)l*256 + c0 + 16*q + lr, f32);
  }
  #pragma unroll
  for (int rg = 0; rg < 3; ++rg) {
    #pragma unroll
    for (int r = 0; r < 4; ++r) {
      float sv = acc[rg][0][r]*asw[0] + acc[rg][1][r]*asw[1]
               + acc[rg][2][r]*asw[2] + acc[rg][3][r]*asw[3];
      float dv = acc[rg][0][r]*adw[0] + acc[rg][1][r]*adw[1]
               + acc[rg][2][r]*adw[2] + acc[rg][3][r]*adw[3];
      #pragma unroll
      for (int o = 1; o < 16; o <<= 1) { sv += __shfl_xor(sv, o); dv += __shfl_xor(dv, o); }
      if (lr == 0) { sred[w][rg][g*4+r] = sv; dred[w][rg][g*4+r] = dv; }
      int row = rg*16 + g*4 + r;
      xtile[row][c0 + lr +  0] = f2bf(acc[rg][0][r]);
      xtile[row][c0 + lr + 16] = f2bf(acc[rg][1][r]);
      xtile[row][c0 + lr + 32] = f2bf(acc[rg][2][r]);
      xtile[row][c0 + lr + 48] = f2bf(acc[rg][3][r]);
    }
  }
  __syncthreads();
  int t = threadIdx.x;
  if (t < GROWS) {
    int rg = t >> 4, rr = t & 15;
    float s = sred[0][rg][rr] + sred[1][rg][rr] + sred[2][rg][rr] + sred[3][rg][rr];
    float d = dred[0][rg][rr] + dred[1][rg][rr] + dred[2][rg][rr] + dred[3][rg][rr];
    as_[m0 + t] = s;
    ad_[m0 + t] = d;
  }
  {
    const us8* srcp = (const us8*)&xtile[0][0];
    us8* dstp = (us8*)(xlbf + (size_t)m0 * 256);
    #pragma unroll
    for (int u = 0; u < 6; ++u) dstp[t + u*256] = srcp[t + u*256];
  }
}

// fused per-node attention: clamped segment softmax + half-wave 2-edge us8 gather +
// epilogue; bf16 residual stream; 16B AoS edge records.
__global__ __launch_bounds__(256) void k_fused(const int* __restrict__ row_ptr,
                                               const float4* __restrict__ erec,
                                               const float* __restrict__ as_,
                                               const float* __restrict__ ad_,
                                               const unsigned short* __restrict__ xlbf,
                                               const void* __restrict__ bias, int l,
                                               unsigned short* __restrict__ hbf,
                                               int do_relu, const int* __restrict__ cntp) {
  int n = blockIdx.x * 4 + (threadIdx.x >> 6);
  int lane = threadIdx.x & 63;
  int half = lane >> 5;        // 0: even edges, 1: odd edges
  int colb = (lane & 31) * 8;  // 8 columns per lane
  int beg = row_ptr[n], end = row_ptr[n+1];
  int deg = end - beg;
  float ad_n = ad_[n];

  float dsum_l = 0.f, wesum_l = 0.f;
  float acc8[8];
  #pragma unroll
  for (int i = 0; i < 8; ++i) acc8[i] = 0.f;

  // software-pipelined edge records (one per lane, 64 edges per chunk)
  int s_cur = 0; float we_cur = 0.f;
  {
    int j = beg + lane;
    if (j < end) {
      float4 rec = erec[j];
      s_cur = __float_as_int(rec.x);
      we_cur = (l == 0) ? rec.y : ((l == 1) ? rec.z : rec.w);
    }
  }

  for (int cb = beg; cb < end; cb += 64) {
    int jn = cb + 64 + lane;
    int s_nxt = 0; float we_nxt = 0.f;
    if (jn < end) {
      float4 rec = erec[jn];
      s_nxt = __float_as_int(rec.x);
      we_nxt = (l == 0) ? rec.y : ((l == 1) ? rec.z : rec.w);
    }

    bool valid = (cb + lane) < end;
    wesum_l += we_cur;
    float p = 0.f;
    if (valid) {
      float a = as_[s_cur] + ad_n + we_cur;
      a = (a >= 0.f) ? a : LEAK * a;
      p = __expf(fmaxf(fminf(a, 60.f), -60.f));
    }
    dsum_l += p;
    int cl = end - cb; if (cl > 64) cl = 64;
    // half-wave 2-edge gather: lanes 0-31 edge jj, lanes 32-63 edge jj+1.
    // invalid edges have p==0 (FMA adds 0; ss defaults to row 0, in-bounds).
    #pragma unroll 4
    for (int jj = 0; jj < cl; jj += 2) {
      int e0 = jj + half;
      float ww = __shfl(p, e0);
      int   ss = __shfl(s_cur, e0);
      us8 xv = *(const us8*)(xlbf + (size_t)ss*256 + colb);
      #pragma unroll
      for (int i = 0; i < 8; ++i) acc8[i] += ww * bf2f(xv[i]);
    }
    s_cur = s_nxt; we_cur = we_nxt;
  }
  #pragma unroll
  for (int o = 32; o > 0; o >>= 1) {
    dsum_l  += __shfl_xor(dsum_l, o);
    wesum_l += __shfl_xor(wesum_l, o);
  }

  float a_self = as_[n] + ad_n + wesum_l / fmaxf((float)deg, 1.f);
  a_self = (a_self >= 0.f) ? a_self : LEAK * a_self;
  float p_self = __expf(fmaxf(fminf(a_self, 60.f), -60.f));
  float dsum = dsum_l + p_self;

  // fold even/odd halves: lane L and L+32 hold the same columns
  #pragma unroll
  for (int i = 0; i < 8; ++i) acc8[i] += __shfl_xor(acc8[i], 32);

  if (half == 0) {
    // self loop
    us8 xv = *(const us8*)(xlbf + (size_t)n*256 + colb);
    #pragma unroll
    for (int i = 0; i < 8; ++i) acc8[i] += p_self * bf2f(xv[i]);
    float inv_d = 1.f / dsum;
    int f32 = (*cntp >= 4) ? 1 : 0;
    unsigned short* hp = hbf + (size_t)n*256 + colb;
    us8 hv = *(const us8*)hp;
    us8 q;
    #pragma unroll
    for (int i = 0; i < 8; ++i) {
      float val = acc8[i] * inv_d + rdw(bias, (size_t)l*256 + colb + i, f32);
      if (do_relu) val = fmaxf(val, 0.f);
      q[i] = f2bf(val + bf2f(hv[i]));
    }
    *(us8*)hp = q;
  }
}

// ---------------- pooling + head (batch is sorted; h stream is bf16) ----------------

__global__ __launch_bounds__(256) void k_pool_head(const unsigned short* __restrict__ hbf,
                                                   const int* __restrict__ batch,
                                                   const float* __restrict__ v,
                                                   const float* __restrict__ c0,
                                                   void* __restrict__ out,
                                                   const int* __restrict__ cntp) {
  int g = blockIdx.x;
  int lo = 0, hi = NN;
  while (lo < hi) { int mid = (lo + hi) >> 1; if (batch[mid] < g) lo = mid + 1; else hi = mid; }
  int start = lo;
  lo = 0; hi = NN;
  while (lo < hi) { int mid = (lo + hi) >> 1; if (batch[mid] < g + 1) lo = mid + 1; else hi = mid; }
  int endn = lo;

  int c = threadIdx.x;
  float s = 0.f;
  for (int n = start; n < endn; ++n) s += bf2f(hbf[(size_t)n*256 + c]);
  __shared__ float red[256];
  red[c] = s * v[c];
  __syncthreads();
  for (int off = 128; off > 0; off >>= 1) {
    if (c < off) red[c] += red[c + off];
    __syncthreads();
  }
  if (c == 0) {
    float cntf = (float)(endn - start);
    float val = red[0] / fmaxf(cntf, 1.f) + *c0;
    if (*cntp >= 4) ((float*)out)[g] = val;
    else            ((unsigned short*)out)[g] = f2bf(val);
  }
}

extern "C" void kernel_launch(void* const* d_in, const int* in_sizes, int n_in,
                              void* d_out, int out_size, void* d_ws, size_t ws_size,
                              hipStream_t stream) {
  const int* x     = (const int*)d_in[0];
  const int* eidx  = (const int*)d_in[1];
  const int* eattr = (const int*)d_in[2];
  const int* batch = (const int*)d_in[3];
  const void* atom_emb = d_in[4];
  const void* bond_emb = d_in[5];
  const void* W        = d_in[6];
  const void* att_src  = d_in[7];
  const void* att_dst  = d_in[8];
  const void* We       = d_in[9];
  const void* att_edge = d_in[10];
  const void* bias     = d_in[11];
  const void* W1 = d_in[12];
  const void* b1 = d_in[13];
  const void* W2 = d_in[14];
  const void* b2 = d_in[15];

  const int* src = eidx;
  const int* dst = eidx + NE;

  char* base = (char*)d_ws;
  size_t off = 0;
  auto alloc = [&](size_t bytes) -> char* {
    char* p = base + off; off += (bytes + 255) & ~(size_t)255; return p;
  };
  unsigned short* xlbf = (unsigned short*)alloc((size_t)NN*EMBD*2);
  unsigned short* hbf  = (unsigned short*)alloc((size_t)NN*EMBD*2);
  unsigned short* wt   = (unsigned short*)alloc((size_t)NLAY*EMBD*EMBD*2);
  float4* erec = (float4*)alloc((size_t)NE*16);
  float* as_   = (float*)alloc((size_t)NN*4);
  float* ad_   = (float*)alloc((size_t)NN*4);
  float* vvec  = (float*)alloc((size_t)EMBD*4);
  float* c0    = (float*)alloc(4);
  float* wa_all= (float*)alloc(64);
  int*   cnt   = (int*)alloc(4);
  int* cnt_i   = (int*)alloc((size_t)NN*4);
  int* row_ptr = (int*)alloc((size_t)(NN+1)*4);
  int* cursor  = (int*)alloc((size_t)NN*4);
  int* part    = (int*)alloc((size_t)NBLK_SCAN*4);
  int* offs    = (int*)alloc((size_t)NBLK_SCAN*4);

  (void)hipMemsetAsync(cnt, 0, 4, stream);
  (void)hipMemsetAsync(cnt_i, 0, (size_t)NN*4, stream);
  k_sniff_hist<<<16 + (NE+255)/256, 256, 0, stream>>>((const unsigned short*)atom_emb,
                                                      cnt, dst, cnt_i);
  k_scan_dots<<<NBLK_SCAN + 67, 256, 0, stream>>>(cnt_i, row_ptr, part,
                                                  We, att_edge, W1, b1, W2, b2,
                                                  cnt, wa_all, vvec, c0);
  k_scan_mid<<<1, 128, 0, stream>>>(part, offs);
  k_scan_add<<<NBLK_SCAN, 256, 0, stream>>>(row_ptr, offs, cursor);
  k_fill_we<<<(NE+255)/256, 256, 0, stream>>>(src, dst, eattr, bond_emb, wa_all,
                                              cursor, erec, cnt);
  k_atom_prep<<<NN + 768, 256, 0, stream>>>(x, atom_emb, hbf, W, wt, cnt);

  for (int l = 0; l < NLAY; ++l) {
    k_gemm_fused<<<NN/GROWS, 256, 0, stream>>>(hbf, wt + (size_t)l*EMBD*EMBD,
                                               att_src, att_dst, l, xlbf, as_, ad_, cnt);
    k_fused<<<NN/4, 256, 0, stream>>>(row_ptr, erec, as_, ad_, xlbf, bias, l, hbf,
                                      (l < NLAY-1) ? 1 : 0, cnt);
  }

  k_pool_head<<<NG, 256, 0, stream>>>(hbf, batch, vvec, c0, d_out, cnt);
}